// Round 1
// baseline (2644.668 us; speedup 1.0000x reference)
//
#include <hip/hip_runtime.h>
#include <hip/hip_bf16.h>
#include <math.h>

typedef unsigned int uint;
typedef unsigned long long u64;

#define BB 4
#define NN 100000
#define PRE 6000
#define POST 1000
#define NWRD 94          // 6000/64 rounded up
#define PITCH 96         // padded words per matrix row
#define CAP 8192
#define ROWP 6016        // padded rows for boxes/scores arrays

// ---- workspace layout (bytes) ----
constexpr size_t OFF_HDR   = 0;                                   // 16 uints: t1[4], cLt1[4], vstar[4], cnt[4]
constexpr size_t OFF_H1    = 1024;
constexpr size_t OFF_H2    = OFF_H1  + (size_t)BB*65536*4;
constexpr size_t OFF_KEY   = OFF_H2  + (size_t)BB*65536*4;
constexpr size_t OFF_CAND  = OFF_KEY + (size_t)BB*NN*4;
constexpr size_t OFF_BOX   = OFF_CAND+ (size_t)BB*CAP*8;
constexpr size_t OFF_SCO   = OFF_BOX + (size_t)BB*ROWP*16;
constexpr size_t OFF_AREA  = OFF_SCO + (size_t)BB*ROWP*4;
constexpr size_t OFF_KINIT = OFF_AREA+ (size_t)BB*ROWP*4;
constexpr size_t OFF_KFIN  = OFF_KINIT+(size_t)BB*96*8;
constexpr size_t OFF_MAT   = OFF_KFIN +(size_t)BB*96*8;
// total = OFF_MAT + BB*6000*96*8  ~= 23 MB

__device__ __forceinline__ float clipf(float v, float hi) {
  return fminf(fmaxf(v, 0.0f), hi);
}

// ---------- zero hists + header ----------
__global__ void zero_ws(uint4* p, int n4) {
  int t = blockIdx.x * 256 + threadIdx.x;
  uint4 z; z.x = z.y = z.z = z.w = 0u;
  for (; t < n4; t += gridDim.x * 256) p[t] = z;
}

// ---------- pass 1: keys + level-0 histogram ----------
__global__ void keys_hist(const float4* __restrict__ props,
                          const float2* __restrict__ clsp,
                          uint* __restrict__ keyhi,
                          uint* __restrict__ hist1) {
  int b = blockIdx.y;
  int i = blockIdx.x * 256 + threadIdx.x;
  bool act = (i < NN);
  bool valid = false;
  uint kh = 0xFF800000u;     // key of -inf
  if (act) {
    float4 p = props[(size_t)b * NN + i];
    float x1 = clipf(p.x, 800.0f), y1 = clipf(p.y, 800.0f);
    float x2 = clipf(p.z, 800.0f), y2 = clipf(p.w, 800.0f);
    valid = ((x2 - x1) >= 16.0f) && ((y2 - y1) >= 16.0f);
    float s  = clsp[(size_t)b * NN + i].y;
    float sm = valid ? s : -INFINITY;
    uint u = __float_as_uint(sm);
    u = (u & 0x80000000u) ? ~u : (u | 0x80000000u);  // monotonic: ascending u == ascending score
    kh = ~u;                                          // ascending kh == DESCENDING score
    keyhi[(size_t)b * NN + i] = kh;
  }
  if (act && valid) atomicAdd(&hist1[(size_t)b * 65536 + (kh >> 16)], 1u);
  // invalid boxes all hit one bucket -> aggregate per wave to avoid hot-spot atomics
  u64 mb = __ballot(act && !valid);
  int lane = threadIdx.x & 63;
  if ((act && !valid) && lane == (__ffsll((long long)mb) - 1))
    atomicAdd(&hist1[(size_t)b * 65536 + 0xFF80u], (uint)__popcll(mb));
}

// ---------- histogram threshold scan (level 0 and 1) ----------
__global__ __launch_bounds__(1024) void scan_hist(const uint* __restrict__ hist,
                                                  uint* __restrict__ hdr, int level) {
  int b = blockIdx.x, tid = threadIdx.x;
  const uint* h = hist + (size_t)b * 65536;
  uint target = (level == 0) ? (uint)PRE : ((uint)PRE - hdr[4 + b]);
  uint base = tid * 64, s = 0;
  for (int k = 0; k < 64; ++k) s += h[base + k];
  __shared__ uint sc[1024];
  sc[tid] = s; __syncthreads();
  for (int off = 1; off < 1024; off <<= 1) {
    uint v = (tid >= off) ? sc[tid - off] : 0u;
    __syncthreads();
    sc[tid] += v;
    __syncthreads();
  }
  uint incl = sc[tid], excl = incl - s;
  if (excl < target && target <= incl) {   // unique owner thread
    uint c = excl, bucket = 0, clt = 0;
    for (int k = 0; k < 64; ++k) {
      uint hv = h[base + k];
      if (c < target && target <= c + hv) { bucket = base + k; clt = c; break; }
      c += hv;
    }
    if (level == 0) { hdr[0 + b] = bucket; hdr[4 + b] = clt; }
    else            { hdr[8 + b] = (hdr[0 + b] << 16) | (bucket & 0xFFFFu); }
  }
}

// ---------- pass 2: level-1 histogram of the boundary bucket ----------
__global__ void hist2_fill(const uint* __restrict__ keyhi,
                           const uint* __restrict__ hdr,
                           uint* __restrict__ hist2) {
  int b = blockIdx.y;
  int i = blockIdx.x * 256 + threadIdx.x;
  if (i >= NN) return;
  uint kh = keyhi[(size_t)b * NN + i];
  if ((kh >> 16) == hdr[0 + b])
    atomicAdd(&hist2[(size_t)b * 65536 + (kh & 0xFFFFu)], 1u);
}

// ---------- pass 3: compact candidates (all keys <= vstar) ----------
__global__ void compact(const uint* __restrict__ keyhi,
                        uint* __restrict__ hdr,
                        u64* __restrict__ cand) {
  int b = blockIdx.y;
  int i = blockIdx.x * 256 + threadIdx.x;
  int lane = threadIdx.x & 63;
  bool take = false; uint kh = 0;
  if (i < NN) {
    kh = keyhi[(size_t)b * NN + i];
    take = (kh <= hdr[8 + b]);
  }
  u64 mb = __ballot(take);
  if (mb) {
    int leader = __ffsll((long long)mb) - 1;
    uint base = 0;
    if (lane == leader) base = atomicAdd(&hdr[12 + b], (uint)__popcll(mb));
    base = __shfl(base, leader);
    if (take) {
      uint pos = base + (uint)__popcll(mb & ((1ull << lane) - 1ull));
      if (pos < CAP) cand[(size_t)b * CAP + pos] = ((u64)kh << 32) | (uint)i;
    }
  }
}

// ---------- pass 4: per-image bitonic sort + gather top-6000 ----------
__global__ __launch_bounds__(1024) void sort_gather(const u64* __restrict__ cand,
                                                    const uint* __restrict__ hdr,
                                                    const float4* __restrict__ props,
                                                    const float2* __restrict__ clsp,
                                                    float4* __restrict__ boxes6k,
                                                    float* __restrict__ score6k,
                                                    float* __restrict__ area6k,
                                                    u64* __restrict__ keepInit) {
  int b = blockIdx.x, tid = threadIdx.x;
  __shared__ u64 sh[CAP];          // 64 KiB
  int cntb = (int)hdr[12 + b]; if (cntb > CAP) cntb = CAP;
  for (int j = tid; j < CAP; j += 1024) sh[j] = (j < cntb) ? cand[(size_t)b * CAP + j] : ~0ull;
  __syncthreads();
  for (int k = 2; k <= CAP; k <<= 1) {
    for (int j = k >> 1; j > 0; j >>= 1) {
      for (int t = tid; t < CAP; t += 1024) {
        int ixj = t ^ j;
        if (ixj > t) {
          u64 a = sh[t], c = sh[ixj];
          bool up = ((t & k) == 0);
          if ((a > c) == up) { sh[t] = c; sh[ixj] = a; }
        }
      }
      __syncthreads();
    }
  }
  int lane = tid & 63;
  for (int basej = 0; basej < 6144; basej += 1024) {
    int j = basej + tid;
    bool valid = false; float sc = -INFINITY, ar = 0.0f;
    float4 bx; bx.x = bx.y = bx.z = bx.w = 0.0f;
    if (j < PRE && j < cntb) {
      uint idx = (uint)(sh[j] & 0xFFFFFFFFull);
      float4 p = props[(size_t)b * NN + idx];
      float x1 = clipf(p.x, 800.0f), y1 = clipf(p.y, 800.0f);
      float x2 = clipf(p.z, 800.0f), y2 = clipf(p.w, 800.0f);
      float w = x2 - x1, h = y2 - y1;
      valid = (w >= 16.0f) && (h >= 16.0f);
      sc = clsp[(size_t)b * NN + idx].y;
      bx.x = x1; bx.y = y1; bx.z = x2; bx.w = y2;
      ar = fmaxf(x2 - x1, 0.0f) * fmaxf(y2 - y1, 0.0f);
    }
    if (j < ROWP) {
      boxes6k[(size_t)b * ROWP + j] = bx;
      score6k[(size_t)b * ROWP + j] = sc;
      area6k [(size_t)b * ROWP + j] = ar;
    }
    u64 mb = __ballot(valid);
    if (lane == 0) keepInit[(size_t)b * 96 + (j >> 6)] = ~mb;   // removed-init = ~valid
  }
}

// ---------- pass 5: suppression bit-matrix (upper triangle) ----------
__global__ __launch_bounds__(64) void nms_matrix(const float4* __restrict__ boxes6k,
                                                 const float* __restrict__ area6k,
                                                 u64* __restrict__ mat) {
  int cb = blockIdx.x, rb = blockIdx.y, b = blockIdx.z;
  if (cb < rb) return;
  __shared__ float4 cbox[64];
  __shared__ float  car[64];
  int t = threadIdx.x;
  int cj = cb * 64 + t;
  int cjc = cj < (ROWP - 1) ? cj : (ROWP - 1);
  cbox[t] = boxes6k[(size_t)b * ROWP + cjc];
  car[t]  = area6k [(size_t)b * ROWP + cjc];
  __syncthreads();
  int i = rb * 64 + t;
  if (i >= PRE) return;
  float4 r = boxes6k[(size_t)b * ROWP + i];
  float ra = area6k[(size_t)b * ROWP + i];
  u64 bits = 0;
  #pragma unroll 8
  for (int jj = 0; jj < 64; ++jj) {
    int j = cb * 64 + jj;
    if (j < PRE && j > i) {
      float4 c = cbox[jj];
      float xx1 = fmaxf(r.x, c.x), yy1 = fmaxf(r.y, c.y);
      float xx2 = fminf(r.z, c.z), yy2 = fminf(r.w, c.w);
      float inter = fmaxf(xx2 - xx1, 0.0f) * fmaxf(yy2 - yy1, 0.0f);
      float un = ra + car[jj] - inter;
      float iou = inter / fmaxf(un, 1e-9f);
      if (iou > 0.7f) bits |= (1ull << jj);
    }
  }
  mat[((size_t)b * PRE + i) * PITCH + cb] = bits;
}

// ---------- pass 6: sequential greedy bit pass (1 wave per image) ----------
__global__ __launch_bounds__(64) void nms_seq(const u64* __restrict__ mat,
                                              const u64* __restrict__ keepInit,
                                              u64* __restrict__ keepFin) {
  int b = blockIdx.x, lane = threadIdx.x;
  const u64* M = mat + (size_t)b * PRE * PITCH;
  u64 rem0 = keepInit[(size_t)b * 96 + lane];                       // word = lane
  u64 rem1 = (lane < 30) ? keepInit[(size_t)b * 96 + 64 + lane] : ~0ull; // word = 64+lane
  int r1w = 64 + (lane < 30 ? lane : 29);
  u64 pfD[8], pf0[8], pf1[8];
  #pragma unroll
  for (int d = 0; d < 8; ++d) {
    pfD[d] = M[(size_t)d * PITCH + 0];
    pf0[d] = M[(size_t)d * PITCH + lane];
    pf1[d] = M[(size_t)d * PITCH + r1w];
  }
  u64 cur = 0;
  for (int i8 = 0; i8 < PRE; i8 += 8) {
    if ((i8 & 63) == 0) {
      int g = i8 >> 6;
      cur = (g < 64) ? __shfl(rem0, g) : __shfl(rem1, g - 64);
    }
    int w = i8 >> 6;                       // 8-blocks never span a 64-group
    u64 mA = (lane >= w) ? ~0ull : 0ull;
    u64 mB = ((lane < 30) && (lane + 64 >= w)) ? ~0ull : 0ull;
    #pragma unroll
    for (int d = 0; d < 8; ++d) {
      int i = i8 + d;
      u64 diag = pfD[d], row0 = pf0[d], row1 = pf1[d];
      int ip = i + 8;
      if (ip < PRE) {
        pfD[d] = M[(size_t)ip * PITCH + (ip >> 6)];
        pf0[d] = M[(size_t)ip * PITCH + lane];
        pf1[d] = M[(size_t)ip * PITCH + r1w];
      }
      int bit = i & 63;
      u64 m = (((cur >> bit) & 1ull) == 0ull) ? ~0ull : 0ull;  // alive?
      cur  |= diag & m;
      rem0 |= row0 & mA & m;
      rem1 |= row1 & mB & m;
    }
  }
  keepFin[(size_t)b * 96 + lane] = ~rem0;
  if (lane < 30) keepFin[(size_t)b * 96 + 64 + lane] = ~rem1;
}

// ---------- pass 7: finalize (rank kept, emit first 1000) ----------
__global__ __launch_bounds__(1024) void finalize(const u64* __restrict__ keepFin,
                                                 const float* __restrict__ score6k,
                                                 const float4* __restrict__ boxes6k,
                                                 float* __restrict__ out) {
  int b = blockIdx.x, tid = threadIdx.x;
  __shared__ u64 kw[NWRD];
  __shared__ uint pre[NWRD + 1];
  if (tid < NWRD) kw[tid] = keepFin[(size_t)b * 96 + tid];
  __syncthreads();
  if (tid == 0) {
    uint c = 0;
    for (int w = 0; w < NWRD; ++w) { pre[w] = c; c += (uint)__popcll(kw[w]); }
    pre[NWRD] = c;
  }
  __syncthreads();
  for (int q = tid; q < POST; q += 1024) out[(size_t)b * POST + q] = 0.0f;
  for (int t = tid; t < POST * 4; t += 1024) out[(size_t)BB * POST + (size_t)b * POST * 4 + t] = 0.0f;
  __syncthreads();
  for (int j = tid; j < PRE; j += 1024) {
    int w = j >> 6, bit = j & 63;
    u64 word = kw[w];
    if ((word >> bit) & 1ull) {
      uint rank = pre[w] + (uint)__popcll(word & ((1ull << bit) - 1ull));
      if (rank < POST) {
        out[(size_t)b * POST + rank] = score6k[(size_t)b * ROWP + j];
        float4 bx = boxes6k[(size_t)b * ROWP + j];
        float* o = out + (size_t)BB * POST + ((size_t)b * POST + rank) * 4;
        o[0] = bx.x; o[1] = bx.y; o[2] = bx.z; o[3] = bx.w;
      }
    }
  }
}

extern "C" void kernel_launch(void* const* d_in, const int* in_sizes, int n_in,
                              void* d_out, int out_size, void* d_ws, size_t ws_size,
                              hipStream_t stream) {
  const float4* props = (const float4*)d_in[0];
  const float2* clsp  = (const float2*)d_in[1];
  float* out = (float*)d_out;
  char* ws = (char*)d_ws;

  uint*   hdr     = (uint*)(ws + OFF_HDR);
  uint*   hist1   = (uint*)(ws + OFF_H1);
  uint*   hist2   = (uint*)(ws + OFF_H2);
  uint*   keyhi   = (uint*)(ws + OFF_KEY);
  u64*    cand    = (u64*) (ws + OFF_CAND);
  float4* boxes6k = (float4*)(ws + OFF_BOX);
  float*  score6k = (float*)(ws + OFF_SCO);
  float*  area6k  = (float*)(ws + OFF_AREA);
  u64*    keepInit= (u64*) (ws + OFF_KINIT);
  u64*    keepFin = (u64*) (ws + OFF_KFIN);
  u64*    mat     = (u64*) (ws + OFF_MAT);

  // zero header + both histograms
  int n4 = (int)((1024 + 2 * (size_t)BB * 65536 * 4) / 16);
  zero_ws<<<512, 256, 0, stream>>>((uint4*)ws, n4);

  dim3 gN((NN + 255) / 256, BB);
  keys_hist<<<gN, 256, 0, stream>>>(props, clsp, keyhi, hist1);
  scan_hist<<<BB, 1024, 0, stream>>>(hist1, hdr, 0);
  hist2_fill<<<gN, 256, 0, stream>>>(keyhi, hdr, hist2);
  scan_hist<<<BB, 1024, 0, stream>>>(hist2, hdr, 1);
  compact<<<gN, 256, 0, stream>>>(keyhi, hdr, cand);
  sort_gather<<<BB, 1024, 0, stream>>>(cand, hdr, props, clsp, boxes6k, score6k, area6k, keepInit);
  nms_matrix<<<dim3(NWRD, NWRD, BB), 64, 0, stream>>>(boxes6k, area6k, mat);
  nms_seq<<<BB, 64, 0, stream>>>(mat, keepInit, keepFin);
  finalize<<<BB, 1024, 0, stream>>>(keepFin, score6k, boxes6k, out);
}

// Round 2
// 947.186 us; speedup vs baseline: 2.7921x; 2.7921x over previous
//
#include <hip/hip_runtime.h>
#include <hip/hip_bf16.h>
#include <math.h>

typedef unsigned int uint;
typedef unsigned long long u64;

#define BB 4
#define NN 100000
#define PRE 6000
#define POST 1000
#define NWRD 94          // 6000/64 rounded up
#define NCW 96           // padded column-words
#define CAP 8192
#define ROWP 6016        // padded rows for boxes/scores arrays and matT columns

// ---- workspace layout (bytes) ----
constexpr size_t OFF_HDR   = 0;                                   // 16 uints
constexpr size_t OFF_H1    = 1024;
constexpr size_t OFF_H2    = OFF_H1  + (size_t)BB*65536*4;
constexpr size_t OFF_KEY   = OFF_H2  + (size_t)BB*65536*4;
constexpr size_t OFF_CAND  = OFF_KEY + (size_t)BB*NN*4;
constexpr size_t OFF_BOX   = OFF_CAND+ (size_t)BB*CAP*8;
constexpr size_t OFF_SCO   = OFF_BOX + (size_t)BB*ROWP*16;
constexpr size_t OFF_AREA  = OFF_SCO + (size_t)BB*ROWP*4;
constexpr size_t OFF_KINIT = OFF_AREA+ (size_t)BB*ROWP*4;
constexpr size_t OFF_KFIN  = OFF_KINIT+(size_t)BB*96*8;
constexpr size_t OFF_MAT   = OFF_KFIN +(size_t)BB*96*8;
// total = OFF_MAT + BB*NCW*ROWP*8  ~= 23 MB

__device__ __forceinline__ float clipf(float v, float hi) {
  return fminf(fmaxf(v, 0.0f), hi);
}

// ---------- zero hists + header ----------
__global__ void zero_ws(uint4* p, int n4) {
  int t = blockIdx.x * 256 + threadIdx.x;
  uint4 z; z.x = z.y = z.z = z.w = 0u;
  for (; t < n4; t += gridDim.x * 256) p[t] = z;
}

// ---------- pass 1: keys + level-0 histogram ----------
__global__ void keys_hist(const float4* __restrict__ props,
                          const float2* __restrict__ clsp,
                          uint* __restrict__ keyhi,
                          uint* __restrict__ hist1) {
  int b = blockIdx.y;
  int i = blockIdx.x * 256 + threadIdx.x;
  bool act = (i < NN);
  bool valid = false;
  uint kh = 0xFF800000u;     // key of -inf
  if (act) {
    float4 p = props[(size_t)b * NN + i];
    float x1 = clipf(p.x, 800.0f), y1 = clipf(p.y, 800.0f);
    float x2 = clipf(p.z, 800.0f), y2 = clipf(p.w, 800.0f);
    valid = ((x2 - x1) >= 16.0f) && ((y2 - y1) >= 16.0f);
    float s  = clsp[(size_t)b * NN + i].y;
    float sm = valid ? s : -INFINITY;
    uint u = __float_as_uint(sm);
    u = (u & 0x80000000u) ? ~u : (u | 0x80000000u);  // monotonic: ascending u == ascending score
    kh = ~u;                                          // ascending kh == DESCENDING score
    keyhi[(size_t)b * NN + i] = kh;
  }
  if (act && valid) atomicAdd(&hist1[(size_t)b * 65536 + (kh >> 16)], 1u);
  // invalid boxes all hit one bucket -> aggregate per wave to avoid hot-spot atomics
  u64 mb = __ballot(act && !valid);
  int lane = threadIdx.x & 63;
  if ((act && !valid) && lane == (__ffsll((long long)mb) - 1))
    atomicAdd(&hist1[(size_t)b * 65536 + 0xFF80u], (uint)__popcll(mb));
}

// ---------- histogram threshold scan (level 0 and 1) ----------
__global__ __launch_bounds__(1024) void scan_hist(const uint* __restrict__ hist,
                                                  uint* __restrict__ hdr, int level) {
  int b = blockIdx.x, tid = threadIdx.x;
  const uint* h = hist + (size_t)b * 65536;
  uint target = (level == 0) ? (uint)PRE : ((uint)PRE - hdr[4 + b]);
  uint base = tid * 64, s = 0;
  for (int k = 0; k < 64; ++k) s += h[base + k];
  __shared__ uint sc[1024];
  sc[tid] = s; __syncthreads();
  for (int off = 1; off < 1024; off <<= 1) {
    uint v = (tid >= off) ? sc[tid - off] : 0u;
    __syncthreads();
    sc[tid] += v;
    __syncthreads();
  }
  uint incl = sc[tid], excl = incl - s;
  if (excl < target && target <= incl) {   // unique owner thread
    uint c = excl, bucket = 0, clt = 0;
    for (int k = 0; k < 64; ++k) {
      uint hv = h[base + k];
      if (c < target && target <= c + hv) { bucket = base + k; clt = c; break; }
      c += hv;
    }
    if (level == 0) { hdr[0 + b] = bucket; hdr[4 + b] = clt; }
    else            { hdr[8 + b] = (hdr[0 + b] << 16) | (bucket & 0xFFFFu); }
  }
}

// ---------- pass 2: level-1 histogram of the boundary bucket ----------
__global__ void hist2_fill(const uint* __restrict__ keyhi,
                           const uint* __restrict__ hdr,
                           uint* __restrict__ hist2) {
  int b = blockIdx.y;
  int i = blockIdx.x * 256 + threadIdx.x;
  if (i >= NN) return;
  uint kh = keyhi[(size_t)b * NN + i];
  if ((kh >> 16) == hdr[0 + b])
    atomicAdd(&hist2[(size_t)b * 65536 + (kh & 0xFFFFu)], 1u);
}

// ---------- pass 3: compact candidates (all keys <= vstar) ----------
__global__ void compact(const uint* __restrict__ keyhi,
                        uint* __restrict__ hdr,
                        u64* __restrict__ cand) {
  int b = blockIdx.y;
  int i = blockIdx.x * 256 + threadIdx.x;
  int lane = threadIdx.x & 63;
  bool take = false; uint kh = 0;
  if (i < NN) {
    kh = keyhi[(size_t)b * NN + i];
    take = (kh <= hdr[8 + b]);
  }
  u64 mb = __ballot(take);
  if (mb) {
    int leader = __ffsll((long long)mb) - 1;
    uint base = 0;
    if (lane == leader) base = atomicAdd(&hdr[12 + b], (uint)__popcll(mb));
    base = __shfl(base, leader);
    if (take) {
      uint pos = base + (uint)__popcll(mb & ((1ull << lane) - 1ull));
      if (pos < CAP) cand[(size_t)b * CAP + pos] = ((u64)kh << 32) | (uint)i;
    }
  }
}

// ---------- pass 4: per-image bitonic sort + gather top-6000 ----------
__global__ __launch_bounds__(1024) void sort_gather(const u64* __restrict__ cand,
                                                    const uint* __restrict__ hdr,
                                                    const float4* __restrict__ props,
                                                    const float2* __restrict__ clsp,
                                                    float4* __restrict__ boxes6k,
                                                    float* __restrict__ score6k,
                                                    float* __restrict__ area6k,
                                                    u64* __restrict__ keepInit) {
  int b = blockIdx.x, tid = threadIdx.x;
  __shared__ u64 sh[CAP];          // 64 KiB
  int cntb = (int)hdr[12 + b]; if (cntb > CAP) cntb = CAP;
  for (int j = tid; j < CAP; j += 1024) sh[j] = (j < cntb) ? cand[(size_t)b * CAP + j] : ~0ull;
  __syncthreads();
  for (int k = 2; k <= CAP; k <<= 1) {
    for (int j = k >> 1; j > 0; j >>= 1) {
      for (int t = tid; t < CAP; t += 1024) {
        int ixj = t ^ j;
        if (ixj > t) {
          u64 a = sh[t], c = sh[ixj];
          bool up = ((t & k) == 0);
          if ((a > c) == up) { sh[t] = c; sh[ixj] = a; }
        }
      }
      __syncthreads();
    }
  }
  int lane = tid & 63;
  for (int basej = 0; basej < 6144; basej += 1024) {
    int j = basej + tid;
    bool valid = false; float sc = -INFINITY, ar = 0.0f;
    float4 bx; bx.x = bx.y = bx.z = bx.w = 0.0f;
    if (j < PRE && j < cntb) {
      uint idx = (uint)(sh[j] & 0xFFFFFFFFull);
      float4 p = props[(size_t)b * NN + idx];
      float x1 = clipf(p.x, 800.0f), y1 = clipf(p.y, 800.0f);
      float x2 = clipf(p.z, 800.0f), y2 = clipf(p.w, 800.0f);
      float w = x2 - x1, h = y2 - y1;
      valid = (w >= 16.0f) && (h >= 16.0f);
      sc = clsp[(size_t)b * NN + idx].y;
      bx.x = x1; bx.y = y1; bx.z = x2; bx.w = y2;
      ar = fmaxf(x2 - x1, 0.0f) * fmaxf(y2 - y1, 0.0f);
    }
    if (j < ROWP) {
      boxes6k[(size_t)b * ROWP + j] = bx;
      score6k[(size_t)b * ROWP + j] = sc;
      area6k [(size_t)b * ROWP + j] = ar;
    }
    u64 mb = __ballot(valid);
    if (lane == 0) keepInit[(size_t)b * 96 + (j >> 6)] = ~mb;   // removed-init = ~valid
  }
}

// ---------- pass 5: suppression bit-matrix, TRANSPOSED: matT[colword][row] ----------
__global__ __launch_bounds__(64) void nms_matrix(const float4* __restrict__ boxes6k,
                                                 const float* __restrict__ area6k,
                                                 u64* __restrict__ matT) {
  int cb = blockIdx.x, rb = blockIdx.y, b = blockIdx.z;
  if (cb < rb) return;
  __shared__ float4 cbox[64];
  __shared__ float  car[64];
  int t = threadIdx.x;
  int cj = cb * 64 + t;
  int cjc = cj < (ROWP - 1) ? cj : (ROWP - 1);
  cbox[t] = boxes6k[(size_t)b * ROWP + cjc];
  car[t]  = area6k [(size_t)b * ROWP + cjc];
  __syncthreads();
  int i = rb * 64 + t;
  if (i >= PRE) return;
  float4 r = boxes6k[(size_t)b * ROWP + i];
  float ra = area6k[(size_t)b * ROWP + i];
  u64 bits = 0;
  #pragma unroll 8
  for (int jj = 0; jj < 64; ++jj) {
    int j = cb * 64 + jj;
    if (j < PRE && j > i) {
      float4 c = cbox[jj];
      float xx1 = fmaxf(r.x, c.x), yy1 = fmaxf(r.y, c.y);
      float xx2 = fminf(r.z, c.z), yy2 = fminf(r.w, c.w);
      float inter = fmaxf(xx2 - xx1, 0.0f) * fmaxf(yy2 - yy1, 0.0f);
      float un = ra + car[jj] - inter;
      float iou = inter / fmaxf(un, 1e-9f);
      if (iou > 0.7f) bits |= (1ull << jj);
    }
  }
  matT[((size_t)b * NCW + cb) * ROWP + i] = bits;   // coalesced: consecutive i
}

// ---------- pass 6: group-sequential greedy NMS, 16 waves per image ----------
// Per 64-group g: wave0 serially resolves diagonal; 16 waves reduce-OR the
// alive rows' suppression words into later column-words (LDS REM[]).
// Column loads for group g+1 are prefetched (double-buffered regs) before the
// serial phase, hiding load latency under it.
__global__ __launch_bounds__(1024) void nms_seq2(const u64* __restrict__ matT,
                                                 const u64* __restrict__ keepInit,
                                                 u64* __restrict__ keepFin) {
  int b = blockIdx.x;
  int tid = threadIdx.x, lane = tid & 63, W = tid >> 6;
  __shared__ u64 REM[96];
  __shared__ u64 ALIVE;
  if (tid < NWRD) REM[tid] = keepInit[(size_t)b * 96 + tid];
  else if (tid < 96) REM[tid] = ~0ull;
  const u64* T = matT + (size_t)b * NCW * ROWP;

  u64 pfA[6], pfB[6];
  u64 D = 0;
  // prologue: prefetch group 0
  {
    const int g = 0;
    #pragma unroll
    for (int j = 0; j < 6; ++j) {
      int c = g + 1 + W + 16 * j;
      pfA[j] = (c < NWRD) ? T[(size_t)c * ROWP + (g * 64 + lane)] : 0ull;
    }
    if (W == 0) D = T[(size_t)g * ROWP + (g * 64 + lane)];
  }
  __syncthreads();

  for (int g = 0; g < NWRD; ++g) {
    // issue prefetch for group g+1 (independent of this group's outcome)
    int gn = g + 1;
    u64 Dn = 0;
    #pragma unroll
    for (int j = 0; j < 6; ++j) {
      int c = gn + 1 + W + 16 * j;
      pfB[j] = (gn < NWRD && c < NWRD) ? T[(size_t)c * ROWP + (gn * 64 + lane)] : 0ull;
    }
    if (W == 0 && gn < NWRD) Dn = T[(size_t)gn * ROWP + (gn * 64 + lane)];

    // P1: wave 0 resolves the diagonal serially over alive bits
    if (W == 0) {
      u64 w = REM[g];
      u64 alive = ~w;
      u64 todo = alive;
      while (todo) {
        int k = __ffsll((long long)todo) - 1;
        todo &= todo - 1;
        u64 wk = __shfl(D, k);   // suppression of row g*64+k within this word (bits > k only)
        alive &= ~wk;
        todo  &= ~wk;
      }
      if (lane == 0) { ALIVE = alive; REM[g] = ~alive; }
    }
    __syncthreads();

    // P2: all 16 waves fold alive rows into their owned later column-words
    u64 alive = ALIVE;
    if (alive) {
      #pragma unroll
      for (int j = 0; j < 6; ++j) {
        int c = g + 1 + W + 16 * j;
        if (c < NWRD) {
          u64 v = ((alive >> lane) & 1ull) ? pfA[j] : 0ull;
          #pragma unroll
          for (int s = 1; s < 64; s <<= 1) v |= __shfl_xor(v, s);
          if (lane == 0) REM[c] |= v;   // unique wave per column-word
        }
      }
    }
    __syncthreads();

    #pragma unroll
    for (int j = 0; j < 6; ++j) pfA[j] = pfB[j];
    D = Dn;
  }
  if (tid < NWRD) keepFin[(size_t)b * 96 + tid] = ~REM[tid];
}

// ---------- pass 7: finalize (rank kept, emit first 1000) ----------
__global__ __launch_bounds__(1024) void finalize(const u64* __restrict__ keepFin,
                                                 const float* __restrict__ score6k,
                                                 const float4* __restrict__ boxes6k,
                                                 float* __restrict__ out) {
  int b = blockIdx.x, tid = threadIdx.x;
  __shared__ u64 kw[NWRD];
  __shared__ uint pre[NWRD + 1];
  if (tid < NWRD) kw[tid] = keepFin[(size_t)b * 96 + tid];
  __syncthreads();
  if (tid == 0) {
    uint c = 0;
    for (int w = 0; w < NWRD; ++w) { pre[w] = c; c += (uint)__popcll(kw[w]); }
    pre[NWRD] = c;
  }
  __syncthreads();
  for (int q = tid; q < POST; q += 1024) out[(size_t)b * POST + q] = 0.0f;
  for (int t = tid; t < POST * 4; t += 1024) out[(size_t)BB * POST + (size_t)b * POST * 4 + t] = 0.0f;
  __syncthreads();
  for (int j = tid; j < PRE; j += 1024) {
    int w = j >> 6, bit = j & 63;
    u64 word = kw[w];
    if ((word >> bit) & 1ull) {
      uint rank = pre[w] + (uint)__popcll(word & ((1ull << bit) - 1ull));
      if (rank < POST) {
        out[(size_t)b * POST + rank] = score6k[(size_t)b * ROWP + j];
        float4 bx = boxes6k[(size_t)b * ROWP + j];
        float* o = out + (size_t)BB * POST + ((size_t)b * POST + rank) * 4;
        o[0] = bx.x; o[1] = bx.y; o[2] = bx.z; o[3] = bx.w;
      }
    }
  }
}

extern "C" void kernel_launch(void* const* d_in, const int* in_sizes, int n_in,
                              void* d_out, int out_size, void* d_ws, size_t ws_size,
                              hipStream_t stream) {
  const float4* props = (const float4*)d_in[0];
  const float2* clsp  = (const float2*)d_in[1];
  float* out = (float*)d_out;
  char* ws = (char*)d_ws;

  uint*   hdr     = (uint*)(ws + OFF_HDR);
  uint*   hist1   = (uint*)(ws + OFF_H1);
  uint*   hist2   = (uint*)(ws + OFF_H2);
  uint*   keyhi   = (uint*)(ws + OFF_KEY);
  u64*    cand    = (u64*) (ws + OFF_CAND);
  float4* boxes6k = (float4*)(ws + OFF_BOX);
  float*  score6k = (float*)(ws + OFF_SCO);
  float*  area6k  = (float*)(ws + OFF_AREA);
  u64*    keepInit= (u64*) (ws + OFF_KINIT);
  u64*    keepFin = (u64*) (ws + OFF_KFIN);
  u64*    matT    = (u64*) (ws + OFF_MAT);

  // zero header + both histograms
  int n4 = (int)((1024 + 2 * (size_t)BB * 65536 * 4) / 16);
  zero_ws<<<512, 256, 0, stream>>>((uint4*)ws, n4);

  dim3 gN((NN + 255) / 256, BB);
  keys_hist<<<gN, 256, 0, stream>>>(props, clsp, keyhi, hist1);
  scan_hist<<<BB, 1024, 0, stream>>>(hist1, hdr, 0);
  hist2_fill<<<gN, 256, 0, stream>>>(keyhi, hdr, hist2);
  scan_hist<<<BB, 1024, 0, stream>>>(hist2, hdr, 1);
  compact<<<gN, 256, 0, stream>>>(keyhi, hdr, cand);
  sort_gather<<<BB, 1024, 0, stream>>>(cand, hdr, props, clsp, boxes6k, score6k, area6k, keepInit);
  nms_matrix<<<dim3(NWRD, NWRD, BB), 64, 0, stream>>>(boxes6k, area6k, matT);
  nms_seq2<<<BB, 1024, 0, stream>>>(matT, keepInit, keepFin);
  finalize<<<BB, 1024, 0, stream>>>(keepFin, score6k, boxes6k, out);
}

// Round 3
// 497.056 us; speedup vs baseline: 5.3207x; 1.9056x over previous
//
#include <hip/hip_runtime.h>
#include <hip/hip_bf16.h>
#include <math.h>

typedef unsigned int uint;
typedef unsigned long long u64;

#define BB 4
#define NN 100000
#define PRE 6000
#define POST 1000
#define NWRD 94          // 6000/64 rounded up
#define CAP 8192
#define ROWP 6016        // padded rows/cols

// ---- workspace layout (bytes) ----
constexpr size_t OFF_HDR   = 0;                                   // 16 uints
constexpr size_t OFF_H1    = 1024;
constexpr size_t OFF_H2    = OFF_H1  + (size_t)BB*65536*4;
constexpr size_t OFF_KEY   = OFF_H2  + (size_t)BB*65536*4;
constexpr size_t OFF_CAND  = OFF_KEY + (size_t)BB*NN*4;
constexpr size_t OFF_BOX   = OFF_CAND+ (size_t)BB*CAP*8;
constexpr size_t OFF_SCO   = OFF_BOX + (size_t)BB*ROWP*16;
constexpr size_t OFF_AREA  = OFF_SCO + (size_t)BB*ROWP*4;
constexpr size_t OFF_KINIT = OFF_AREA+ (size_t)BB*ROWP*4;
constexpr size_t OFF_KFIN  = OFF_KINIT+(size_t)BB*96*8;
constexpr size_t OFF_MAT   = OFF_KFIN +(size_t)BB*96*8;
// matC: [BB][NWRD rowwords][ROWP cols] u64; bit r of matC[b][g][col] =
// "row g*64+r suppresses col".  ~18.1 MB

__device__ __forceinline__ float clipf(float v, float hi) {
  return fminf(fmaxf(v, 0.0f), hi);
}

// ---------- zero hists + header ----------
__global__ void zero_ws(uint4* p, int n4) {
  int t = blockIdx.x * 256 + threadIdx.x;
  uint4 z; z.x = z.y = z.z = z.w = 0u;
  for (; t < n4; t += gridDim.x * 256) p[t] = z;
}

// ---------- pass 1: keys + level-0 histogram ----------
__global__ void keys_hist(const float4* __restrict__ props,
                          const float2* __restrict__ clsp,
                          uint* __restrict__ keyhi,
                          uint* __restrict__ hist1) {
  int b = blockIdx.y;
  int i = blockIdx.x * 256 + threadIdx.x;
  bool act = (i < NN);
  bool valid = false;
  uint kh = 0xFF800000u;     // key of -inf
  if (act) {
    float4 p = props[(size_t)b * NN + i];
    float x1 = clipf(p.x, 800.0f), y1 = clipf(p.y, 800.0f);
    float x2 = clipf(p.z, 800.0f), y2 = clipf(p.w, 800.0f);
    valid = ((x2 - x1) >= 16.0f) && ((y2 - y1) >= 16.0f);
    float s  = clsp[(size_t)b * NN + i].y;
    float sm = valid ? s : -INFINITY;
    uint u = __float_as_uint(sm);
    u = (u & 0x80000000u) ? ~u : (u | 0x80000000u);  // monotonic: ascending u == ascending score
    kh = ~u;                                          // ascending kh == DESCENDING score
    keyhi[(size_t)b * NN + i] = kh;
  }
  if (act && valid) atomicAdd(&hist1[(size_t)b * 65536 + (kh >> 16)], 1u);
  // invalid boxes all hit one bucket -> aggregate per wave to avoid hot-spot atomics
  u64 mb = __ballot(act && !valid);
  int lane = threadIdx.x & 63;
  if ((act && !valid) && lane == (__ffsll((long long)mb) - 1))
    atomicAdd(&hist1[(size_t)b * 65536 + 0xFF80u], (uint)__popcll(mb));
}

// ---------- histogram threshold scan (level 0 and 1) ----------
__global__ __launch_bounds__(1024) void scan_hist(const uint* __restrict__ hist,
                                                  uint* __restrict__ hdr, int level) {
  int b = blockIdx.x, tid = threadIdx.x;
  const uint* h = hist + (size_t)b * 65536;
  uint target = (level == 0) ? (uint)PRE : ((uint)PRE - hdr[4 + b]);
  uint base = tid * 64, s = 0;
  for (int k = 0; k < 64; ++k) s += h[base + k];
  __shared__ uint sc[1024];
  sc[tid] = s; __syncthreads();
  for (int off = 1; off < 1024; off <<= 1) {
    uint v = (tid >= off) ? sc[tid - off] : 0u;
    __syncthreads();
    sc[tid] += v;
    __syncthreads();
  }
  uint incl = sc[tid], excl = incl - s;
  if (excl < target && target <= incl) {   // unique owner thread
    uint c = excl, bucket = 0, clt = 0;
    for (int k = 0; k < 64; ++k) {
      uint hv = h[base + k];
      if (c < target && target <= c + hv) { bucket = base + k; clt = c; break; }
      c += hv;
    }
    if (level == 0) { hdr[0 + b] = bucket; hdr[4 + b] = clt; }
    else            { hdr[8 + b] = (hdr[0 + b] << 16) | (bucket & 0xFFFFu); }
  }
}

// ---------- pass 2: level-1 histogram of the boundary bucket ----------
__global__ void hist2_fill(const uint* __restrict__ keyhi,
                           const uint* __restrict__ hdr,
                           uint* __restrict__ hist2) {
  int b = blockIdx.y;
  int i = blockIdx.x * 256 + threadIdx.x;
  if (i >= NN) return;
  uint kh = keyhi[(size_t)b * NN + i];
  if ((kh >> 16) == hdr[0 + b])
    atomicAdd(&hist2[(size_t)b * 65536 + (kh & 0xFFFFu)], 1u);
}

// ---------- pass 3: compact candidates (all keys <= vstar) ----------
__global__ void compact(const uint* __restrict__ keyhi,
                        uint* __restrict__ hdr,
                        u64* __restrict__ cand) {
  int b = blockIdx.y;
  int i = blockIdx.x * 256 + threadIdx.x;
  int lane = threadIdx.x & 63;
  bool take = false; uint kh = 0;
  if (i < NN) {
    kh = keyhi[(size_t)b * NN + i];
    take = (kh <= hdr[8 + b]);
  }
  u64 mb = __ballot(take);
  if (mb) {
    int leader = __ffsll((long long)mb) - 1;
    uint base = 0;
    if (lane == leader) base = atomicAdd(&hdr[12 + b], (uint)__popcll(mb));
    base = __shfl(base, leader);
    if (take) {
      uint pos = base + (uint)__popcll(mb & ((1ull << lane) - 1ull));
      if (pos < CAP) cand[(size_t)b * CAP + pos] = ((u64)kh << 32) | (uint)i;
    }
  }
}

// ---------- pass 4: per-image bitonic sort + gather top-6000 ----------
__global__ __launch_bounds__(1024) void sort_gather(const u64* __restrict__ cand,
                                                    const uint* __restrict__ hdr,
                                                    const float4* __restrict__ props,
                                                    const float2* __restrict__ clsp,
                                                    float4* __restrict__ boxes6k,
                                                    float* __restrict__ score6k,
                                                    float* __restrict__ area6k,
                                                    u64* __restrict__ keepInit) {
  int b = blockIdx.x, tid = threadIdx.x;
  __shared__ u64 sh[CAP];          // 64 KiB
  int cntb = (int)hdr[12 + b]; if (cntb > CAP) cntb = CAP;
  for (int j = tid; j < CAP; j += 1024) sh[j] = (j < cntb) ? cand[(size_t)b * CAP + j] : ~0ull;
  __syncthreads();
  for (int k = 2; k <= CAP; k <<= 1) {
    for (int j = k >> 1; j > 0; j >>= 1) {
      for (int t = tid; t < CAP; t += 1024) {
        int ixj = t ^ j;
        if (ixj > t) {
          u64 a = sh[t], c = sh[ixj];
          bool up = ((t & k) == 0);
          if ((a > c) == up) { sh[t] = c; sh[ixj] = a; }
        }
      }
      __syncthreads();
    }
  }
  int lane = tid & 63;
  for (int basej = 0; basej < 6144; basej += 1024) {
    int j = basej + tid;
    bool valid = false; float sc = -INFINITY, ar = 0.0f;
    float4 bx; bx.x = bx.y = bx.z = bx.w = 0.0f;
    if (j < PRE && j < cntb) {
      uint idx = (uint)(sh[j] & 0xFFFFFFFFull);
      float4 p = props[(size_t)b * NN + idx];
      float x1 = clipf(p.x, 800.0f), y1 = clipf(p.y, 800.0f);
      float x2 = clipf(p.z, 800.0f), y2 = clipf(p.w, 800.0f);
      float w = x2 - x1, h = y2 - y1;
      valid = (w >= 16.0f) && (h >= 16.0f);
      sc = clsp[(size_t)b * NN + idx].y;
      bx.x = x1; bx.y = y1; bx.z = x2; bx.w = y2;
      ar = fmaxf(x2 - x1, 0.0f) * fmaxf(y2 - y1, 0.0f);
    }
    if (j < ROWP) {
      boxes6k[(size_t)b * ROWP + j] = bx;
      score6k[(size_t)b * ROWP + j] = sc;
      area6k [(size_t)b * ROWP + j] = ar;
    }
    u64 mb = __ballot(valid);
    if (lane == 0) keepInit[(size_t)b * 96 + (j >> 6)] = ~mb;   // removed-init = ~valid
  }
}

// ---------- pass 5: suppression matrix, suppressor-row-packed ----------
// matC[b][gb][col]: bit r = "row gb*64+r suppresses col" (row < col only).
// Lane = col -> stores coalesced; nms_seq2 reads coalesced too.
__global__ __launch_bounds__(64) void nms_matrix(const float4* __restrict__ boxes6k,
                                                 const float* __restrict__ area6k,
                                                 u64* __restrict__ matC) {
  int cb = blockIdx.x, gb = blockIdx.y, b = blockIdx.z;
  if (cb < gb) return;
  __shared__ float4 rbox[64];
  __shared__ float  rar[64];
  int t = threadIdx.x;
  rbox[t] = boxes6k[(size_t)b * ROWP + gb * 64 + t];
  rar[t]  = area6k [(size_t)b * ROWP + gb * 64 + t];
  __syncthreads();
  int col = cb * 64 + t;
  float4 c = boxes6k[(size_t)b * ROWP + col];
  float ca = area6k[(size_t)b * ROWP + col];
  int rbase = gb * 64;
  u64 bits = 0;
  #pragma unroll 8
  for (int r = 0; r < 64; ++r) {
    int row = rbase + r;
    if (row < col) {
      float4 rb = rbox[r];
      float xx1 = fmaxf(rb.x, c.x), yy1 = fmaxf(rb.y, c.y);
      float xx2 = fminf(rb.z, c.z), yy2 = fminf(rb.w, c.w);
      float inter = fmaxf(xx2 - xx1, 0.0f) * fmaxf(yy2 - yy1, 0.0f);
      float un = rar[r] + ca - inter;
      float iou = inter / fmaxf(un, 1e-9f);
      if (iou > 0.7f) bits |= (1ull << r);
    }
  }
  matC[((size_t)b * NWRD + gb) * ROWP + col] = bits;
}

// ---------- pass 6: group-sequential greedy NMS, ballot-based ----------
// Per group g: P1 = ballot-fixpoint diagonal resolve (wave 0, no shuffles);
// P2 = per-lane AND + ballot fold into REM (zero cross-lane reduces).
// 2-deep double-buffered prefetch via loop unroll-by-2 (NWRD is even).
__global__ __launch_bounds__(1024) void nms_seq2(const u64* __restrict__ matC,
                                                 const u64* __restrict__ keepInit,
                                                 u64* __restrict__ keepFin) {
  int b = blockIdx.x;
  int tid = threadIdx.x, lane = tid & 63, W = tid >> 6;
  __shared__ u64 REM[96];
  __shared__ u64 SHA;
  if (tid < 96) REM[tid] = (tid < NWRD) ? keepInit[(size_t)b * 96 + tid] : ~0ull;
  const u64* M = matC + (size_t)b * NWRD * ROWP;

  u64 pfA[6], pfB[6], dA = 0, dB = 0;
  // prologue: group 0 -> A
  #pragma unroll
  for (int j = 0; j < 6; ++j) {
    int w = 1 + W + 16 * j;
    pfA[j] = (w < NWRD) ? M[(size_t)w * 64 + lane] : 0ull;
  }
  if (W == 0) dA = M[lane];
  __syncthreads();

  #pragma unroll 1
  for (int g = 0; g < NWRD; g += 2) {
    // ===== group g (current: A), prefetch g+1 -> B =====
    {
      int gn = g + 1;                       // always < NWRD (NWRD even)
      #pragma unroll
      for (int j = 0; j < 6; ++j) {
        int w = gn + 1 + W + 16 * j;
        pfB[j] = (w < NWRD) ? M[(size_t)gn * ROWP + (size_t)w * 64 + lane] : 0ull;
      }
      if (W == 0) dB = M[(size_t)gn * ROWP + (size_t)gn * 64 + lane];

      if (W == 0) {
        u64 validM = ~REM[g];
        bool inU = (validM >> lane) & 1ull;
        u64 U = __ballot(inU);
        u64 A = 0ull;
        while (U) {
          u64 newA = __ballot(inU && ((dA & U) == 0ull));  // no undecided suppressor
          A |= newA;
          bool deadNew = (((newA >> lane) & 1ull) != 0ull) || ((dA & newA) != 0ull);
          u64 rm = __ballot(inU && deadNew);
          U &= ~rm;
          inU = inU && !deadNew;
        }
        if (lane == 0) { SHA = A; keepFin[(size_t)b * 96 + g] = A; }
      }
      __syncthreads();
      u64 A = SHA;
      #pragma unroll
      for (int j = 0; j < 6; ++j) {
        int w = g + 1 + W + 16 * j;
        if (w < NWRD) {
          u64 bits = __ballot((pfA[j] & A) != 0ull);
          if (lane == 0) REM[w] |= bits;
        }
      }
      __syncthreads();
    }
    // ===== group g+1 (current: B), prefetch g+2 -> A =====
    {
      int go = g + 1;
      int gn = (g + 2 < NWRD) ? (g + 2) : (NWRD - 1);
      #pragma unroll
      for (int j = 0; j < 6; ++j) {
        int w = gn + 1 + W + 16 * j;
        pfA[j] = (w < NWRD) ? M[(size_t)gn * ROWP + (size_t)w * 64 + lane] : 0ull;
      }
      if (W == 0) dA = M[(size_t)gn * ROWP + (size_t)gn * 64 + lane];

      if (W == 0) {
        u64 validM = ~REM[go];
        bool inU = (validM >> lane) & 1ull;
        u64 U = __ballot(inU);
        u64 A = 0ull;
        while (U) {
          u64 newA = __ballot(inU && ((dB & U) == 0ull));
          A |= newA;
          bool deadNew = (((newA >> lane) & 1ull) != 0ull) || ((dB & newA) != 0ull);
          u64 rm = __ballot(inU && deadNew);
          U &= ~rm;
          inU = inU && !deadNew;
        }
        if (lane == 0) { SHA = A; keepFin[(size_t)b * 96 + go] = A; }
      }
      __syncthreads();
      u64 A = SHA;
      #pragma unroll
      for (int j = 0; j < 6; ++j) {
        int w = go + 1 + W + 16 * j;
        if (w < NWRD) {
          u64 bits = __ballot((pfB[j] & A) != 0ull);
          if (lane == 0) REM[w] |= bits;
        }
      }
      __syncthreads();
    }
  }
}

// ---------- pass 7: finalize (rank kept, emit first 1000) ----------
__global__ __launch_bounds__(1024) void finalize(const u64* __restrict__ keepFin,
                                                 const float* __restrict__ score6k,
                                                 const float4* __restrict__ boxes6k,
                                                 float* __restrict__ out) {
  int b = blockIdx.x, tid = threadIdx.x;
  __shared__ u64 kw[NWRD];
  __shared__ uint pre[NWRD + 1];
  if (tid < NWRD) kw[tid] = keepFin[(size_t)b * 96 + tid];
  __syncthreads();
  if (tid == 0) {
    uint c = 0;
    for (int w = 0; w < NWRD; ++w) { pre[w] = c; c += (uint)__popcll(kw[w]); }
    pre[NWRD] = c;
  }
  __syncthreads();
  for (int q = tid; q < POST; q += 1024) out[(size_t)b * POST + q] = 0.0f;
  for (int t = tid; t < POST * 4; t += 1024) out[(size_t)BB * POST + (size_t)b * POST * 4 + t] = 0.0f;
  __syncthreads();
  for (int j = tid; j < PRE; j += 1024) {
    int w = j >> 6, bit = j & 63;
    u64 word = kw[w];
    if ((word >> bit) & 1ull) {
      uint rank = pre[w] + (uint)__popcll(word & ((1ull << bit) - 1ull));
      if (rank < POST) {
        out[(size_t)b * POST + rank] = score6k[(size_t)b * ROWP + j];
        float4 bx = boxes6k[(size_t)b * ROWP + j];
        float* o = out + (size_t)BB * POST + ((size_t)b * POST + rank) * 4;
        o[0] = bx.x; o[1] = bx.y; o[2] = bx.z; o[3] = bx.w;
      }
    }
  }
}

extern "C" void kernel_launch(void* const* d_in, const int* in_sizes, int n_in,
                              void* d_out, int out_size, void* d_ws, size_t ws_size,
                              hipStream_t stream) {
  const float4* props = (const float4*)d_in[0];
  const float2* clsp  = (const float2*)d_in[1];
  float* out = (float*)d_out;
  char* ws = (char*)d_ws;

  uint*   hdr     = (uint*)(ws + OFF_HDR);
  uint*   hist1   = (uint*)(ws + OFF_H1);
  uint*   hist2   = (uint*)(ws + OFF_H2);
  uint*   keyhi   = (uint*)(ws + OFF_KEY);
  u64*    cand    = (u64*) (ws + OFF_CAND);
  float4* boxes6k = (float4*)(ws + OFF_BOX);
  float*  score6k = (float*)(ws + OFF_SCO);
  float*  area6k  = (float*)(ws + OFF_AREA);
  u64*    keepInit= (u64*) (ws + OFF_KINIT);
  u64*    keepFin = (u64*) (ws + OFF_KFIN);
  u64*    matC    = (u64*) (ws + OFF_MAT);

  // zero header + both histograms
  int n4 = (int)((1024 + 2 * (size_t)BB * 65536 * 4) / 16);
  zero_ws<<<512, 256, 0, stream>>>((uint4*)ws, n4);

  dim3 gN((NN + 255) / 256, BB);
  keys_hist<<<gN, 256, 0, stream>>>(props, clsp, keyhi, hist1);
  scan_hist<<<BB, 1024, 0, stream>>>(hist1, hdr, 0);
  hist2_fill<<<gN, 256, 0, stream>>>(keyhi, hdr, hist2);
  scan_hist<<<BB, 1024, 0, stream>>>(hist2, hdr, 1);
  compact<<<gN, 256, 0, stream>>>(keyhi, hdr, cand);
  sort_gather<<<BB, 1024, 0, stream>>>(cand, hdr, props, clsp, boxes6k, score6k, area6k, keepInit);
  nms_matrix<<<dim3(NWRD, NWRD, BB), 64, 0, stream>>>(boxes6k, area6k, matC);
  nms_seq2<<<BB, 1024, 0, stream>>>(matC, keepInit, keepFin);
  finalize<<<BB, 1024, 0, stream>>>(keepFin, score6k, boxes6k, out);
}

// Round 4
// 375.241 us; speedup vs baseline: 7.0479x; 1.3246x over previous
//
#include <hip/hip_runtime.h>
#include <hip/hip_bf16.h>
#include <math.h>

typedef unsigned int uint;
typedef unsigned long long u64;

#define BB 4
#define NN 100000
#define PRE 6000
#define POST 1000
#define NWRD 94          // 6000/64 rounded up
#define SCAP 8192        // bucketed/sorted capacity
#define ROWP 6016        // padded rows/cols

// ---- workspace layout (bytes) ----
constexpr size_t OFF_HDR   = 0;                                    // 16 uints: t1[4], limit[4]
constexpr size_t OFF_H1    = 1024;                                 // hist1: BB*65536*4 = 1MB
constexpr size_t OFF_BASE  = OFF_H1  + (size_t)BB*65536*4;         // base:  1MB
constexpr size_t OFF_KEY   = OFF_BASE+ (size_t)BB*65536*4;         // keyhi: BB*NN*4
constexpr size_t OFF_BUCK  = OFF_KEY + (size_t)BB*NN*4;            // BB*SCAP*8
constexpr size_t OFF_SORT  = OFF_BUCK+ (size_t)BB*SCAP*8;          // BB*SCAP*8
constexpr size_t OFF_BOX   = OFF_SORT+ (size_t)BB*SCAP*8;
constexpr size_t OFF_SCO   = OFF_BOX + (size_t)BB*ROWP*16;
constexpr size_t OFF_AREA  = OFF_SCO + (size_t)BB*ROWP*4;
constexpr size_t OFF_KINIT = OFF_AREA+ (size_t)BB*ROWP*4;
constexpr size_t OFF_KFIN  = OFF_KINIT+(size_t)BB*96*8;
constexpr size_t OFF_MAT   = OFF_KFIN +(size_t)BB*96*8;
// matC: [BB][NWRD][ROWP] u64 ~= 18.1 MB ; total ~= 22.7 MB

__device__ __forceinline__ float clipf(float v, float hi) {
  return fminf(fmaxf(v, 0.0f), hi);
}

// ---------- zero hdr+hist1, fill sorted with sentinel ----------
__global__ void zero_fill(uint4* zp, int nz4, uint4* fp, int nf4) {
  int t = blockIdx.x * 256 + threadIdx.x;
  uint4 z; z.x = z.y = z.z = z.w = 0u;
  uint4 f; f.x = f.y = f.z = f.w = 0xFFFFFFFFu;
  for (int i = t; i < nz4; i += gridDim.x * 256) zp[i] = z;
  for (int i = t; i < nf4; i += gridDim.x * 256) fp[i] = f;
}

// ---------- pass 1: keys + histogram over high-16 of key ----------
__global__ void keys_hist(const float4* __restrict__ props,
                          const float2* __restrict__ clsp,
                          uint* __restrict__ keyhi,
                          uint* __restrict__ hist1) {
  int b = blockIdx.y;
  int i = blockIdx.x * 256 + threadIdx.x;
  bool act = (i < NN);
  bool valid = false;
  uint kh = 0xFF800000u;     // key of -inf
  if (act) {
    float4 p = props[(size_t)b * NN + i];
    float x1 = clipf(p.x, 800.0f), y1 = clipf(p.y, 800.0f);
    float x2 = clipf(p.z, 800.0f), y2 = clipf(p.w, 800.0f);
    valid = ((x2 - x1) >= 16.0f) && ((y2 - y1) >= 16.0f);
    float s  = clsp[(size_t)b * NN + i].y;
    float sm = valid ? s : -INFINITY;
    uint u = __float_as_uint(sm);
    u = (u & 0x80000000u) ? ~u : (u | 0x80000000u);  // monotonic: ascending u == ascending score
    kh = ~u;                                          // ascending kh == DESCENDING score
    keyhi[(size_t)b * NN + i] = kh;
  }
  if (act && valid) atomicAdd(&hist1[(size_t)b * 65536 + (kh >> 16)], 1u);
  // invalid boxes all hit one bucket -> aggregate per wave to avoid hot-spot atomics
  u64 mb = __ballot(act && !valid);
  int lane = threadIdx.x & 63;
  if ((act && !valid) && lane == (__ffsll((long long)mb) - 1))
    atomicAdd(&hist1[(size_t)b * 65536 + 0xFF80u], (uint)__popcll(mb));
}

// ---------- pass 2: exclusive scan of hist1 -> base[]; find boundary ----------
__global__ __launch_bounds__(1024) void scan_base(const uint* __restrict__ hist,
                                                  uint* __restrict__ base,
                                                  uint* __restrict__ hdr) {
  int b = blockIdx.x, tid = threadIdx.x;
  const uint* h = hist + (size_t)b * 65536;
  uint* bs = base + (size_t)b * 65536;
  uint loc[64]; uint s = 0;
  #pragma unroll
  for (int k = 0; k < 64; ++k) { loc[k] = h[tid * 64 + k]; s += loc[k]; }
  __shared__ uint sc[1024];
  sc[tid] = s; __syncthreads();
  for (int off = 1; off < 1024; off <<= 1) {
    uint v = (tid >= off) ? sc[tid - off] : 0u;
    __syncthreads();
    sc[tid] += v;
    __syncthreads();
  }
  uint incl = sc[tid], excl = incl - s;
  uint total = sc[1023];
  uint target = total < (uint)PRE ? total : (uint)PRE;
  if (target > 0 && excl < target && target <= incl) {   // unique owner thread
    uint c = excl;
    #pragma unroll 1
    for (int k = 0; k < 64; ++k) {
      uint hv = loc[k];
      if (c < target && target <= c + hv) {
        hdr[0 + b] = (uint)(tid * 64 + k);   // t1 boundary bucket
        hdr[4 + b] = c + hv;                 // limit = cumulative through t1
        break;
      }
      c += hv;
    }
  }
  uint run = excl;
  #pragma unroll
  for (int k = 0; k < 64; ++k) { bs[tid * 64 + k] = run; run += loc[k]; }
}

// ---------- pass 3: scatter elems of buckets <= t1 into bucket slots ----------
// base[bkt] is advanced by the bucket's full size (restored in rank_write).
__global__ void bucket_scatter(const uint* __restrict__ keyhi,
                               uint* __restrict__ base,
                               const uint* __restrict__ hdr,
                               u64* __restrict__ buck) {
  int b = blockIdx.y;
  int i = blockIdx.x * 256 + threadIdx.x;
  if (i >= NN) return;
  uint kh = keyhi[(size_t)b * NN + i];
  if ((kh >> 16) <= hdr[0 + b]) {
    uint pos = atomicAdd(&base[(size_t)b * 65536 + (kh >> 16)], 1u);
    if (pos < SCAP) buck[(size_t)b * SCAP + pos] = ((u64)kh << 32) | (uint)i;
  }
}

// ---------- pass 4: exact rank within bucket -> scatter to sorted[] ----------
__global__ void rank_write(const u64* __restrict__ buck,
                           const uint* __restrict__ base,
                           const uint* __restrict__ hist,
                           const uint* __restrict__ hdr,
                           u64* __restrict__ sorted) {
  int b = blockIdx.y;
  int s = blockIdx.x * 256 + threadIdx.x;
  uint limit = hdr[4 + b];
  if (s >= (int)limit) return;
  u64 v = buck[(size_t)b * SCAP + s];
  uint bkt = (uint)(v >> 48);
  uint cnt = hist[(size_t)b * 65536 + bkt];
  uint b0 = base[(size_t)b * 65536 + bkt] - cnt;   // restore pre-scatter base
  uint r = b0;
  for (uint m = 0; m < cnt; ++m) {
    u64 w = buck[(size_t)b * SCAP + b0 + m];
    r += (w < v) ? 1u : 0u;                        // (key,idx) stable order
  }
  if (r < (uint)PRE) sorted[(size_t)b * SCAP + r] = v;
}

// ---------- pass 5: gather top-6000 boxes/scores/areas + keepInit ----------
__global__ __launch_bounds__(1024) void gather6k(const u64* __restrict__ sorted,
                                                 const float4* __restrict__ props,
                                                 const float2* __restrict__ clsp,
                                                 float4* __restrict__ boxes6k,
                                                 float* __restrict__ score6k,
                                                 float* __restrict__ area6k,
                                                 u64* __restrict__ keepInit) {
  int b = blockIdx.y;
  int j = blockIdx.x * 1024 + threadIdx.x;    // 0..6143
  int lane = threadIdx.x & 63;
  u64 v = sorted[(size_t)b * SCAP + j];
  bool has = (j < PRE) && (v != ~0ull);
  bool valid = false; float sc = -INFINITY, ar = 0.0f;
  float4 bx; bx.x = bx.y = bx.z = bx.w = 0.0f;
  if (has) {
    uint idx = (uint)(v & 0xFFFFFFFFull);
    float4 p = props[(size_t)b * NN + idx];
    float x1 = clipf(p.x, 800.0f), y1 = clipf(p.y, 800.0f);
    float x2 = clipf(p.z, 800.0f), y2 = clipf(p.w, 800.0f);
    float w = x2 - x1, h = y2 - y1;
    valid = (w >= 16.0f) && (h >= 16.0f);
    sc = clsp[(size_t)b * NN + idx].y;
    bx.x = x1; bx.y = y1; bx.z = x2; bx.w = y2;
    ar = fmaxf(w, 0.0f) * fmaxf(h, 0.0f);
  }
  if (j < ROWP) {
    boxes6k[(size_t)b * ROWP + j] = bx;
    score6k[(size_t)b * ROWP + j] = sc;
    area6k [(size_t)b * ROWP + j] = ar;
  }
  u64 mb = __ballot(valid);
  if (lane == 0) keepInit[(size_t)b * 96 + (j >> 6)] = ~mb;   // removed-init = ~valid
}

// ---------- pass 6: suppression matrix, suppressor-row-packed ----------
// matC[b][gb][col]: bit r = "row gb*64+r suppresses col" (row < col only).
__global__ __launch_bounds__(64) void nms_matrix(const float4* __restrict__ boxes6k,
                                                 const float* __restrict__ area6k,
                                                 u64* __restrict__ matC) {
  int cb = blockIdx.x, gb = blockIdx.y, b = blockIdx.z;
  if (cb < gb) return;
  __shared__ float4 rbox[64];
  __shared__ float  rar[64];
  int t = threadIdx.x;
  rbox[t] = boxes6k[(size_t)b * ROWP + gb * 64 + t];
  rar[t]  = area6k [(size_t)b * ROWP + gb * 64 + t];
  __syncthreads();
  int col = cb * 64 + t;
  float4 c = boxes6k[(size_t)b * ROWP + col];
  float ca = area6k[(size_t)b * ROWP + col];
  int rbase = gb * 64;
  u64 bits = 0;
  #pragma unroll 8
  for (int r = 0; r < 64; ++r) {
    int row = rbase + r;
    if (row < col) {
      float4 rb = rbox[r];
      float xx1 = fmaxf(rb.x, c.x), yy1 = fmaxf(rb.y, c.y);
      float xx2 = fminf(rb.z, c.z), yy2 = fminf(rb.w, c.w);
      float inter = fmaxf(xx2 - xx1, 0.0f) * fmaxf(yy2 - yy1, 0.0f);
      float un = rar[r] + ca - inter;
      float iou = inter / fmaxf(un, 1e-9f);
      if (iou > 0.7f) bits |= (1ull << r);
    }
  }
  matC[((size_t)b * NWRD + gb) * ROWP + col] = bits;
}

// ---------- pass 7: group-sequential greedy NMS, ballot-based ----------
__global__ __launch_bounds__(1024) void nms_seq2(const u64* __restrict__ matC,
                                                 const u64* __restrict__ keepInit,
                                                 u64* __restrict__ keepFin) {
  int b = blockIdx.x;
  int tid = threadIdx.x, lane = tid & 63, W = tid >> 6;
  __shared__ u64 REM[96];
  __shared__ u64 SHA;
  if (tid < 96) REM[tid] = (tid < NWRD) ? keepInit[(size_t)b * 96 + tid] : ~0ull;
  const u64* M = matC + (size_t)b * NWRD * ROWP;

  u64 pfA[6], pfB[6], dA = 0, dB = 0;
  // prologue: group 0 -> A
  #pragma unroll
  for (int j = 0; j < 6; ++j) {
    int w = 1 + W + 16 * j;
    pfA[j] = (w < NWRD) ? M[(size_t)w * 64 + lane] : 0ull;
  }
  if (W == 0) dA = M[lane];
  __syncthreads();

  #pragma unroll 1
  for (int g = 0; g < NWRD; g += 2) {
    // ===== group g (current: A), prefetch g+1 -> B =====
    {
      int gn = g + 1;                       // always < NWRD (NWRD even)
      #pragma unroll
      for (int j = 0; j < 6; ++j) {
        int w = gn + 1 + W + 16 * j;
        pfB[j] = (w < NWRD) ? M[(size_t)gn * ROWP + (size_t)w * 64 + lane] : 0ull;
      }
      if (W == 0) dB = M[(size_t)gn * ROWP + (size_t)gn * 64 + lane];

      if (W == 0) {
        u64 validM = ~REM[g];
        bool inU = (validM >> lane) & 1ull;
        u64 U = __ballot(inU);
        u64 A = 0ull;
        while (U) {
          u64 newA = __ballot(inU && ((dA & U) == 0ull));  // no undecided suppressor
          A |= newA;
          bool deadNew = (((newA >> lane) & 1ull) != 0ull) || ((dA & newA) != 0ull);
          u64 rm = __ballot(inU && deadNew);
          U &= ~rm;
          inU = inU && !deadNew;
        }
        if (lane == 0) { SHA = A; keepFin[(size_t)b * 96 + g] = A; }
      }
      __syncthreads();
      u64 A = SHA;
      #pragma unroll
      for (int j = 0; j < 6; ++j) {
        int w = g + 1 + W + 16 * j;
        if (w < NWRD) {
          u64 bits = __ballot((pfA[j] & A) != 0ull);
          if (lane == 0) REM[w] |= bits;
        }
      }
      __syncthreads();
    }
    // ===== group g+1 (current: B), prefetch g+2 -> A =====
    {
      int go = g + 1;
      int gn = (g + 2 < NWRD) ? (g + 2) : (NWRD - 1);
      #pragma unroll
      for (int j = 0; j < 6; ++j) {
        int w = gn + 1 + W + 16 * j;
        pfA[j] = (w < NWRD) ? M[(size_t)gn * ROWP + (size_t)w * 64 + lane] : 0ull;
      }
      if (W == 0) dA = M[(size_t)gn * ROWP + (size_t)gn * 64 + lane];

      if (W == 0) {
        u64 validM = ~REM[go];
        bool inU = (validM >> lane) & 1ull;
        u64 U = __ballot(inU);
        u64 A = 0ull;
        while (U) {
          u64 newA = __ballot(inU && ((dB & U) == 0ull));
          A |= newA;
          bool deadNew = (((newA >> lane) & 1ull) != 0ull) || ((dB & newA) != 0ull);
          u64 rm = __ballot(inU && deadNew);
          U &= ~rm;
          inU = inU && !deadNew;
        }
        if (lane == 0) { SHA = A; keepFin[(size_t)b * 96 + go] = A; }
      }
      __syncthreads();
      u64 A = SHA;
      #pragma unroll
      for (int j = 0; j < 6; ++j) {
        int w = go + 1 + W + 16 * j;
        if (w < NWRD) {
          u64 bits = __ballot((pfB[j] & A) != 0ull);
          if (lane == 0) REM[w] |= bits;
        }
      }
      __syncthreads();
    }
  }
}

// ---------- pass 8: finalize (rank kept, emit first 1000) ----------
__global__ __launch_bounds__(1024) void finalize(const u64* __restrict__ keepFin,
                                                 const float* __restrict__ score6k,
                                                 const float4* __restrict__ boxes6k,
                                                 float* __restrict__ out) {
  int b = blockIdx.x, tid = threadIdx.x;
  __shared__ u64 kw[NWRD];
  __shared__ uint pre[NWRD + 1];
  if (tid < NWRD) kw[tid] = keepFin[(size_t)b * 96 + tid];
  __syncthreads();
  if (tid == 0) {
    uint c = 0;
    for (int w = 0; w < NWRD; ++w) { pre[w] = c; c += (uint)__popcll(kw[w]); }
    pre[NWRD] = c;
  }
  __syncthreads();
  for (int q = tid; q < POST; q += 1024) out[(size_t)b * POST + q] = 0.0f;
  for (int t = tid; t < POST * 4; t += 1024) out[(size_t)BB * POST + (size_t)b * POST * 4 + t] = 0.0f;
  __syncthreads();
  for (int j = tid; j < PRE; j += 1024) {
    int w = j >> 6, bit = j & 63;
    u64 word = kw[w];
    if ((word >> bit) & 1ull) {
      uint rank = pre[w] + (uint)__popcll(word & ((1ull << bit) - 1ull));
      if (rank < POST) {
        out[(size_t)b * POST + rank] = score6k[(size_t)b * ROWP + j];
        float4 bx = boxes6k[(size_t)b * ROWP + j];
        float* o = out + (size_t)BB * POST + ((size_t)b * POST + rank) * 4;
        o[0] = bx.x; o[1] = bx.y; o[2] = bx.z; o[3] = bx.w;
      }
    }
  }
}

extern "C" void kernel_launch(void* const* d_in, const int* in_sizes, int n_in,
                              void* d_out, int out_size, void* d_ws, size_t ws_size,
                              hipStream_t stream) {
  const float4* props = (const float4*)d_in[0];
  const float2* clsp  = (const float2*)d_in[1];
  float* out = (float*)d_out;
  char* ws = (char*)d_ws;

  uint*   hdr     = (uint*)(ws + OFF_HDR);
  uint*   hist1   = (uint*)(ws + OFF_H1);
  uint*   base    = (uint*)(ws + OFF_BASE);
  uint*   keyhi   = (uint*)(ws + OFF_KEY);
  u64*    buck    = (u64*) (ws + OFF_BUCK);
  u64*    sorted  = (u64*) (ws + OFF_SORT);
  float4* boxes6k = (float4*)(ws + OFF_BOX);
  float*  score6k = (float*)(ws + OFF_SCO);
  float*  area6k  = (float*)(ws + OFF_AREA);
  u64*    keepInit= (u64*) (ws + OFF_KINIT);
  u64*    keepFin = (u64*) (ws + OFF_KFIN);
  u64*    matC    = (u64*) (ws + OFF_MAT);

  // zero hdr+hist1; fill sorted[] with ~0 sentinel
  int nz4 = (int)((1024 + (size_t)BB * 65536 * 4) / 16);
  int nf4 = (int)(((size_t)BB * SCAP * 8) / 16);
  zero_fill<<<512, 256, 0, stream>>>((uint4*)ws, nz4, (uint4*)(ws + OFF_SORT), nf4);

  dim3 gN((NN + 255) / 256, BB);
  keys_hist<<<gN, 256, 0, stream>>>(props, clsp, keyhi, hist1);
  scan_base<<<BB, 1024, 0, stream>>>(hist1, base, hdr);
  bucket_scatter<<<gN, 256, 0, stream>>>(keyhi, base, hdr, buck);
  rank_write<<<dim3(SCAP / 256, BB), 256, 0, stream>>>(buck, base, hist1, hdr, sorted);
  gather6k<<<dim3(6, BB), 1024, 0, stream>>>(sorted, props, clsp, boxes6k, score6k, area6k, keepInit);
  nms_matrix<<<dim3(NWRD, NWRD, BB), 64, 0, stream>>>(boxes6k, area6k, matC);
  nms_seq2<<<BB, 1024, 0, stream>>>(matC, keepInit, keepFin);
  finalize<<<BB, 1024, 0, stream>>>(keepFin, score6k, boxes6k, out);
}

// Round 5
// 364.699 us; speedup vs baseline: 7.2516x; 1.0289x over previous
//
#include <hip/hip_runtime.h>
#include <hip/hip_bf16.h>
#include <math.h>

typedef unsigned int uint;
typedef unsigned long long u64;

#define BB 4
#define NN 100000
#define PRE 6000
#define POST 1000
#define NWRD 94          // 6000/64 rounded up
#define SCAP 8192        // bucketed/sorted capacity
#define ROWP 6016        // padded rows/cols

// ---- workspace layout (bytes) ----
constexpr size_t OFF_HDR   = 0;                                    // 16 uints: t1[4], limit[4]
constexpr size_t OFF_H1    = 1024;                                 // hist1: BB*65536*4 = 1MB
constexpr size_t OFF_BASE  = OFF_H1  + (size_t)BB*65536*4;         // base:  1MB
constexpr size_t OFF_KEY   = OFF_BASE+ (size_t)BB*65536*4;         // keyhi: BB*NN*4
constexpr size_t OFF_BUCK  = OFF_KEY + (size_t)BB*NN*4;            // BB*SCAP*8
constexpr size_t OFF_SORT  = OFF_BUCK+ (size_t)BB*SCAP*8;          // BB*SCAP*8
constexpr size_t OFF_BOX   = OFF_SORT+ (size_t)BB*SCAP*8;
constexpr size_t OFF_SCO   = OFF_BOX + (size_t)BB*ROWP*16;
constexpr size_t OFF_AREA  = OFF_SCO + (size_t)BB*ROWP*4;
constexpr size_t OFF_KINIT = OFF_AREA+ (size_t)BB*ROWP*4;
constexpr size_t OFF_MAT   = OFF_KINIT+(size_t)BB*96*8;
// matC: [BB][NWRD][ROWP] u64 ~= 18.1 MB ; total ~= 22.7 MB

__device__ __forceinline__ float clipf(float v, float hi) {
  return fminf(fmaxf(v, 0.0f), hi);
}

// ---------- zero hdr+hist1, fill sorted with sentinel ----------
__global__ void zero_fill(uint4* zp, int nz4, uint4* fp, int nf4) {
  int t = blockIdx.x * 256 + threadIdx.x;
  uint4 z; z.x = z.y = z.z = z.w = 0u;
  uint4 f; f.x = f.y = f.z = f.w = 0xFFFFFFFFu;
  for (int i = t; i < nz4; i += gridDim.x * 256) zp[i] = z;
  for (int i = t; i < nf4; i += gridDim.x * 256) fp[i] = f;
}

// ---------- pass 1: keys + histogram over high-16 of key ----------
__global__ void keys_hist(const float4* __restrict__ props,
                          const float2* __restrict__ clsp,
                          uint* __restrict__ keyhi,
                          uint* __restrict__ hist1) {
  int b = blockIdx.y;
  int i = blockIdx.x * 256 + threadIdx.x;
  bool act = (i < NN);
  bool valid = false;
  uint kh = 0xFF800000u;     // key of -inf
  if (act) {
    float4 p = props[(size_t)b * NN + i];
    float x1 = clipf(p.x, 800.0f), y1 = clipf(p.y, 800.0f);
    float x2 = clipf(p.z, 800.0f), y2 = clipf(p.w, 800.0f);
    valid = ((x2 - x1) >= 16.0f) && ((y2 - y1) >= 16.0f);
    float s  = clsp[(size_t)b * NN + i].y;
    float sm = valid ? s : -INFINITY;
    uint u = __float_as_uint(sm);
    u = (u & 0x80000000u) ? ~u : (u | 0x80000000u);  // monotonic: ascending u == ascending score
    kh = ~u;                                          // ascending kh == DESCENDING score
    keyhi[(size_t)b * NN + i] = kh;
  }
  if (act && valid) atomicAdd(&hist1[(size_t)b * 65536 + (kh >> 16)], 1u);
  // invalid boxes all hit one bucket -> aggregate per wave to avoid hot-spot atomics
  u64 mb = __ballot(act && !valid);
  int lane = threadIdx.x & 63;
  if ((act && !valid) && lane == (__ffsll((long long)mb) - 1))
    atomicAdd(&hist1[(size_t)b * 65536 + 0xFF80u], (uint)__popcll(mb));
}

// ---------- pass 2: exclusive scan of hist1 -> base[]; find boundary ----------
__global__ __launch_bounds__(1024) void scan_base(const uint* __restrict__ hist,
                                                  uint* __restrict__ base,
                                                  uint* __restrict__ hdr) {
  int b = blockIdx.x, tid = threadIdx.x, lane = tid & 63, W = tid >> 6;
  const uint* h = hist + (size_t)b * 65536;
  uint* bs = base + (size_t)b * 65536;
  uint loc[64]; uint s = 0;
  #pragma unroll
  for (int k = 0; k < 64; ++k) { loc[k] = h[tid * 64 + k]; s += loc[k]; }
  // inclusive wave scan (no barriers)
  uint ps = s;
  #pragma unroll
  for (int off = 1; off < 64; off <<= 1) {
    uint v = __shfl_up(ps, off);
    if (lane >= off) ps += v;
  }
  __shared__ uint wsum[16];
  if (lane == 63) wsum[W] = ps;
  __syncthreads();
  if (tid < 16) {
    uint v = wsum[tid], pv = v;
    #pragma unroll
    for (int off = 1; off < 16; off <<= 1) {
      uint t = __shfl_up(pv, off, 16);
      if (tid >= off) pv += t;
    }
    wsum[tid] = pv;   // inclusive over waves
  }
  __syncthreads();
  uint wbase = (W > 0) ? wsum[W - 1] : 0u;
  uint incl = wbase + ps, excl = incl - s;
  uint total = wsum[15];
  uint target = total < (uint)PRE ? total : (uint)PRE;
  if (target > 0 && excl < target && target <= incl) {   // unique owner thread
    uint c = excl;
    #pragma unroll 1
    for (int k = 0; k < 64; ++k) {
      uint hv = loc[k];
      if (c < target && target <= c + hv) {
        hdr[0 + b] = (uint)(tid * 64 + k);   // t1 boundary bucket
        hdr[4 + b] = c + hv;                 // limit = cumulative through t1
        break;
      }
      c += hv;
    }
  }
  uint run = excl;
  #pragma unroll
  for (int k = 0; k < 64; ++k) { bs[tid * 64 + k] = run; run += loc[k]; }
}

// ---------- pass 3: scatter elems of buckets <= t1 into bucket slots ----------
__global__ void bucket_scatter(const uint* __restrict__ keyhi,
                               uint* __restrict__ base,
                               const uint* __restrict__ hdr,
                               u64* __restrict__ buck) {
  int b = blockIdx.y;
  int i = blockIdx.x * 256 + threadIdx.x;
  if (i >= NN) return;
  uint kh = keyhi[(size_t)b * NN + i];
  if ((kh >> 16) <= hdr[0 + b]) {
    uint pos = atomicAdd(&base[(size_t)b * 65536 + (kh >> 16)], 1u);
    if (pos < SCAP) buck[(size_t)b * SCAP + pos] = ((u64)kh << 32) | (uint)i;
  }
}

// ---------- pass 4: exact rank within bucket -> scatter to sorted[] ----------
__global__ void rank_write(const u64* __restrict__ buck,
                           const uint* __restrict__ base,
                           const uint* __restrict__ hist,
                           const uint* __restrict__ hdr,
                           u64* __restrict__ sorted) {
  int b = blockIdx.y;
  int s = blockIdx.x * 256 + threadIdx.x;
  uint limit = hdr[4 + b];
  if (s >= (int)limit) return;
  u64 v = buck[(size_t)b * SCAP + s];
  uint bkt = (uint)(v >> 48);
  uint cnt = hist[(size_t)b * 65536 + bkt];
  uint b0 = base[(size_t)b * 65536 + bkt] - cnt;   // restore pre-scatter base
  uint r = b0;
  for (uint m = 0; m < cnt; ++m) {
    u64 w = buck[(size_t)b * SCAP + b0 + m];
    r += (w < v) ? 1u : 0u;                        // (key,idx) stable order
  }
  if (r < (uint)PRE) sorted[(size_t)b * SCAP + r] = v;
}

// ---------- pass 5: gather top-6000 boxes/scores/areas + keepInit ----------
__global__ __launch_bounds__(1024) void gather6k(const u64* __restrict__ sorted,
                                                 const float4* __restrict__ props,
                                                 const float2* __restrict__ clsp,
                                                 float4* __restrict__ boxes6k,
                                                 float* __restrict__ score6k,
                                                 float* __restrict__ area6k,
                                                 u64* __restrict__ keepInit) {
  int b = blockIdx.y;
  int j = blockIdx.x * 1024 + threadIdx.x;    // 0..6143
  int lane = threadIdx.x & 63;
  u64 v = sorted[(size_t)b * SCAP + j];
  bool has = (j < PRE) && (v != ~0ull);
  bool valid = false; float sc = -INFINITY, ar = 0.0f;
  float4 bx; bx.x = bx.y = bx.z = bx.w = 0.0f;
  if (has) {
    uint idx = (uint)(v & 0xFFFFFFFFull);
    float4 p = props[(size_t)b * NN + idx];
    float x1 = clipf(p.x, 800.0f), y1 = clipf(p.y, 800.0f);
    float x2 = clipf(p.z, 800.0f), y2 = clipf(p.w, 800.0f);
    float w = x2 - x1, h = y2 - y1;
    valid = (w >= 16.0f) && (h >= 16.0f);
    sc = clsp[(size_t)b * NN + idx].y;
    bx.x = x1; bx.y = y1; bx.z = x2; bx.w = y2;
    ar = fmaxf(w, 0.0f) * fmaxf(h, 0.0f);
  }
  if (j < ROWP) {
    boxes6k[(size_t)b * ROWP + j] = bx;
    score6k[(size_t)b * ROWP + j] = sc;
    area6k [(size_t)b * ROWP + j] = ar;
  }
  u64 mb = __ballot(valid);
  if (lane == 0) keepInit[(size_t)b * 96 + (j >> 6)] = ~mb;   // removed-init = ~valid
}

// ---------- pass 6: suppression matrix, suppressor-row-packed ----------
// matC[b][gb][col]: bit r = "row gb*64+r suppresses col" (row < col only).
__global__ __launch_bounds__(64) void nms_matrix(const float4* __restrict__ boxes6k,
                                                 const float* __restrict__ area6k,
                                                 u64* __restrict__ matC) {
  int cb = blockIdx.x, gb = blockIdx.y, b = blockIdx.z;
  if (cb < gb) return;
  __shared__ float4 rbox[64];
  __shared__ float  rar[64];
  int t = threadIdx.x;
  rbox[t] = boxes6k[(size_t)b * ROWP + gb * 64 + t];
  rar[t]  = area6k [(size_t)b * ROWP + gb * 64 + t];
  __syncthreads();
  int col = cb * 64 + t;
  float4 c = boxes6k[(size_t)b * ROWP + col];
  float ca = area6k[(size_t)b * ROWP + col];
  int rbase = gb * 64;
  u64 bits = 0;
  #pragma unroll 8
  for (int r = 0; r < 64; ++r) {
    int row = rbase + r;
    if (row < col) {
      float4 rb = rbox[r];
      float xx1 = fmaxf(rb.x, c.x), yy1 = fmaxf(rb.y, c.y);
      float xx2 = fminf(rb.z, c.z), yy2 = fminf(rb.w, c.w);
      float inter = fmaxf(xx2 - xx1, 0.0f) * fmaxf(yy2 - yy1, 0.0f);
      float un = rar[r] + ca - inter;
      float iou = inter / fmaxf(un, 1e-9f);
      if (iou > 0.7f) bits |= (1ull << r);
    }
  }
  matC[((size_t)b * NWRD + gb) * ROWP + col] = bits;
}

// ---------- pass 7: greedy NMS (redundant per-wave fixpoint, 1 barrier/group)
//            + fused finalize ----------
__global__ __launch_bounds__(1024) void nms_seq2(const u64* __restrict__ matC,
                                                 const u64* __restrict__ keepInit,
                                                 const float* __restrict__ score6k,
                                                 const float4* __restrict__ boxes6k,
                                                 float* __restrict__ out) {
  int b = blockIdx.x;
  int tid = threadIdx.x, lane = tid & 63, W = tid >> 6;
  __shared__ u64 REM[96];     // suppressed-so-far per word (folds from earlier groups)
  __shared__ u64 KEEP[96];    // resolved alive mask per word
  if (tid < 96) {
    REM[tid]  = (tid < NWRD) ? keepInit[(size_t)b * 96 + tid] : ~0ull;
    KEEP[tid] = 0ull;
  }
  const u64* M = matC + (size_t)b * NWRD * ROWP;

  u64 pfA[6], pfB[6], dA = 0, dB = 0;
  // prologue: group 0 -> A (every wave loads the diagonal word itself)
  #pragma unroll
  for (int j = 0; j < 6; ++j) {
    int w = 1 + W + 16 * j;
    pfA[j] = (w < NWRD) ? M[(size_t)w * 64 + lane] : 0ull;
  }
  dA = M[lane];
  __syncthreads();

  #pragma unroll 1
  for (int g = 0; g < NWRD; g += 2) {
    // ===== group g (buffers A), prefetch g+1 -> B =====
    {
      int gn = g + 1;                       // always < NWRD (NWRD even)
      #pragma unroll
      for (int j = 0; j < 6; ++j) {
        int w = gn + 1 + W + 16 * j;
        pfB[j] = (w < NWRD) ? M[(size_t)gn * ROWP + (size_t)w * 64 + lane] : 0ull;
      }
      dB = M[(size_t)gn * ROWP + (size_t)gn * 64 + lane];

      // all waves redundantly resolve the diagonal fixpoint
      u64 validM = ~REM[g];
      bool inU = (validM >> lane) & 1ull;
      u64 U = __ballot(inU);
      u64 A = 0ull;
      while (U) {
        u64 newA = __ballot(inU && ((dA & U) == 0ull));  // no undecided suppressor
        A |= newA;
        bool deadNew = (((newA >> lane) & 1ull) != 0ull) || ((dA & newA) != 0ull);
        u64 rm = __ballot(inU && deadNew);
        U &= ~rm;
        inU = inU && !deadNew;
      }
      // fold alive rows into later column-words
      #pragma unroll
      for (int j = 0; j < 6; ++j) {
        int w = g + 1 + W + 16 * j;
        if (w < NWRD) {
          u64 bits = __ballot((pfA[j] & A) != 0ull);
          if (lane == 0) REM[w] |= bits;
        }
      }
      if (tid == 0) KEEP[g] = A;
      __syncthreads();
    }
    // ===== group g+1 (buffers B), prefetch g+2 -> A =====
    {
      int go = g + 1;
      int gn = (g + 2 < NWRD) ? (g + 2) : (NWRD - 1);
      #pragma unroll
      for (int j = 0; j < 6; ++j) {
        int w = gn + 1 + W + 16 * j;
        pfA[j] = (w < NWRD) ? M[(size_t)gn * ROWP + (size_t)w * 64 + lane] : 0ull;
      }
      dA = M[(size_t)gn * ROWP + (size_t)gn * 64 + lane];

      u64 validM = ~REM[go];
      bool inU = (validM >> lane) & 1ull;
      u64 U = __ballot(inU);
      u64 A = 0ull;
      while (U) {
        u64 newA = __ballot(inU && ((dB & U) == 0ull));
        A |= newA;
        bool deadNew = (((newA >> lane) & 1ull) != 0ull) || ((dB & newA) != 0ull);
        u64 rm = __ballot(inU && deadNew);
        U &= ~rm;
        inU = inU && !deadNew;
      }
      #pragma unroll
      for (int j = 0; j < 6; ++j) {
        int w = go + 1 + W + 16 * j;
        if (w < NWRD) {
          u64 bits = __ballot((pfB[j] & A) != 0ull);
          if (lane == 0) REM[w] |= bits;
        }
      }
      if (tid == 0) KEEP[go] = A;
      __syncthreads();
    }
  }

  // ---- fused finalize: rank kept, emit first 1000 ----
  __shared__ uint pre[NWRD + 1];
  if (tid == 0) {
    uint c = 0;
    for (int w = 0; w < NWRD; ++w) { pre[w] = c; c += (uint)__popcll(KEEP[w]); }
    pre[NWRD] = c;
  }
  __syncthreads();
  for (int q = tid; q < POST; q += 1024) out[(size_t)b * POST + q] = 0.0f;
  for (int t = tid; t < POST * 4; t += 1024) out[(size_t)BB * POST + (size_t)b * POST * 4 + t] = 0.0f;
  __syncthreads();
  for (int j = tid; j < PRE; j += 1024) {
    int w = j >> 6, bit = j & 63;
    u64 word = KEEP[w];
    if ((word >> bit) & 1ull) {
      uint rank = pre[w] + (uint)__popcll(word & ((1ull << bit) - 1ull));
      if (rank < POST) {
        out[(size_t)b * POST + rank] = score6k[(size_t)b * ROWP + j];
        float4 bx = boxes6k[(size_t)b * ROWP + j];
        float* o = out + (size_t)BB * POST + ((size_t)b * POST + rank) * 4;
        o[0] = bx.x; o[1] = bx.y; o[2] = bx.z; o[3] = bx.w;
      }
    }
  }
}

extern "C" void kernel_launch(void* const* d_in, const int* in_sizes, int n_in,
                              void* d_out, int out_size, void* d_ws, size_t ws_size,
                              hipStream_t stream) {
  const float4* props = (const float4*)d_in[0];
  const float2* clsp  = (const float2*)d_in[1];
  float* out = (float*)d_out;
  char* ws = (char*)d_ws;

  uint*   hdr     = (uint*)(ws + OFF_HDR);
  uint*   hist1   = (uint*)(ws + OFF_H1);
  uint*   base    = (uint*)(ws + OFF_BASE);
  uint*   keyhi   = (uint*)(ws + OFF_KEY);
  u64*    buck    = (u64*) (ws + OFF_BUCK);
  u64*    sorted  = (u64*) (ws + OFF_SORT);
  float4* boxes6k = (float4*)(ws + OFF_BOX);
  float*  score6k = (float*)(ws + OFF_SCO);
  float*  area6k  = (float*)(ws + OFF_AREA);
  u64*    keepInit= (u64*) (ws + OFF_KINIT);
  u64*    matC    = (u64*) (ws + OFF_MAT);

  // zero hdr+hist1; fill sorted[] with ~0 sentinel
  int nz4 = (int)((1024 + (size_t)BB * 65536 * 4) / 16);
  int nf4 = (int)(((size_t)BB * SCAP * 8) / 16);
  zero_fill<<<512, 256, 0, stream>>>((uint4*)ws, nz4, (uint4*)(ws + OFF_SORT), nf4);

  dim3 gN((NN + 255) / 256, BB);
  keys_hist<<<gN, 256, 0, stream>>>(props, clsp, keyhi, hist1);
  scan_base<<<BB, 1024, 0, stream>>>(hist1, base, hdr);
  bucket_scatter<<<gN, 256, 0, stream>>>(keyhi, base, hdr, buck);
  rank_write<<<dim3(SCAP / 256, BB), 256, 0, stream>>>(buck, base, hist1, hdr, sorted);
  gather6k<<<dim3(6, BB), 1024, 0, stream>>>(sorted, props, clsp, boxes6k, score6k, area6k, keepInit);
  nms_matrix<<<dim3(NWRD, NWRD, BB), 64, 0, stream>>>(boxes6k, area6k, matC);
  nms_seq2<<<BB, 1024, 0, stream>>>(matC, keepInit, score6k, boxes6k, out);
}

// Round 6
// 345.384 us; speedup vs baseline: 7.6572x; 1.0559x over previous
//
#include <hip/hip_runtime.h>
#include <hip/hip_bf16.h>
#include <math.h>

typedef unsigned int uint;
typedef unsigned long long u64;

#define BB 4
#define NN 100000
#define PRE 6000
#define POST 1000
#define NWRD 94          // 6000/64 rounded up
#define SCAP 8192        // bucketed/sorted capacity
#define ROWP 6016        // padded rows/cols

// ---- workspace layout (bytes) ----
constexpr size_t OFF_HDR   = 0;                                    // 16 uints: t1[4], limit[4]
constexpr size_t OFF_H1    = 1024;                                 // hist1: BB*65536*4 = 1MB
constexpr size_t OFF_BASE  = OFF_H1  + (size_t)BB*65536*4;         // base:  1MB
constexpr size_t OFF_KEY   = OFF_BASE+ (size_t)BB*65536*4;         // keyhi: BB*NN*4
constexpr size_t OFF_BUCK  = OFF_KEY + (size_t)BB*NN*4;            // BB*SCAP*8
constexpr size_t OFF_SORT  = OFF_BUCK+ (size_t)BB*SCAP*8;          // BB*SCAP*8
constexpr size_t OFF_BOX   = OFF_SORT+ (size_t)BB*SCAP*8;
constexpr size_t OFF_SCO   = OFF_BOX + (size_t)BB*ROWP*16;
constexpr size_t OFF_AREA  = OFF_SCO + (size_t)BB*ROWP*4;
constexpr size_t OFF_KINIT = OFF_AREA+ (size_t)BB*ROWP*4;
constexpr size_t OFF_MAT   = OFF_KINIT+(size_t)BB*96*8;
// matC: [BB][NWRD][ROWP] u64 ~= 18.1 MB ; total ~= 22.7 MB

__device__ __forceinline__ float clipf(float v, float hi) {
  return fminf(fmaxf(v, 0.0f), hi);
}

// ---------- zero hdr+hist1, fill sorted with sentinel ----------
__global__ void zero_fill(uint4* zp, int nz4, uint4* fp, int nf4) {
  int t = blockIdx.x * 256 + threadIdx.x;
  uint4 z; z.x = z.y = z.z = z.w = 0u;
  uint4 f; f.x = f.y = f.z = f.w = 0xFFFFFFFFu;
  for (int i = t; i < nz4; i += gridDim.x * 256) zp[i] = z;
  for (int i = t; i < nf4; i += gridDim.x * 256) fp[i] = f;
}

// ---------- pass 1: keys + histogram over high-16 of key ----------
__global__ void keys_hist(const float4* __restrict__ props,
                          const float2* __restrict__ clsp,
                          uint* __restrict__ keyhi,
                          uint* __restrict__ hist1) {
  int b = blockIdx.y;
  int i = blockIdx.x * 256 + threadIdx.x;
  bool act = (i < NN);
  bool valid = false;
  uint kh = 0xFF800000u;     // key of -inf
  if (act) {
    float4 p = props[(size_t)b * NN + i];
    float x1 = clipf(p.x, 800.0f), y1 = clipf(p.y, 800.0f);
    float x2 = clipf(p.z, 800.0f), y2 = clipf(p.w, 800.0f);
    valid = ((x2 - x1) >= 16.0f) && ((y2 - y1) >= 16.0f);
    float s  = clsp[(size_t)b * NN + i].y;
    float sm = valid ? s : -INFINITY;
    uint u = __float_as_uint(sm);
    u = (u & 0x80000000u) ? ~u : (u | 0x80000000u);  // monotonic: ascending u == ascending score
    kh = ~u;                                          // ascending kh == DESCENDING score
    keyhi[(size_t)b * NN + i] = kh;
  }
  if (act && valid) atomicAdd(&hist1[(size_t)b * 65536 + (kh >> 16)], 1u);
  // invalid boxes all hit one bucket -> aggregate per wave to avoid hot-spot atomics
  u64 mb = __ballot(act && !valid);
  int lane = threadIdx.x & 63;
  if ((act && !valid) && lane == (__ffsll((long long)mb) - 1))
    atomicAdd(&hist1[(size_t)b * 65536 + 0xFF80u], (uint)__popcll(mb));
}

// ---------- pass 2: exclusive scan of hist1 -> base[]; find boundary ----------
// uint4-vectorized, no persistent per-thread array (avoids scratch).
__global__ __launch_bounds__(1024) void scan_base(const uint* __restrict__ hist,
                                                  uint* __restrict__ base,
                                                  uint* __restrict__ hdr) {
  int b = blockIdx.x, tid = threadIdx.x, lane = tid & 63, W = tid >> 6;
  const uint* h = hist + (size_t)b * 65536;
  const uint4* h4 = (const uint4*)h + tid * 16;
  uint* bs = base + (size_t)b * 65536;
  uint s = 0;
  #pragma unroll
  for (int k = 0; k < 16; ++k) {
    uint4 v = h4[k];
    s += v.x + v.y + v.z + v.w;
  }
  // inclusive wave scan (no barriers)
  uint ps = s;
  #pragma unroll
  for (int off = 1; off < 64; off <<= 1) {
    uint v = __shfl_up(ps, off);
    if (lane >= off) ps += v;
  }
  __shared__ uint wsum[16];
  if (lane == 63) wsum[W] = ps;
  __syncthreads();
  if (tid < 16) {
    uint v = wsum[tid], pv = v;
    #pragma unroll
    for (int off = 1; off < 16; off <<= 1) {
      uint t = __shfl_up(pv, off, 16);
      if (tid >= off) pv += t;
    }
    wsum[tid] = pv;   // inclusive over waves
  }
  __syncthreads();
  uint wbase = (W > 0) ? wsum[W - 1] : 0u;
  uint incl = wbase + ps, excl = incl - s;
  uint total = wsum[15];
  uint target = total < (uint)PRE ? total : (uint)PRE;
  if (target > 0 && excl < target && target <= incl) {   // unique owner thread
    uint c = excl;
    #pragma unroll 1
    for (int k = 0; k < 64; ++k) {          // re-read own 64 bins (L2-hot)
      uint hv = h[tid * 64 + k];
      if (c < target && target <= c + hv) {
        hdr[0 + b] = (uint)(tid * 64 + k);   // t1 boundary bucket
        hdr[4 + b] = c + hv;                 // limit = cumulative through t1
        break;
      }
      c += hv;
    }
  }
  // write exclusive bases, vectorized (re-read hist, L2-hot)
  uint run = excl;
  uint4* bs4 = (uint4*)bs + tid * 16;
  #pragma unroll
  for (int k = 0; k < 16; ++k) {
    uint4 v = h4[k];
    uint4 o;
    o.x = run; run += v.x;
    o.y = run; run += v.y;
    o.z = run; run += v.z;
    o.w = run; run += v.w;
    bs4[k] = o;
  }
}

// ---------- pass 3: scatter elems of buckets <= t1 into bucket slots ----------
__global__ void bucket_scatter(const uint* __restrict__ keyhi,
                               uint* __restrict__ base,
                               const uint* __restrict__ hdr,
                               u64* __restrict__ buck) {
  int b = blockIdx.y;
  int i = blockIdx.x * 256 + threadIdx.x;
  if (i >= NN) return;
  uint kh = keyhi[(size_t)b * NN + i];
  if ((kh >> 16) <= hdr[0 + b]) {
    uint pos = atomicAdd(&base[(size_t)b * 65536 + (kh >> 16)], 1u);
    if (pos < SCAP) buck[(size_t)b * SCAP + pos] = ((u64)kh << 32) | (uint)i;
  }
}

// ---------- pass 4: exact rank within bucket -> scatter to sorted[] ----------
__global__ void rank_write(const u64* __restrict__ buck,
                           const uint* __restrict__ base,
                           const uint* __restrict__ hist,
                           const uint* __restrict__ hdr,
                           u64* __restrict__ sorted) {
  int b = blockIdx.y;
  int s = blockIdx.x * 256 + threadIdx.x;
  uint limit = hdr[4 + b];
  if (s >= (int)limit) return;
  u64 v = buck[(size_t)b * SCAP + s];
  uint bkt = (uint)(v >> 48);
  uint cnt = hist[(size_t)b * 65536 + bkt];
  uint b0 = base[(size_t)b * 65536 + bkt] - cnt;   // restore pre-scatter base
  uint r = b0;
  for (uint m = 0; m < cnt; ++m) {
    u64 w = buck[(size_t)b * SCAP + b0 + m];
    r += (w < v) ? 1u : 0u;                        // (key,idx) stable order
  }
  if (r < (uint)PRE) sorted[(size_t)b * SCAP + r] = v;
}

// ---------- pass 5: gather top-6000 boxes/scores/areas + keepInit ----------
__global__ __launch_bounds__(1024) void gather6k(const u64* __restrict__ sorted,
                                                 const float4* __restrict__ props,
                                                 const float2* __restrict__ clsp,
                                                 float4* __restrict__ boxes6k,
                                                 float* __restrict__ score6k,
                                                 float* __restrict__ area6k,
                                                 u64* __restrict__ keepInit) {
  int b = blockIdx.y;
  int j = blockIdx.x * 1024 + threadIdx.x;    // 0..6143
  int lane = threadIdx.x & 63;
  u64 v = sorted[(size_t)b * SCAP + j];
  bool has = (j < PRE) && (v != ~0ull);
  bool valid = false; float sc = -INFINITY, ar = 0.0f;
  float4 bx; bx.x = bx.y = bx.z = bx.w = 0.0f;
  if (has) {
    uint idx = (uint)(v & 0xFFFFFFFFull);
    float4 p = props[(size_t)b * NN + idx];
    float x1 = clipf(p.x, 800.0f), y1 = clipf(p.y, 800.0f);
    float x2 = clipf(p.z, 800.0f), y2 = clipf(p.w, 800.0f);
    float w = x2 - x1, h = y2 - y1;
    valid = (w >= 16.0f) && (h >= 16.0f);
    sc = clsp[(size_t)b * NN + idx].y;
    bx.x = x1; bx.y = y1; bx.z = x2; bx.w = y2;
    ar = fmaxf(w, 0.0f) * fmaxf(h, 0.0f);
  }
  if (j < ROWP) {
    boxes6k[(size_t)b * ROWP + j] = bx;
    score6k[(size_t)b * ROWP + j] = sc;
    area6k [(size_t)b * ROWP + j] = ar;
  }
  u64 mb = __ballot(valid);
  if (lane == 0) keepInit[(size_t)b * 96 + (j >> 6)] = ~mb;   // removed-init = ~valid
}

// ---------- pass 6: suppression matrix, suppressor-row-packed ----------
// matC[b][gb][col]: bit r = "row gb*64+r suppresses col" (row < col only).
// 256 threads = 4 column-words per block, shared row-block LDS.
__global__ __launch_bounds__(256) void nms_matrix(const float4* __restrict__ boxes6k,
                                                  const float* __restrict__ area6k,
                                                  u64* __restrict__ matC) {
  int gb = blockIdx.y, b = blockIdx.z;
  int sub = threadIdx.x >> 6, t = threadIdx.x & 63;
  int cb = blockIdx.x * 4 + sub;
  __shared__ float4 rbox[64];
  __shared__ float  rar[64];
  if (threadIdx.x < 64) {
    rbox[t] = boxes6k[(size_t)b * ROWP + gb * 64 + t];
    rar[t]  = area6k [(size_t)b * ROWP + gb * 64 + t];
  }
  __syncthreads();
  if (cb >= NWRD || cb < gb) return;
  int col = cb * 64 + t;
  float4 c = boxes6k[(size_t)b * ROWP + col];
  float ca = area6k[(size_t)b * ROWP + col];
  int rbase = gb * 64;
  u64 bits = 0;
  #pragma unroll 8
  for (int r = 0; r < 64; ++r) {
    int row = rbase + r;
    if (row < col) {
      float4 rb = rbox[r];
      float xx1 = fmaxf(rb.x, c.x), yy1 = fmaxf(rb.y, c.y);
      float xx2 = fminf(rb.z, c.z), yy2 = fminf(rb.w, c.w);
      float inter = fmaxf(xx2 - xx1, 0.0f) * fmaxf(yy2 - yy1, 0.0f);
      float un = rar[r] + ca - inter;
      float iou = inter / fmaxf(un, 1e-9f);
      if (iou > 0.7f) bits |= (1ull << r);
    }
  }
  matC[((size_t)b * NWRD + gb) * ROWP + col] = bits;
}

// ---------- ballot fixpoint: resolve 64-candidate diagonal ----------
// d (per lane) = in-group suppressors of candidate `lane` (bit r = row r suppresses).
__device__ __forceinline__ u64 resolve_fix(u64 d, u64 validM, int lane) {
  bool inU = (validM >> lane) & 1ull;
  u64 U = __ballot(inU);
  u64 A = 0ull;
  while (U) {
    u64 newA = __ballot(inU && ((d & U) == 0ull));   // no undecided suppressor
    A |= newA;
    bool deadNew = (((newA >> lane) & 1ull) != 0ull) || ((d & newA) != 0ull);
    u64 rm = __ballot(inU && deadNew);
    U &= ~rm;
    inU = inU && !deadNew;
  }
  return A;
}

// ---------- pass 7: greedy NMS — register-resident REM, fixed ownership,
//            2 groups per barrier, redundant per-wave fixpoint + fused finalize
__global__ __launch_bounds__(1024) void nms_seq3(const u64* __restrict__ matC,
                                                 const u64* __restrict__ keepInit,
                                                 const float* __restrict__ score6k,
                                                 const float4* __restrict__ boxes6k,
                                                 float* __restrict__ out) {
  int b = blockIdx.x;
  int tid = threadIdx.x, lane = tid & 63, W = tid >> 6;
  __shared__ u64 REMS[96];    // published removed-mask (valid only for current groups)
  __shared__ u64 KEEP[96];    // resolved alive mask per word
  if (tid < 96) {
    REMS[tid] = (tid < NWRD) ? keepInit[(size_t)b * 96 + tid] : ~0ull;
    KEEP[tid] = 0ull;
  }
  const u64* M = matC + (size_t)b * NWRD * ROWP;

  // wave W owns words w = W + 16*j  (register-resident removed-masks)
  u64 rem[6];
  #pragma unroll
  for (int j = 0; j < 6; ++j) {
    int w = W + 16 * j;
    rem[j] = (w < NWRD) ? keepInit[(size_t)b * 96 + w] : ~0ull;
  }

  // prefetch buffers: per owned word, rows g and g+1; crit = diag/cross/diag
  u64 pfA0[6], pfA1[6], pfB0[6], pfB1[6];
  u64 cA0, cA1, cA2, cB0, cB1, cB2;
  {
    const int g = 0;
    #pragma unroll
    for (int j = 0; j < 6; ++j) {
      int w = W + 16 * j;
      bool ld = (w >= g + 2) && (w < NWRD);
      pfA0[j] = ld ? M[(size_t)g       * ROWP + (size_t)w * 64 + lane] : 0ull;
      pfA1[j] = ld ? M[(size_t)(g + 1) * ROWP + (size_t)w * 64 + lane] : 0ull;
    }
    cA0 = M[(size_t)g * ROWP + (size_t)g * 64 + lane];
    cA1 = M[(size_t)g * ROWP + (size_t)(g + 1) * 64 + lane];
    cA2 = M[(size_t)(g + 1) * ROWP + (size_t)(g + 1) * 64 + lane];
  }
  __syncthreads();

  #pragma unroll 1
  for (int g = 0; g < NWRD; g += 2) {
    // prefetch next iteration (groups g+2, g+3)
    int gn = g + 2;
    if (gn < NWRD) {
      #pragma unroll
      for (int j = 0; j < 6; ++j) {
        int w = W + 16 * j;
        bool ld = (w >= gn + 2) && (w < NWRD);
        pfB0[j] = ld ? M[(size_t)gn       * ROWP + (size_t)w * 64 + lane] : 0ull;
        pfB1[j] = ld ? M[(size_t)(gn + 1) * ROWP + (size_t)w * 64 + lane] : 0ull;
      }
      cB0 = M[(size_t)gn * ROWP + (size_t)gn * 64 + lane];
      cB1 = M[(size_t)gn * ROWP + (size_t)(gn + 1) * 64 + lane];
      cB2 = M[(size_t)(gn + 1) * ROWP + (size_t)(gn + 1) * 64 + lane];
    } else {
      cB0 = cB1 = cB2 = 0ull;
      #pragma unroll
      for (int j = 0; j < 6; ++j) { pfB0[j] = 0ull; pfB1[j] = 0ull; }
    }

    // group g: all waves redundantly resolve
    u64 Ag = resolve_fix(cA0, ~REMS[g], lane);
    // cross-fold g -> word g+1 (in-register, redundant)
    u64 REMg1 = REMS[g + 1] | __ballot((cA1 & Ag) != 0ull);
    // group g+1
    u64 Ag1 = resolve_fix(cA2, ~REMg1, lane);

    // fold alive rows of g, g+1 into owned later words (register ORs)
    #pragma unroll
    for (int j = 0; j < 6; ++j) {
      int w = W + 16 * j;
      if (w >= g + 2 && w < NWRD) {
        u64 bits = __ballot(((pfA0[j] & Ag) | (pfA1[j] & Ag1)) != 0ull);
        rem[j] |= bits;
      }
    }
    if (tid == 0) { KEEP[g] = Ag; KEEP[g + 1] = Ag1; }
    // publish all owned words (write-only; only g+2, g+3 are read next iter)
    if (lane == 0) {
      #pragma unroll
      for (int j = 0; j < 6; ++j) {
        int w = W + 16 * j;
        if (w < NWRD) REMS[w] = rem[j];
      }
    }
    __syncthreads();

    // rotate buffers B -> A
    #pragma unroll
    for (int j = 0; j < 6; ++j) { pfA0[j] = pfB0[j]; pfA1[j] = pfB1[j]; }
    cA0 = cB0; cA1 = cB1; cA2 = cB2;
  }

  // ---- fused finalize: rank kept, emit first 1000 ----
  __shared__ uint pre[NWRD + 1];
  if (tid == 0) {
    uint c = 0;
    for (int w = 0; w < NWRD; ++w) { pre[w] = c; c += (uint)__popcll(KEEP[w]); }
    pre[NWRD] = c;
  }
  __syncthreads();
  for (int q = tid; q < POST; q += 1024) out[(size_t)b * POST + q] = 0.0f;
  for (int t = tid; t < POST * 4; t += 1024) out[(size_t)BB * POST + (size_t)b * POST * 4 + t] = 0.0f;
  __syncthreads();
  for (int j = tid; j < PRE; j += 1024) {
    int w = j >> 6, bit = j & 63;
    u64 word = KEEP[w];
    if ((word >> bit) & 1ull) {
      uint rank = pre[w] + (uint)__popcll(word & ((1ull << bit) - 1ull));
      if (rank < POST) {
        out[(size_t)b * POST + rank] = score6k[(size_t)b * ROWP + j];
        float4 bx = boxes6k[(size_t)b * ROWP + j];
        float* o = out + (size_t)BB * POST + ((size_t)b * POST + rank) * 4;
        o[0] = bx.x; o[1] = bx.y; o[2] = bx.z; o[3] = bx.w;
      }
    }
  }
}

extern "C" void kernel_launch(void* const* d_in, const int* in_sizes, int n_in,
                              void* d_out, int out_size, void* d_ws, size_t ws_size,
                              hipStream_t stream) {
  const float4* props = (const float4*)d_in[0];
  const float2* clsp  = (const float2*)d_in[1];
  float* out = (float*)d_out;
  char* ws = (char*)d_ws;

  uint*   hdr     = (uint*)(ws + OFF_HDR);
  uint*   hist1   = (uint*)(ws + OFF_H1);
  uint*   base    = (uint*)(ws + OFF_BASE);
  uint*   keyhi   = (uint*)(ws + OFF_KEY);
  u64*    buck    = (u64*) (ws + OFF_BUCK);
  u64*    sorted  = (u64*) (ws + OFF_SORT);
  float4* boxes6k = (float4*)(ws + OFF_BOX);
  float*  score6k = (float*)(ws + OFF_SCO);
  float*  area6k  = (float*)(ws + OFF_AREA);
  u64*    keepInit= (u64*) (ws + OFF_KINIT);
  u64*    matC    = (u64*) (ws + OFF_MAT);

  // zero hdr+hist1; fill sorted[] with ~0 sentinel
  int nz4 = (int)((1024 + (size_t)BB * 65536 * 4) / 16);
  int nf4 = (int)(((size_t)BB * SCAP * 8) / 16);
  zero_fill<<<512, 256, 0, stream>>>((uint4*)ws, nz4, (uint4*)(ws + OFF_SORT), nf4);

  dim3 gN((NN + 255) / 256, BB);
  keys_hist<<<gN, 256, 0, stream>>>(props, clsp, keyhi, hist1);
  scan_base<<<BB, 1024, 0, stream>>>(hist1, base, hdr);
  bucket_scatter<<<gN, 256, 0, stream>>>(keyhi, base, hdr, buck);
  rank_write<<<dim3(SCAP / 256, BB), 256, 0, stream>>>(buck, base, hist1, hdr, sorted);
  gather6k<<<dim3(6, BB), 1024, 0, stream>>>(sorted, props, clsp, boxes6k, score6k, area6k, keepInit);
  nms_matrix<<<dim3((NWRD + 3) / 4, NWRD, BB), 256, 0, stream>>>(boxes6k, area6k, matC);
  nms_seq3<<<BB, 1024, 0, stream>>>(matC, keepInit, score6k, boxes6k, out);
}

// Round 7
// 296.080 us; speedup vs baseline: 8.9323x; 1.1665x over previous
//
#include <hip/hip_runtime.h>
#include <hip/hip_bf16.h>
#include <math.h>

typedef unsigned int uint;
typedef unsigned long long u64;

#define BB 4
#define NN 100000
#define PRE 6000
#define POST 1000
#define NWRD 94          // 6000/64 rounded up
#define SCAP 8192        // bucketed/sorted capacity
#define ROWP 6016        // padded rows/cols
#define KSUP 64          // max suppressors tracked per box

// ---- workspace layout (bytes); [OFF_HDR, OFF_H1+1MB) is one contiguous zero region ----
constexpr size_t OFF_HDR   = 0;                                    // 16 uints: t1[4], limit[4]
constexpr size_t OFF_CNT   = 1024;                                 // BB*ROWP*4 = 96256
constexpr size_t OFF_H1    = OFF_CNT + (size_t)BB*ROWP*4;          // hist1: 1MB
constexpr size_t OFF_BASE  = OFF_H1  + (size_t)BB*65536*4;         // base:  1MB
constexpr size_t OFF_KEY   = OFF_BASE+ (size_t)BB*65536*4;         // keyhi: BB*NN*4
constexpr size_t OFF_BUCK  = OFF_KEY + (size_t)BB*NN*4;            // BB*SCAP*8
constexpr size_t OFF_SORT  = OFF_BUCK+ (size_t)BB*SCAP*8;          // BB*SCAP*8
constexpr size_t OFF_LIST  = OFF_SORT+ (size_t)BB*SCAP*8;          // BB*ROWP*KSUP*4 ~= 6.2MB
constexpr size_t OFF_BOX   = OFF_LIST+ (size_t)BB*ROWP*KSUP*4;
constexpr size_t OFF_SCO   = OFF_BOX + (size_t)BB*ROWP*16;
constexpr size_t OFF_AREA  = OFF_SCO + (size_t)BB*ROWP*4;
constexpr size_t OFF_VAL   = OFF_AREA+ (size_t)BB*ROWP*4;          // validW: BB*96*8
// total ~= 10.6 MB

__device__ __forceinline__ float clipf(float v, float hi) {
  return fminf(fmaxf(v, 0.0f), hi);
}

// ---------- zero hdr+cnt+hist1, fill sorted with sentinel ----------
__global__ void zero_fill(uint4* zp, int nz4, uint4* fp, int nf4) {
  int t = blockIdx.x * 256 + threadIdx.x;
  uint4 z; z.x = z.y = z.z = z.w = 0u;
  uint4 f; f.x = f.y = f.z = f.w = 0xFFFFFFFFu;
  for (int i = t; i < nz4; i += gridDim.x * 256) zp[i] = z;
  for (int i = t; i < nf4; i += gridDim.x * 256) fp[i] = f;
}

// ---------- pass 1: keys + histogram over high-16 of key ----------
__global__ void keys_hist(const float4* __restrict__ props,
                          const float2* __restrict__ clsp,
                          uint* __restrict__ keyhi,
                          uint* __restrict__ hist1) {
  int b = blockIdx.y;
  int i = blockIdx.x * 256 + threadIdx.x;
  bool act = (i < NN);
  bool valid = false;
  uint kh = 0xFF800000u;     // key of -inf
  if (act) {
    float4 p = props[(size_t)b * NN + i];
    float x1 = clipf(p.x, 800.0f), y1 = clipf(p.y, 800.0f);
    float x2 = clipf(p.z, 800.0f), y2 = clipf(p.w, 800.0f);
    valid = ((x2 - x1) >= 16.0f) && ((y2 - y1) >= 16.0f);
    float s  = clsp[(size_t)b * NN + i].y;
    float sm = valid ? s : -INFINITY;
    uint u = __float_as_uint(sm);
    u = (u & 0x80000000u) ? ~u : (u | 0x80000000u);  // monotonic: ascending u == ascending score
    kh = ~u;                                          // ascending kh == DESCENDING score
    keyhi[(size_t)b * NN + i] = kh;
  }
  if (act && valid) atomicAdd(&hist1[(size_t)b * 65536 + (kh >> 16)], 1u);
  // invalid boxes all hit one bucket -> aggregate per wave to avoid hot-spot atomics
  u64 mb = __ballot(act && !valid);
  int lane = threadIdx.x & 63;
  if ((act && !valid) && lane == (__ffsll((long long)mb) - 1))
    atomicAdd(&hist1[(size_t)b * 65536 + 0xFF80u], (uint)__popcll(mb));
}

// ---------- pass 2: exclusive scan of hist1 -> base[]; find boundary ----------
__global__ __launch_bounds__(1024) void scan_base(const uint* __restrict__ hist,
                                                  uint* __restrict__ base,
                                                  uint* __restrict__ hdr) {
  int b = blockIdx.x, tid = threadIdx.x, lane = tid & 63, W = tid >> 6;
  const uint* h = hist + (size_t)b * 65536;
  const uint4* h4 = (const uint4*)h + tid * 16;
  uint* bs = base + (size_t)b * 65536;
  uint s = 0;
  #pragma unroll
  for (int k = 0; k < 16; ++k) {
    uint4 v = h4[k];
    s += v.x + v.y + v.z + v.w;
  }
  // inclusive wave scan (no barriers)
  uint ps = s;
  #pragma unroll
  for (int off = 1; off < 64; off <<= 1) {
    uint v = __shfl_up(ps, off);
    if (lane >= off) ps += v;
  }
  __shared__ uint wsum[16];
  if (lane == 63) wsum[W] = ps;
  __syncthreads();
  if (tid < 16) {
    uint v = wsum[tid], pv = v;
    #pragma unroll
    for (int off = 1; off < 16; off <<= 1) {
      uint t = __shfl_up(pv, off, 16);
      if (tid >= off) pv += t;
    }
    wsum[tid] = pv;   // inclusive over waves
  }
  __syncthreads();
  uint wbase = (W > 0) ? wsum[W - 1] : 0u;
  uint incl = wbase + ps, excl = incl - s;
  uint total = wsum[15];
  uint target = total < (uint)PRE ? total : (uint)PRE;
  if (target > 0 && excl < target && target <= incl) {   // unique owner thread
    uint c = excl;
    #pragma unroll 1
    for (int k = 0; k < 64; ++k) {          // re-read own 64 bins (L2-hot)
      uint hv = h[tid * 64 + k];
      if (c < target && target <= c + hv) {
        hdr[0 + b] = (uint)(tid * 64 + k);   // t1 boundary bucket
        hdr[4 + b] = c + hv;                 // limit = cumulative through t1
        break;
      }
      c += hv;
    }
  }
  // write exclusive bases, vectorized (re-read hist, L2-hot)
  uint run = excl;
  uint4* bs4 = (uint4*)bs + tid * 16;
  #pragma unroll
  for (int k = 0; k < 16; ++k) {
    uint4 v = h4[k];
    uint4 o;
    o.x = run; run += v.x;
    o.y = run; run += v.y;
    o.z = run; run += v.z;
    o.w = run; run += v.w;
    bs4[k] = o;
  }
}

// ---------- pass 3: scatter elems of buckets <= t1 into bucket slots ----------
__global__ void bucket_scatter(const uint* __restrict__ keyhi,
                               uint* __restrict__ base,
                               const uint* __restrict__ hdr,
                               u64* __restrict__ buck) {
  int b = blockIdx.y;
  int i = blockIdx.x * 256 + threadIdx.x;
  if (i >= NN) return;
  uint kh = keyhi[(size_t)b * NN + i];
  if ((kh >> 16) <= hdr[0 + b]) {
    uint pos = atomicAdd(&base[(size_t)b * 65536 + (kh >> 16)], 1u);
    if (pos < SCAP) buck[(size_t)b * SCAP + pos] = ((u64)kh << 32) | (uint)i;
  }
}

// ---------- pass 4: exact rank within bucket -> scatter to sorted[] ----------
__global__ void rank_write(const u64* __restrict__ buck,
                           const uint* __restrict__ base,
                           const uint* __restrict__ hist,
                           const uint* __restrict__ hdr,
                           u64* __restrict__ sorted) {
  int b = blockIdx.y;
  int s = blockIdx.x * 256 + threadIdx.x;
  uint limit = hdr[4 + b];
  if (s >= (int)limit) return;
  u64 v = buck[(size_t)b * SCAP + s];
  uint bkt = (uint)(v >> 48);
  uint cnt = hist[(size_t)b * 65536 + bkt];
  uint b0 = base[(size_t)b * 65536 + bkt] - cnt;   // restore pre-scatter base
  uint r = b0;
  for (uint m = 0; m < cnt; ++m) {
    u64 w = buck[(size_t)b * SCAP + b0 + m];
    r += (w < v) ? 1u : 0u;                        // (key,idx) stable order
  }
  if (r < (uint)PRE) sorted[(size_t)b * SCAP + r] = v;
}

// ---------- pass 5: gather top-6000 boxes/scores/areas + validW ----------
__global__ __launch_bounds__(1024) void gather6k(const u64* __restrict__ sorted,
                                                 const float4* __restrict__ props,
                                                 const float2* __restrict__ clsp,
                                                 float4* __restrict__ boxes6k,
                                                 float* __restrict__ score6k,
                                                 float* __restrict__ area6k,
                                                 u64* __restrict__ validW) {
  int b = blockIdx.y;
  int j = blockIdx.x * 1024 + threadIdx.x;    // 0..6143
  int lane = threadIdx.x & 63;
  u64 v = sorted[(size_t)b * SCAP + j];
  bool has = (j < PRE) && (v != ~0ull);
  bool valid = false; float sc = -INFINITY, ar = 0.0f;
  float4 bx; bx.x = bx.y = bx.z = bx.w = 0.0f;
  if (has) {
    uint idx = (uint)(v & 0xFFFFFFFFull);
    float4 p = props[(size_t)b * NN + idx];
    float x1 = clipf(p.x, 800.0f), y1 = clipf(p.y, 800.0f);
    float x2 = clipf(p.z, 800.0f), y2 = clipf(p.w, 800.0f);
    float w = x2 - x1, h = y2 - y1;
    valid = (w >= 16.0f) && (h >= 16.0f);
    sc = clsp[(size_t)b * NN + idx].y;
    bx.x = x1; bx.y = y1; bx.z = x2; bx.w = y2;
    ar = fmaxf(w, 0.0f) * fmaxf(h, 0.0f);
  }
  if (j < ROWP) {
    boxes6k[(size_t)b * ROWP + j] = bx;
    score6k[(size_t)b * ROWP + j] = sc;
    area6k [(size_t)b * ROWP + j] = ar;
  }
  u64 mb = __ballot(valid);
  if (lane == 0) validW[(size_t)b * 96 + (j >> 6)] = mb;   // bit=1 => valid
}

// ---------- pass 6: sparse suppressor-list build ----------
// For each pair (row < col) with valid[row] and IoU>0.7: append row to col's list.
__global__ __launch_bounds__(256) void sup_build(const float4* __restrict__ boxes6k,
                                                 const float* __restrict__ area6k,
                                                 const u64* __restrict__ validW,
                                                 uint* __restrict__ cnt,
                                                 uint* __restrict__ list) {
  int gb = blockIdx.y, b = blockIdx.z;
  int sub = threadIdx.x >> 6, t = threadIdx.x & 63;
  int cb = blockIdx.x * 4 + sub;
  __shared__ float4 rbox[64];
  __shared__ float  rar[64];
  if (threadIdx.x < 64) {
    rbox[t] = boxes6k[(size_t)b * ROWP + gb * 64 + t];
    rar[t]  = area6k [(size_t)b * ROWP + gb * 64 + t];
  }
  __syncthreads();
  if (cb >= NWRD || cb < gb) return;
  u64 vmask = validW[(size_t)b * 96 + gb];
  int col = cb * 64 + t;
  float4 c = boxes6k[(size_t)b * ROWP + col];
  float ca = area6k[(size_t)b * ROWP + col];
  int rbase = gb * 64;
  u64 bits = 0;
  #pragma unroll 8
  for (int r = 0; r < 64; ++r) {
    int row = rbase + r;
    if (row < col && ((vmask >> r) & 1ull)) {
      float4 rb = rbox[r];
      float xx1 = fmaxf(rb.x, c.x), yy1 = fmaxf(rb.y, c.y);
      float xx2 = fminf(rb.z, c.z), yy2 = fminf(rb.w, c.w);
      float inter = fmaxf(xx2 - xx1, 0.0f) * fmaxf(yy2 - yy1, 0.0f);
      float un = rar[r] + ca - inter;
      float iou = inter / fmaxf(un, 1e-9f);
      if (iou > 0.7f) bits |= (1ull << r);
    }
  }
  while (bits) {
    int r = __ffsll((long long)bits) - 1;
    bits &= bits - 1;
    uint pos = atomicAdd(&cnt[(size_t)b * ROWP + col], 1u);
    if (pos < KSUP) list[((size_t)b * ROWP + col) * KSUP + pos] = (uint)(rbase + r);
  }
}

// ---------- pass 7: sparse Jacobi fixpoint resolve + fused finalize ----------
// Deterministic: each round's decisions depend only on the previous round's state.
__global__ __launch_bounds__(1024) void sparse_resolve(const uint* __restrict__ cnt,
                                                       const uint* __restrict__ list,
                                                       const u64* __restrict__ validW,
                                                       const float* __restrict__ score6k,
                                                       const float4* __restrict__ boxes6k,
                                                       float* __restrict__ out) {
  int b = blockIdx.x, tid = threadIdx.x;
  __shared__ u64 ALIVE[96], DEC[96], VW[96];
  __shared__ int changed;
  if (tid < 96) {
    ALIVE[tid] = 0ull; DEC[tid] = 0ull;
    VW[tid] = validW[(size_t)b * 96 + tid];
  }
  __syncthreads();

  uint myCnt[6];
  #pragma unroll
  for (int r = 0; r < 6; ++r) {
    int j = tid + r * 1024;
    myCnt[r] = (j < PRE) ? cnt[(size_t)b * ROWP + j] : 0u;
  }
  // init: cnt==0 or invalid boxes decide immediately
  #pragma unroll
  for (int r = 0; r < 6; ++r) {
    int j = tid + r * 1024;
    if (j >= PRE) continue;
    bool valid = (VW[j >> 6] >> (j & 63)) & 1ull;
    if (myCnt[r] == 0u || !valid) {
      atomicOr(&DEC[j >> 6], 1ull << (j & 63));
      if (valid) atomicOr(&ALIVE[j >> 6], 1ull << (j & 63));
    }
  }
  __syncthreads();

  // fixpoint rounds (terminates: lowest undecided box always decides)
  while (true) {
    if (tid == 0) changed = 0;
    __syncthreads();
    // compute phase (state is stable)
    int decJ[6]; bool decAlive[6];
    #pragma unroll
    for (int r = 0; r < 6; ++r) {
      decJ[r] = -1; decAlive[r] = false;
      int j = tid + r * 1024;
      if (j >= PRE || myCnt[r] == 0u) continue;
      if ((DEC[j >> 6] >> (j & 63)) & 1ull) continue;
      const uint* lj = list + ((size_t)b * ROWP + j) * KSUP;
      uint c = myCnt[r] < KSUP ? myCnt[r] : KSUP;
      bool anyAlive = false, pending = false;
      for (uint m = 0; m < c; ++m) {
        uint i = lj[m];
        bool ai = (ALIVE[i >> 6] >> (i & 63)) & 1ull;
        bool di = (DEC[i >> 6] >> (i & 63)) & 1ull;
        if (ai) { anyAlive = true; break; }
        if (!di) pending = true;
      }
      if (anyAlive)      { decJ[r] = j; decAlive[r] = false; }
      else if (!pending) { decJ[r] = j; decAlive[r] = true;  }
    }
    __syncthreads();
    // apply phase
    bool any = false;
    #pragma unroll
    for (int r = 0; r < 6; ++r) {
      if (decJ[r] >= 0) {
        int j = decJ[r];
        if (decAlive[r]) atomicOr(&ALIVE[j >> 6], 1ull << (j & 63));
        atomicOr(&DEC[j >> 6], 1ull << (j & 63));
        any = true;
      }
    }
    if (any) atomicAdd(&changed, 1);
    __syncthreads();
    if (changed == 0) break;
  }

  // ---- fused finalize: rank kept, emit first 1000 ----
  __shared__ uint pre[NWRD + 1];
  if (tid == 0) {
    uint c = 0;
    for (int w = 0; w < NWRD; ++w) { pre[w] = c; c += (uint)__popcll(ALIVE[w]); }
    pre[NWRD] = c;
  }
  __syncthreads();
  for (int q = tid; q < POST; q += 1024) out[(size_t)b * POST + q] = 0.0f;
  for (int t = tid; t < POST * 4; t += 1024) out[(size_t)BB * POST + (size_t)b * POST * 4 + t] = 0.0f;
  __syncthreads();
  for (int j = tid; j < PRE; j += 1024) {
    int w = j >> 6, bit = j & 63;
    u64 word = ALIVE[w];
    if ((word >> bit) & 1ull) {
      uint rank = pre[w] + (uint)__popcll(word & ((1ull << bit) - 1ull));
      if (rank < POST) {
        out[(size_t)b * POST + rank] = score6k[(size_t)b * ROWP + j];
        float4 bx = boxes6k[(size_t)b * ROWP + j];
        float* o = out + (size_t)BB * POST + ((size_t)b * POST + rank) * 4;
        o[0] = bx.x; o[1] = bx.y; o[2] = bx.z; o[3] = bx.w;
      }
    }
  }
}

extern "C" void kernel_launch(void* const* d_in, const int* in_sizes, int n_in,
                              void* d_out, int out_size, void* d_ws, size_t ws_size,
                              hipStream_t stream) {
  const float4* props = (const float4*)d_in[0];
  const float2* clsp  = (const float2*)d_in[1];
  float* out = (float*)d_out;
  char* ws = (char*)d_ws;

  uint*   hdr     = (uint*)(ws + OFF_HDR);
  uint*   cnt     = (uint*)(ws + OFF_CNT);
  uint*   hist1   = (uint*)(ws + OFF_H1);
  uint*   base    = (uint*)(ws + OFF_BASE);
  uint*   keyhi   = (uint*)(ws + OFF_KEY);
  u64*    buck    = (u64*) (ws + OFF_BUCK);
  u64*    sorted  = (u64*) (ws + OFF_SORT);
  uint*   list    = (uint*)(ws + OFF_LIST);
  float4* boxes6k = (float4*)(ws + OFF_BOX);
  float*  score6k = (float*)(ws + OFF_SCO);
  float*  area6k  = (float*)(ws + OFF_AREA);
  u64*    validW  = (u64*) (ws + OFF_VAL);

  // zero hdr+cnt+hist1 (contiguous); fill sorted[] with ~0 sentinel
  int nz4 = (int)((OFF_H1 + (size_t)BB * 65536 * 4) / 16);
  int nf4 = (int)(((size_t)BB * SCAP * 8) / 16);
  zero_fill<<<512, 256, 0, stream>>>((uint4*)ws, nz4, (uint4*)(ws + OFF_SORT), nf4);

  dim3 gN((NN + 255) / 256, BB);
  keys_hist<<<gN, 256, 0, stream>>>(props, clsp, keyhi, hist1);
  scan_base<<<BB, 1024, 0, stream>>>(hist1, base, hdr);
  bucket_scatter<<<gN, 256, 0, stream>>>(keyhi, base, hdr, buck);
  rank_write<<<dim3(SCAP / 256, BB), 256, 0, stream>>>(buck, base, hist1, hdr, sorted);
  gather6k<<<dim3(6, BB), 1024, 0, stream>>>(sorted, props, clsp, boxes6k, score6k, area6k, validW);
  sup_build<<<dim3((NWRD + 3) / 4, NWRD, BB), 256, 0, stream>>>(boxes6k, area6k, validW, cnt, list);
  sparse_resolve<<<BB, 1024, 0, stream>>>(cnt, list, validW, score6k, boxes6k, out);
}

// Round 8
// 280.802 us; speedup vs baseline: 9.4183x; 1.0544x over previous
//
#include <hip/hip_runtime.h>
#include <hip/hip_bf16.h>
#include <math.h>

typedef unsigned int uint;
typedef unsigned long long u64;

#define BB 4
#define NN 100000
#define PRE 6000
#define POST 1000
#define NWRD 94          // 6000/64 rounded up
#define SCAP 8192        // bucketed/sorted capacity
#define ROWP 6016        // padded rows/cols
#define KSUP 64          // max suppressors tracked per box

// ---- workspace layout (bytes); [OFF_HDR, OFF_BASE) is one contiguous zero region ----
constexpr size_t OFF_HDR   = 0;                                    // 16 uints: t1[4], limit[4]
constexpr size_t OFF_CNT   = 1024;                                 // BB*ROWP*4 = 96256
constexpr size_t OFF_H1    = OFF_CNT + (size_t)BB*ROWP*4;          // hist1: 1MB
constexpr size_t OFF_BASE  = OFF_H1  + (size_t)BB*65536*4;         // base:  1MB (no zero needed)
constexpr size_t OFF_KEY   = OFF_BASE+ (size_t)BB*65536*4;         // keyhi: BB*NN*4
constexpr size_t OFF_BUCK  = OFF_KEY + (size_t)BB*NN*4;            // BB*SCAP*8
constexpr size_t OFF_SORT  = OFF_BUCK+ (size_t)BB*SCAP*8;          // BB*SCAP*8
constexpr size_t OFF_LIST  = OFF_SORT+ (size_t)BB*SCAP*8;          // BB*ROWP*KSUP*4 ~= 6.2MB
constexpr size_t OFF_BOX   = OFF_LIST+ (size_t)BB*ROWP*KSUP*4;
constexpr size_t OFF_SCO   = OFF_BOX + (size_t)BB*ROWP*16;
constexpr size_t OFF_AREA  = OFF_SCO + (size_t)BB*ROWP*4;
constexpr size_t OFF_VAL   = OFF_AREA+ (size_t)BB*ROWP*4;          // validW: BB*96*8
// total ~= 10.6 MB

__device__ __forceinline__ float clipf(float v, float hi) {
  return fminf(fmaxf(v, 0.0f), hi);
}

// ---------- zero hdr+cnt+hist1 (contiguous) ----------
__global__ void zero_fill(uint4* zp, int nz4) {
  int t = blockIdx.x * 256 + threadIdx.x;
  uint4 z; z.x = z.y = z.z = z.w = 0u;
  for (int i = t; i < nz4; i += gridDim.x * 256) zp[i] = z;
}

// ---------- pass 1: keys + histogram over high-16 of key ----------
__global__ void keys_hist(const float4* __restrict__ props,
                          const float2* __restrict__ clsp,
                          uint* __restrict__ keyhi,
                          uint* __restrict__ hist1) {
  int b = blockIdx.y;
  int i = blockIdx.x * 256 + threadIdx.x;
  bool act = (i < NN);
  bool valid = false;
  uint kh = 0xFF800000u;     // key of -inf
  if (act) {
    float4 p = props[(size_t)b * NN + i];
    float x1 = clipf(p.x, 800.0f), y1 = clipf(p.y, 800.0f);
    float x2 = clipf(p.z, 800.0f), y2 = clipf(p.w, 800.0f);
    valid = ((x2 - x1) >= 16.0f) && ((y2 - y1) >= 16.0f);
    float s  = clsp[(size_t)b * NN + i].y;
    float sm = valid ? s : -INFINITY;
    uint u = __float_as_uint(sm);
    u = (u & 0x80000000u) ? ~u : (u | 0x80000000u);  // monotonic: ascending u == ascending score
    kh = ~u;                                          // ascending kh == DESCENDING score
    keyhi[(size_t)b * NN + i] = kh;
  }
  if (act && valid) atomicAdd(&hist1[(size_t)b * 65536 + (kh >> 16)], 1u);
  // invalid boxes all hit one bucket -> aggregate per wave to avoid hot-spot atomics
  u64 mb = __ballot(act && !valid);
  int lane = threadIdx.x & 63;
  if ((act && !valid) && lane == (__ffsll((long long)mb) - 1))
    atomicAdd(&hist1[(size_t)b * 65536 + 0xFF80u], (uint)__popcll(mb));
}

// ---------- pass 2: exclusive scan of hist1 -> base[]; find boundary ----------
__global__ __launch_bounds__(1024) void scan_base(const uint* __restrict__ hist,
                                                  uint* __restrict__ base,
                                                  uint* __restrict__ hdr) {
  int b = blockIdx.x, tid = threadIdx.x, lane = tid & 63, W = tid >> 6;
  const uint* h = hist + (size_t)b * 65536;
  const uint4* h4 = (const uint4*)h + tid * 16;
  uint* bs = base + (size_t)b * 65536;
  uint s = 0;
  #pragma unroll
  for (int k = 0; k < 16; ++k) {
    uint4 v = h4[k];
    s += v.x + v.y + v.z + v.w;
  }
  // inclusive wave scan (no barriers)
  uint ps = s;
  #pragma unroll
  for (int off = 1; off < 64; off <<= 1) {
    uint v = __shfl_up(ps, off);
    if (lane >= off) ps += v;
  }
  __shared__ uint wsum[16];
  if (lane == 63) wsum[W] = ps;
  __syncthreads();
  if (tid < 16) {
    uint v = wsum[tid], pv = v;
    #pragma unroll
    for (int off = 1; off < 16; off <<= 1) {
      uint t = __shfl_up(pv, off, 16);
      if (tid >= off) pv += t;
    }
    wsum[tid] = pv;   // inclusive over waves
  }
  __syncthreads();
  uint wbase = (W > 0) ? wsum[W - 1] : 0u;
  uint incl = wbase + ps, excl = incl - s;
  uint total = wsum[15];
  uint target = total < (uint)PRE ? total : (uint)PRE;
  if (target > 0 && excl < target && target <= incl) {   // unique owner thread
    uint c = excl;
    #pragma unroll 1
    for (int k = 0; k < 64; ++k) {          // re-read own 64 bins (L2-hot)
      uint hv = h[tid * 64 + k];
      if (c < target && target <= c + hv) {
        hdr[0 + b] = (uint)(tid * 64 + k);   // t1 boundary bucket
        hdr[4 + b] = c + hv;                 // limit = cumulative through t1
        break;
      }
      c += hv;
    }
  }
  // write exclusive bases, vectorized (re-read hist, L2-hot)
  uint run = excl;
  uint4* bs4 = (uint4*)bs + tid * 16;
  #pragma unroll
  for (int k = 0; k < 16; ++k) {
    uint4 v = h4[k];
    uint4 o;
    o.x = run; run += v.x;
    o.y = run; run += v.y;
    o.z = run; run += v.z;
    o.w = run; run += v.w;
    bs4[k] = o;
  }
}

// ---------- pass 3: scatter elems of buckets <= t1 into bucket slots ----------
__global__ void bucket_scatter(const uint* __restrict__ keyhi,
                               uint* __restrict__ base,
                               const uint* __restrict__ hdr,
                               u64* __restrict__ buck) {
  int b = blockIdx.y;
  int i = blockIdx.x * 256 + threadIdx.x;
  if (i >= NN) return;
  uint kh = keyhi[(size_t)b * NN + i];
  if ((kh >> 16) <= hdr[0 + b]) {
    uint pos = atomicAdd(&base[(size_t)b * 65536 + (kh >> 16)], 1u);
    if (pos < SCAP) buck[(size_t)b * SCAP + pos] = ((u64)kh << 32) | (uint)i;
  }
}

// ---------- pass 4: exact rank within bucket -> scatter to sorted[] ----------
__global__ void rank_write(const u64* __restrict__ buck,
                           const uint* __restrict__ base,
                           const uint* __restrict__ hist,
                           const uint* __restrict__ hdr,
                           u64* __restrict__ sorted) {
  int b = blockIdx.y;
  int s = blockIdx.x * 256 + threadIdx.x;
  uint limit = hdr[4 + b];
  if (s >= (int)limit) return;
  u64 v = buck[(size_t)b * SCAP + s];
  uint bkt = (uint)(v >> 48);
  uint cnt = hist[(size_t)b * 65536 + bkt];
  uint b0 = base[(size_t)b * 65536 + bkt] - cnt;   // restore pre-scatter base
  uint r = b0;
  for (uint m = 0; m < cnt; ++m) {
    u64 w = buck[(size_t)b * SCAP + b0 + m];
    r += (w < v) ? 1u : 0u;                        // (key,idx) stable order
  }
  if (r < (uint)PRE) sorted[(size_t)b * SCAP + r] = v;
}

// ---------- pass 5: gather top-6000 boxes/scores/areas + validW ----------
// NOTE: every sorted[r], r<PRE is always written by rank_write (limit >= PRE
// since all 100K keys are histogrammed), so no sentinel fill is needed.
__global__ __launch_bounds__(1024) void gather6k(const u64* __restrict__ sorted,
                                                 const float4* __restrict__ props,
                                                 const float2* __restrict__ clsp,
                                                 float4* __restrict__ boxes6k,
                                                 float* __restrict__ score6k,
                                                 float* __restrict__ area6k,
                                                 u64* __restrict__ validW) {
  int b = blockIdx.y;
  int j = blockIdx.x * 1024 + threadIdx.x;    // 0..6143
  int lane = threadIdx.x & 63;
  u64 v = sorted[(size_t)b * SCAP + j];
  bool has = (j < PRE);
  bool valid = false; float sc = -INFINITY, ar = 0.0f;
  float4 bx; bx.x = bx.y = bx.z = bx.w = 0.0f;
  if (has) {
    uint idx = (uint)(v & 0xFFFFFFFFull);
    float4 p = props[(size_t)b * NN + idx];
    float x1 = clipf(p.x, 800.0f), y1 = clipf(p.y, 800.0f);
    float x2 = clipf(p.z, 800.0f), y2 = clipf(p.w, 800.0f);
    float w = x2 - x1, h = y2 - y1;
    valid = (w >= 16.0f) && (h >= 16.0f);
    sc = clsp[(size_t)b * NN + idx].y;
    bx.x = x1; bx.y = y1; bx.z = x2; bx.w = y2;
    ar = fmaxf(w, 0.0f) * fmaxf(h, 0.0f);
  }
  if (j < ROWP) {
    boxes6k[(size_t)b * ROWP + j] = bx;
    score6k[(size_t)b * ROWP + j] = sc;
    area6k [(size_t)b * ROWP + j] = ar;
  }
  u64 mb = __ballot(valid);
  if (lane == 0) validW[(size_t)b * 96 + (j >> 6)] = mb;   // bit=1 => valid
}

// ---------- pass 6: sparse suppressor-list build (division-free exact test) ----
// fl32(inter/unc) > 0.7f  <=>  inter/unc >= 0.7f + 2^-25 (tie rounds to even,
// up)  <=>  (double)inter >= 0x1.666667p-1 * (double)unc  -- EXACT: 25b x 24b
// mantissa product = 49 bits < 53, conversions exact, unc > 0.
__global__ __launch_bounds__(256) void sup_build(const float4* __restrict__ boxes6k,
                                                 const float* __restrict__ area6k,
                                                 const u64* __restrict__ validW,
                                                 uint* __restrict__ cnt,
                                                 uint* __restrict__ list) {
  int gb = blockIdx.y, b = blockIdx.z;
  int sub = threadIdx.x >> 6, t = threadIdx.x & 63;
  int cb = blockIdx.x * 4 + sub;
  __shared__ float4 rbox[64];
  __shared__ float  rar[64];
  if (threadIdx.x < 64) {
    rbox[t] = boxes6k[(size_t)b * ROWP + gb * 64 + t];
    rar[t]  = area6k [(size_t)b * ROWP + gb * 64 + t];
  }
  __syncthreads();
  if (cb >= NWRD || cb < gb) return;
  u64 vmask = validW[(size_t)b * 96 + gb];
  // row<col hoisted: strict-upper tiles take all rows; diagonal masks r < t.
  u64 rowsel = (cb == gb) ? (t ? (vmask & ((1ull << t) - 1ull)) : 0ull) : vmask;
  int col = cb * 64 + t;
  float4 c = boxes6k[(size_t)b * ROWP + col];
  float ca = area6k[(size_t)b * ROWP + col];
  const double M = 0x1.666667p-1;   // exact decision boundary for (iou > 0.7f)
  int rbase = gb * 64;
  u64 bits = 0;
  #pragma unroll 8
  for (int r = 0; r < 64; ++r) {
    float4 rb = rbox[r];
    float xx1 = fmaxf(rb.x, c.x), yy1 = fmaxf(rb.y, c.y);
    float xx2 = fminf(rb.z, c.z), yy2 = fminf(rb.w, c.w);
    float inter = fmaxf(xx2 - xx1, 0.0f) * fmaxf(yy2 - yy1, 0.0f);
    float un = fmaxf(rar[r] + ca - inter, 1e-9f);
    if (((rowsel >> r) & 1ull) && ((double)inter >= M * (double)un))
      bits |= (1ull << r);
  }
  while (bits) {
    int r = __ffsll((long long)bits) - 1;
    bits &= bits - 1;
    uint pos = atomicAdd(&cnt[(size_t)b * ROWP + col], 1u);
    if (pos < KSUP) list[((size_t)b * ROWP + col) * KSUP + pos] = (uint)(rbase + r);
  }
}

// ---------- pass 7: sparse Jacobi fixpoint resolve + fused finalize ----------
__global__ __launch_bounds__(1024) void sparse_resolve(const uint* __restrict__ cnt,
                                                       const uint* __restrict__ list,
                                                       const u64* __restrict__ validW,
                                                       const float* __restrict__ score6k,
                                                       const float4* __restrict__ boxes6k,
                                                       float* __restrict__ out) {
  int b = blockIdx.x, tid = threadIdx.x;
  __shared__ u64 ALIVE[96], DEC[96], VW[96];
  __shared__ int changed;
  if (tid < 96) {
    ALIVE[tid] = 0ull; DEC[tid] = 0ull;
    VW[tid] = validW[(size_t)b * 96 + tid];
  }
  __syncthreads();

  uint myCnt[6];
  #pragma unroll
  for (int r = 0; r < 6; ++r) {
    int j = tid + r * 1024;
    myCnt[r] = (j < PRE) ? cnt[(size_t)b * ROWP + j] : 0u;
  }
  // init: cnt==0 or invalid boxes decide immediately
  #pragma unroll
  for (int r = 0; r < 6; ++r) {
    int j = tid + r * 1024;
    if (j >= PRE) continue;
    bool valid = (VW[j >> 6] >> (j & 63)) & 1ull;
    if (myCnt[r] == 0u || !valid) {
      atomicOr(&DEC[j >> 6], 1ull << (j & 63));
      if (valid) atomicOr(&ALIVE[j >> 6], 1ull << (j & 63));
    }
  }
  __syncthreads();

  // fixpoint rounds (terminates: lowest undecided box always decides)
  while (true) {
    if (tid == 0) changed = 0;
    __syncthreads();
    // compute phase (state is stable)
    int decJ[6]; bool decAlive[6];
    #pragma unroll
    for (int r = 0; r < 6; ++r) {
      decJ[r] = -1; decAlive[r] = false;
      int j = tid + r * 1024;
      if (j >= PRE || myCnt[r] == 0u) continue;
      if ((DEC[j >> 6] >> (j & 63)) & 1ull) continue;
      const uint* lj = list + ((size_t)b * ROWP + j) * KSUP;
      uint c = myCnt[r] < KSUP ? myCnt[r] : KSUP;
      bool anyAlive = false, pending = false;
      for (uint m = 0; m < c; ++m) {
        uint i = lj[m];
        bool ai = (ALIVE[i >> 6] >> (i & 63)) & 1ull;
        bool di = (DEC[i >> 6] >> (i & 63)) & 1ull;
        if (ai) { anyAlive = true; break; }
        if (!di) pending = true;
      }
      if (anyAlive)      { decJ[r] = j; decAlive[r] = false; }
      else if (!pending) { decJ[r] = j; decAlive[r] = true;  }
    }
    __syncthreads();
    // apply phase
    bool any = false;
    #pragma unroll
    for (int r = 0; r < 6; ++r) {
      if (decJ[r] >= 0) {
        int j = decJ[r];
        if (decAlive[r]) atomicOr(&ALIVE[j >> 6], 1ull << (j & 63));
        atomicOr(&DEC[j >> 6], 1ull << (j & 63));
        any = true;
      }
    }
    if (any) atomicAdd(&changed, 1);
    __syncthreads();
    if (changed == 0) break;
  }

  // ---- fused finalize: rank kept, emit first 1000 ----
  __shared__ uint pre[NWRD + 1];
  if (tid == 0) {
    uint c = 0;
    for (int w = 0; w < NWRD; ++w) { pre[w] = c; c += (uint)__popcll(ALIVE[w]); }
    pre[NWRD] = c;
  }
  __syncthreads();
  for (int q = tid; q < POST; q += 1024) out[(size_t)b * POST + q] = 0.0f;
  for (int t = tid; t < POST * 4; t += 1024) out[(size_t)BB * POST + (size_t)b * POST * 4 + t] = 0.0f;
  __syncthreads();
  for (int j = tid; j < PRE; j += 1024) {
    int w = j >> 6, bit = j & 63;
    u64 word = ALIVE[w];
    if ((word >> bit) & 1ull) {
      uint rank = pre[w] + (uint)__popcll(word & ((1ull << bit) - 1ull));
      if (rank < POST) {
        out[(size_t)b * POST + rank] = score6k[(size_t)b * ROWP + j];
        float4 bx = boxes6k[(size_t)b * ROWP + j];
        float* o = out + (size_t)BB * POST + ((size_t)b * POST + rank) * 4;
        o[0] = bx.x; o[1] = bx.y; o[2] = bx.z; o[3] = bx.w;
      }
    }
  }
}

extern "C" void kernel_launch(void* const* d_in, const int* in_sizes, int n_in,
                              void* d_out, int out_size, void* d_ws, size_t ws_size,
                              hipStream_t stream) {
  const float4* props = (const float4*)d_in[0];
  const float2* clsp  = (const float2*)d_in[1];
  float* out = (float*)d_out;
  char* ws = (char*)d_ws;

  uint*   hdr     = (uint*)(ws + OFF_HDR);
  uint*   cnt     = (uint*)(ws + OFF_CNT);
  uint*   hist1   = (uint*)(ws + OFF_H1);
  uint*   base    = (uint*)(ws + OFF_BASE);
  uint*   keyhi   = (uint*)(ws + OFF_KEY);
  u64*    buck    = (u64*) (ws + OFF_BUCK);
  u64*    sorted  = (u64*) (ws + OFF_SORT);
  uint*   list    = (uint*)(ws + OFF_LIST);
  float4* boxes6k = (float4*)(ws + OFF_BOX);
  float*  score6k = (float*)(ws + OFF_SCO);
  float*  area6k  = (float*)(ws + OFF_AREA);
  u64*    validW  = (u64*) (ws + OFF_VAL);

  // zero hdr+cnt+hist1 (contiguous region [0, OFF_BASE))
  int nz4 = (int)(OFF_BASE / 16);
  zero_fill<<<512, 256, 0, stream>>>((uint4*)ws, nz4);

  dim3 gN((NN + 255) / 256, BB);
  keys_hist<<<gN, 256, 0, stream>>>(props, clsp, keyhi, hist1);
  scan_base<<<BB, 1024, 0, stream>>>(hist1, base, hdr);
  bucket_scatter<<<gN, 256, 0, stream>>>(keyhi, base, hdr, buck);
  rank_write<<<dim3(SCAP / 256, BB), 256, 0, stream>>>(buck, base, hist1, hdr, sorted);
  gather6k<<<dim3(6, BB), 1024, 0, stream>>>(sorted, props, clsp, boxes6k, score6k, area6k, validW);
  sup_build<<<dim3((NWRD + 3) / 4, NWRD, BB), 256, 0, stream>>>(boxes6k, area6k, validW, cnt, list);
  sparse_resolve<<<BB, 1024, 0, stream>>>(cnt, list, validW, score6k, boxes6k, out);
}

// Round 9
// 259.300 us; speedup vs baseline: 10.1993x; 1.0829x over previous
//
#include <hip/hip_runtime.h>
#include <hip/hip_bf16.h>
#include <math.h>

typedef unsigned int uint;
typedef unsigned long long u64;

#define BB 4
#define NN 100000
#define PRE 6000
#define POST 1000
#define NWRD 94          // 6000/64 rounded up
#define SCAP 8192        // bucketed/sorted capacity
#define ROWP 6016        // padded rows/cols
#define KSUP 64          // max suppressors tracked per box
#define NRANGE 32        // hist range-blocks per image (2048 bins each)

// ---- workspace layout (bytes); [OFF_HDR, OFF_H1) is the zeroed region ----
constexpr size_t OFF_HDR   = 0;                                    // 16 uints: t1[4], limit[4]
constexpr size_t OFF_CNT   = 1024;                                 // BB*ROWP*4 = 96256
constexpr size_t OFF_H1    = OFF_CNT + (size_t)BB*ROWP*4;          // hist1: 1MB (fully overwritten)
constexpr size_t OFF_BASE  = OFF_H1  + (size_t)BB*65536*4;         // base:  1MB (fully overwritten)
constexpr size_t OFF_KEY   = OFF_BASE+ (size_t)BB*65536*4;         // keyhi: BB*NN*4
constexpr size_t OFF_BUCK  = OFF_KEY + (size_t)BB*NN*4;            // BB*SCAP*8
constexpr size_t OFF_SORT  = OFF_BUCK+ (size_t)BB*SCAP*8;          // BB*SCAP*8
constexpr size_t OFF_LIST  = OFF_SORT+ (size_t)BB*SCAP*8;          // BB*ROWP*KSUP*4 ~= 6.2MB
constexpr size_t OFF_BOX   = OFF_LIST+ (size_t)BB*ROWP*KSUP*4;
constexpr size_t OFF_SCO   = OFF_BOX + (size_t)BB*ROWP*16;
constexpr size_t OFF_AREA  = OFF_SCO + (size_t)BB*ROWP*4;
constexpr size_t OFF_VAL   = OFF_AREA+ (size_t)BB*ROWP*4;          // validW: BB*96*8
// total ~= 10.6 MB

__device__ __forceinline__ float clipf(float v, float hi) {
  return fminf(fmaxf(v, 0.0f), hi);
}

// ---------- zero hdr+cnt (contiguous, 97 KB) ----------
__global__ void zero_fill(uint4* zp, int nz4) {
  int t = blockIdx.x * 256 + threadIdx.x;
  uint4 z; z.x = z.y = z.z = z.w = 0u;
  for (int i = t; i < nz4; i += gridDim.x * 256) zp[i] = z;
}

// ---------- pass 1a: keys only (pure streaming, no atomics) ----------
__global__ void keys_only(const float4* __restrict__ props,
                          const float2* __restrict__ clsp,
                          uint* __restrict__ keyhi) {
  int b = blockIdx.y;
  int i = blockIdx.x * 256 + threadIdx.x;
  if (i >= NN) return;
  float4 p = props[(size_t)b * NN + i];
  float x1 = clipf(p.x, 800.0f), y1 = clipf(p.y, 800.0f);
  float x2 = clipf(p.z, 800.0f), y2 = clipf(p.w, 800.0f);
  bool valid = ((x2 - x1) >= 16.0f) && ((y2 - y1) >= 16.0f);
  float s  = clsp[(size_t)b * NN + i].y;
  float sm = valid ? s : -INFINITY;
  uint u = __float_as_uint(sm);
  u = (u & 0x80000000u) ? ~u : (u | 0x80000000u);  // monotonic: ascending u == ascending score
  keyhi[(size_t)b * NN + i] = ~u;                   // ascending key == DESCENDING score
}

// ---------- pass 1b: range-partitioned histogram (LDS, zero global atomics) ----
// Block (r,b) owns bins [r*2048,(r+1)*2048): counts in-range keys into LDS,
// then PLAIN-stores its bin range. hist1 is fully overwritten every call.
__global__ __launch_bounds__(256) void hist_range(const uint4* __restrict__ keyhi4,
                                                  uint* __restrict__ hist1) {
  int b = blockIdx.y;
  uint lo = (uint)blockIdx.x << 11;     // 2048 bins per range block
  __shared__ uint lh[2048];
  for (int i = threadIdx.x; i < 2048; i += 256) lh[i] = 0u;
  __syncthreads();
  const uint4* K = keyhi4 + (size_t)b * (NN / 4);
  for (int i = threadIdx.x; i < NN / 4; i += 256) {
    uint4 v = K[i];
    uint b0 = (v.x >> 16) - lo; if (b0 < 2048u) atomicAdd(&lh[b0], 1u);
    uint b1 = (v.y >> 16) - lo; if (b1 < 2048u) atomicAdd(&lh[b1], 1u);
    uint b2 = (v.z >> 16) - lo; if (b2 < 2048u) atomicAdd(&lh[b2], 1u);
    uint b3 = (v.w >> 16) - lo; if (b3 < 2048u) atomicAdd(&lh[b3], 1u);
  }
  __syncthreads();
  uint* H = hist1 + (size_t)b * 65536 + lo;
  for (int i = threadIdx.x; i < 2048; i += 256) H[i] = lh[i];
}

// ---------- pass 2: exclusive scan of hist1 -> base[]; find boundary ----------
__global__ __launch_bounds__(1024) void scan_base(const uint* __restrict__ hist,
                                                  uint* __restrict__ base,
                                                  uint* __restrict__ hdr) {
  int b = blockIdx.x, tid = threadIdx.x, lane = tid & 63, W = tid >> 6;
  const uint* h = hist + (size_t)b * 65536;
  const uint4* h4 = (const uint4*)h + tid * 16;
  uint* bs = base + (size_t)b * 65536;
  uint s = 0;
  #pragma unroll
  for (int k = 0; k < 16; ++k) {
    uint4 v = h4[k];
    s += v.x + v.y + v.z + v.w;
  }
  // inclusive wave scan (no barriers)
  uint ps = s;
  #pragma unroll
  for (int off = 1; off < 64; off <<= 1) {
    uint v = __shfl_up(ps, off);
    if (lane >= off) ps += v;
  }
  __shared__ uint wsum[16];
  if (lane == 63) wsum[W] = ps;
  __syncthreads();
  if (tid < 16) {
    uint v = wsum[tid], pv = v;
    #pragma unroll
    for (int off = 1; off < 16; off <<= 1) {
      uint t = __shfl_up(pv, off, 16);
      if (tid >= off) pv += t;
    }
    wsum[tid] = pv;   // inclusive over waves
  }
  __syncthreads();
  uint wbase = (W > 0) ? wsum[W - 1] : 0u;
  uint incl = wbase + ps, excl = incl - s;
  uint total = wsum[15];
  uint target = total < (uint)PRE ? total : (uint)PRE;
  if (target > 0 && excl < target && target <= incl) {   // unique owner thread
    uint c = excl;
    #pragma unroll 1
    for (int k = 0; k < 64; ++k) {          // re-read own 64 bins (L2-hot)
      uint hv = h[tid * 64 + k];
      if (c < target && target <= c + hv) {
        hdr[0 + b] = (uint)(tid * 64 + k);   // t1 boundary bucket
        hdr[4 + b] = c + hv;                 // limit = cumulative through t1
        break;
      }
      c += hv;
    }
  }
  // write exclusive bases, vectorized (re-read hist, L2-hot)
  uint run = excl;
  uint4* bs4 = (uint4*)bs + tid * 16;
  #pragma unroll
  for (int k = 0; k < 16; ++k) {
    uint4 v = h4[k];
    uint4 o;
    o.x = run; run += v.x;
    o.y = run; run += v.y;
    o.z = run; run += v.z;
    o.w = run; run += v.w;
    bs4[k] = o;
  }
}

// ---------- pass 3: scatter elems of buckets <= t1 into bucket slots ----------
__global__ void bucket_scatter(const uint* __restrict__ keyhi,
                               uint* __restrict__ base,
                               const uint* __restrict__ hdr,
                               u64* __restrict__ buck) {
  int b = blockIdx.y;
  int i = blockIdx.x * 256 + threadIdx.x;
  if (i >= NN) return;
  uint kh = keyhi[(size_t)b * NN + i];
  if ((kh >> 16) <= hdr[0 + b]) {
    uint pos = atomicAdd(&base[(size_t)b * 65536 + (kh >> 16)], 1u);
    if (pos < SCAP) buck[(size_t)b * SCAP + pos] = ((u64)kh << 32) | (uint)i;
  }
}

// ---------- pass 4: exact rank within bucket -> scatter to sorted[] ----------
__global__ void rank_write(const u64* __restrict__ buck,
                           const uint* __restrict__ base,
                           const uint* __restrict__ hist,
                           const uint* __restrict__ hdr,
                           u64* __restrict__ sorted) {
  int b = blockIdx.y;
  int s = blockIdx.x * 256 + threadIdx.x;
  uint limit = hdr[4 + b];
  if (s >= (int)limit) return;
  u64 v = buck[(size_t)b * SCAP + s];
  uint bkt = (uint)(v >> 48);
  uint cnt = hist[(size_t)b * 65536 + bkt];
  uint b0 = base[(size_t)b * 65536 + bkt] - cnt;   // restore pre-scatter base
  uint r = b0;
  for (uint m = 0; m < cnt; ++m) {
    u64 w = buck[(size_t)b * SCAP + b0 + m];
    r += (w < v) ? 1u : 0u;                        // (key,idx) stable order
  }
  if (r < (uint)PRE) sorted[(size_t)b * SCAP + r] = v;
}

// ---------- pass 5: gather top-6000 boxes/scores/areas + validW ----------
// Every sorted[r], r<PRE is always written by rank_write (limit >= PRE).
__global__ __launch_bounds__(1024) void gather6k(const u64* __restrict__ sorted,
                                                 const float4* __restrict__ props,
                                                 const float2* __restrict__ clsp,
                                                 float4* __restrict__ boxes6k,
                                                 float* __restrict__ score6k,
                                                 float* __restrict__ area6k,
                                                 u64* __restrict__ validW) {
  int b = blockIdx.y;
  int j = blockIdx.x * 1024 + threadIdx.x;    // 0..6143
  int lane = threadIdx.x & 63;
  u64 v = sorted[(size_t)b * SCAP + j];
  bool has = (j < PRE);
  bool valid = false; float sc = -INFINITY, ar = 0.0f;
  float4 bx; bx.x = bx.y = bx.z = bx.w = 0.0f;
  if (has) {
    uint idx = (uint)(v & 0xFFFFFFFFull);
    float4 p = props[(size_t)b * NN + idx];
    float x1 = clipf(p.x, 800.0f), y1 = clipf(p.y, 800.0f);
    float x2 = clipf(p.z, 800.0f), y2 = clipf(p.w, 800.0f);
    float w = x2 - x1, h = y2 - y1;
    valid = (w >= 16.0f) && (h >= 16.0f);
    sc = clsp[(size_t)b * NN + idx].y;
    bx.x = x1; bx.y = y1; bx.z = x2; bx.w = y2;
    ar = fmaxf(w, 0.0f) * fmaxf(h, 0.0f);
  }
  if (j < ROWP) {
    boxes6k[(size_t)b * ROWP + j] = bx;
    score6k[(size_t)b * ROWP + j] = sc;
    area6k [(size_t)b * ROWP + j] = ar;
  }
  u64 mb = __ballot(valid);
  if (lane == 0) validW[(size_t)b * 96 + (j >> 6)] = mb;   // bit=1 => valid
}

// ---------- pass 6: sparse suppressor-list build (division-free exact test) ----
// fl32(inter/un) > 0.7f  <=>  inter/un >= mid, mid = 0.7f + 2^-25 =
// 0x1.6666668p-1 (the rounding midpoint; the tie rounds-to-even UP to
// 0x3F333334 > 0.7f, so >= mid is the exact condition).
// (double)inter >= mid*(double)un evaluates it EXACTLY: 25b x 24b mantissa
// product = 49 bits <= 53, conversions exact, un > 0.
__global__ __launch_bounds__(256) void sup_build(const float4* __restrict__ boxes6k,
                                                 const float* __restrict__ area6k,
                                                 const u64* __restrict__ validW,
                                                 uint* __restrict__ cnt,
                                                 uint* __restrict__ list) {
  int gb = blockIdx.y, b = blockIdx.z;
  int sub = threadIdx.x >> 6, t = threadIdx.x & 63;
  int cb = blockIdx.x * 4 + sub;
  __shared__ float4 rbox[64];
  __shared__ float  rar[64];
  if (threadIdx.x < 64) {
    rbox[t] = boxes6k[(size_t)b * ROWP + gb * 64 + t];
    rar[t]  = area6k [(size_t)b * ROWP + gb * 64 + t];
  }
  __syncthreads();
  if (cb >= NWRD || cb < gb) return;
  u64 vmask = validW[(size_t)b * 96 + gb];
  // row<col hoisted: strict-upper tiles take all rows; diagonal masks r < t.
  u64 rowsel = (cb == gb) ? (t ? (vmask & ((1ull << t) - 1ull)) : 0ull) : vmask;
  int col = cb * 64 + t;
  float4 c = boxes6k[(size_t)b * ROWP + col];
  float ca = area6k[(size_t)b * ROWP + col];
  const double M = 0x1.6666668p-1;   // exact decision midpoint for (iou > 0.7f)
  int rbase = gb * 64;
  u64 bits = 0;
  #pragma unroll 8
  for (int r = 0; r < 64; ++r) {
    float4 rb = rbox[r];
    float xx1 = fmaxf(rb.x, c.x), yy1 = fmaxf(rb.y, c.y);
    float xx2 = fminf(rb.z, c.z), yy2 = fminf(rb.w, c.w);
    float inter = fmaxf(xx2 - xx1, 0.0f) * fmaxf(yy2 - yy1, 0.0f);
    float un = fmaxf(rar[r] + ca - inter, 1e-9f);
    if (((rowsel >> r) & 1ull) && ((double)inter >= M * (double)un))
      bits |= (1ull << r);
  }
  while (bits) {
    int r = __ffsll((long long)bits) - 1;
    bits &= bits - 1;
    uint pos = atomicAdd(&cnt[(size_t)b * ROWP + col], 1u);
    if (pos < KSUP) list[((size_t)b * ROWP + col) * KSUP + pos] = (uint)(rbase + r);
  }
}

// ---------- pass 7: sparse Jacobi fixpoint resolve + fused finalize ----------
__global__ __launch_bounds__(1024) void sparse_resolve(const uint* __restrict__ cnt,
                                                       const uint* __restrict__ list,
                                                       const u64* __restrict__ validW,
                                                       const float* __restrict__ score6k,
                                                       const float4* __restrict__ boxes6k,
                                                       float* __restrict__ out) {
  int b = blockIdx.x, tid = threadIdx.x;
  __shared__ u64 ALIVE[96], DEC[96], VW[96];
  __shared__ int changed;
  if (tid < 96) {
    ALIVE[tid] = 0ull; DEC[tid] = 0ull;
    VW[tid] = validW[(size_t)b * 96 + tid];
  }
  __syncthreads();

  uint myCnt[6];
  #pragma unroll
  for (int r = 0; r < 6; ++r) {
    int j = tid + r * 1024;
    myCnt[r] = (j < PRE) ? cnt[(size_t)b * ROWP + j] : 0u;
  }
  // init: cnt==0 or invalid boxes decide immediately
  #pragma unroll
  for (int r = 0; r < 6; ++r) {
    int j = tid + r * 1024;
    if (j >= PRE) continue;
    bool valid = (VW[j >> 6] >> (j & 63)) & 1ull;
    if (myCnt[r] == 0u || !valid) {
      atomicOr(&DEC[j >> 6], 1ull << (j & 63));
      if (valid) atomicOr(&ALIVE[j >> 6], 1ull << (j & 63));
    }
  }
  __syncthreads();

  // fixpoint rounds (terminates: lowest undecided box always decides)
  while (true) {
    if (tid == 0) changed = 0;
    __syncthreads();
    // compute phase (state is stable)
    int decJ[6]; bool decAlive[6];
    #pragma unroll
    for (int r = 0; r < 6; ++r) {
      decJ[r] = -1; decAlive[r] = false;
      int j = tid + r * 1024;
      if (j >= PRE || myCnt[r] == 0u) continue;
      if ((DEC[j >> 6] >> (j & 63)) & 1ull) continue;
      const uint* lj = list + ((size_t)b * ROWP + j) * KSUP;
      uint c = myCnt[r] < KSUP ? myCnt[r] : KSUP;
      bool anyAlive = false, pending = false;
      for (uint m = 0; m < c; ++m) {
        uint i = lj[m];
        bool ai = (ALIVE[i >> 6] >> (i & 63)) & 1ull;
        bool di = (DEC[i >> 6] >> (i & 63)) & 1ull;
        if (ai) { anyAlive = true; break; }
        if (!di) pending = true;
      }
      if (anyAlive)      { decJ[r] = j; decAlive[r] = false; }
      else if (!pending) { decJ[r] = j; decAlive[r] = true;  }
    }
    __syncthreads();
    // apply phase
    bool any = false;
    #pragma unroll
    for (int r = 0; r < 6; ++r) {
      if (decJ[r] >= 0) {
        int j = decJ[r];
        if (decAlive[r]) atomicOr(&ALIVE[j >> 6], 1ull << (j & 63));
        atomicOr(&DEC[j >> 6], 1ull << (j & 63));
        any = true;
      }
    }
    if (any) atomicAdd(&changed, 1);
    __syncthreads();
    if (changed == 0) break;
  }

  // ---- fused finalize: rank kept, emit first 1000 ----
  __shared__ uint pre[NWRD + 1];
  if (tid == 0) {
    uint c = 0;
    for (int w = 0; w < NWRD; ++w) { pre[w] = c; c += (uint)__popcll(ALIVE[w]); }
    pre[NWRD] = c;
  }
  __syncthreads();
  for (int q = tid; q < POST; q += 1024) out[(size_t)b * POST + q] = 0.0f;
  for (int t = tid; t < POST * 4; t += 1024) out[(size_t)BB * POST + (size_t)b * POST * 4 + t] = 0.0f;
  __syncthreads();
  for (int j = tid; j < PRE; j += 1024) {
    int w = j >> 6, bit = j & 63;
    u64 word = ALIVE[w];
    if ((word >> bit) & 1ull) {
      uint rank = pre[w] + (uint)__popcll(word & ((1ull << bit) - 1ull));
      if (rank < POST) {
        out[(size_t)b * POST + rank] = score6k[(size_t)b * ROWP + j];
        float4 bx = boxes6k[(size_t)b * ROWP + j];
        float* o = out + (size_t)BB * POST + ((size_t)b * POST + rank) * 4;
        o[0] = bx.x; o[1] = bx.y; o[2] = bx.z; o[3] = bx.w;
      }
    }
  }
}

extern "C" void kernel_launch(void* const* d_in, const int* in_sizes, int n_in,
                              void* d_out, int out_size, void* d_ws, size_t ws_size,
                              hipStream_t stream) {
  const float4* props = (const float4*)d_in[0];
  const float2* clsp  = (const float2*)d_in[1];
  float* out = (float*)d_out;
  char* ws = (char*)d_ws;

  uint*   hdr     = (uint*)(ws + OFF_HDR);
  uint*   cnt     = (uint*)(ws + OFF_CNT);
  uint*   hist1   = (uint*)(ws + OFF_H1);
  uint*   base    = (uint*)(ws + OFF_BASE);
  uint*   keyhi   = (uint*)(ws + OFF_KEY);
  u64*    buck    = (u64*) (ws + OFF_BUCK);
  u64*    sorted  = (u64*) (ws + OFF_SORT);
  uint*   list    = (uint*)(ws + OFF_LIST);
  float4* boxes6k = (float4*)(ws + OFF_BOX);
  float*  score6k = (float*)(ws + OFF_SCO);
  float*  area6k  = (float*)(ws + OFF_AREA);
  u64*    validW  = (u64*) (ws + OFF_VAL);

  // zero hdr+cnt only (hist1/base are fully overwritten each call)
  int nz4 = (int)(OFF_H1 / 16);
  zero_fill<<<60, 256, 0, stream>>>((uint4*)ws, nz4);

  dim3 gN((NN + 255) / 256, BB);
  keys_only<<<gN, 256, 0, stream>>>(props, clsp, keyhi);
  hist_range<<<dim3(NRANGE, BB), 256, 0, stream>>>((const uint4*)keyhi, hist1);
  scan_base<<<BB, 1024, 0, stream>>>(hist1, base, hdr);
  bucket_scatter<<<gN, 256, 0, stream>>>(keyhi, base, hdr, buck);
  rank_write<<<dim3(SCAP / 256, BB), 256, 0, stream>>>(buck, base, hist1, hdr, sorted);
  gather6k<<<dim3(6, BB), 1024, 0, stream>>>(sorted, props, clsp, boxes6k, score6k, area6k, validW);
  sup_build<<<dim3((NWRD + 3) / 4, NWRD, BB), 256, 0, stream>>>(boxes6k, area6k, validW, cnt, list);
  sparse_resolve<<<BB, 1024, 0, stream>>>(cnt, list, validW, score6k, boxes6k, out);
}

// Round 10
// 245.844 us; speedup vs baseline: 10.7575x; 1.0547x over previous
//
#include <hip/hip_runtime.h>
#include <hip/hip_bf16.h>
#include <math.h>

typedef unsigned int uint;
typedef unsigned long long u64;

#define BB 4
#define NN 100000
#define PRE 6000
#define POST 1000
#define NWRD 94          // 6000/64 rounded up
#define SCAP 8192        // bucketed capacity
#define ROWP 6016        // padded rows/cols
#define KSUP 64          // max suppressors tracked per box
#define NRANGE 32        // hist range-blocks per image (2048 bins each)

// ---- workspace layout (bytes) ----
constexpr size_t OFF_HDR   = 0;                                    // 16 uints: t1[4], limit[4]
constexpr size_t OFF_CNT   = 1024;                                 // BB*ROWP*4 (zeroed by hist_range)
constexpr size_t OFF_H1    = OFF_CNT + (size_t)BB*ROWP*4;          // hist1: 1MB (fully overwritten)
constexpr size_t OFF_BASE  = OFF_H1  + (size_t)BB*65536*4;         // base:  1MB (fully overwritten)
constexpr size_t OFF_KEY   = OFF_BASE+ (size_t)BB*65536*4;         // keyhi: BB*NN*4
constexpr size_t OFF_BUCK  = OFF_KEY + (size_t)BB*NN*4;            // BB*SCAP*8
constexpr size_t OFF_LIST  = OFF_BUCK+ (size_t)BB*SCAP*8;          // BB*ROWP*KSUP*4 ~= 6.2MB
constexpr size_t OFF_BOX   = OFF_LIST+ (size_t)BB*ROWP*KSUP*4;
constexpr size_t OFF_SCO   = OFF_BOX + (size_t)BB*ROWP*16;
constexpr size_t OFF_AREA  = OFF_SCO + (size_t)BB*ROWP*4;
constexpr size_t OFF_VAL   = OFF_AREA+ (size_t)BB*ROWP*4;          // validW: BB*96*8 (zeroed by scan_base)
// total ~= 10.3 MB

__device__ __forceinline__ float clipf(float v, float hi) {
  return fminf(fmaxf(v, 0.0f), hi);
}

// ---------- pass 1a: keys only (pure streaming, no atomics) ----------
__global__ void keys_only(const float4* __restrict__ props,
                          const float2* __restrict__ clsp,
                          uint* __restrict__ keyhi) {
  int b = blockIdx.y;
  int i = blockIdx.x * 256 + threadIdx.x;
  if (i >= NN) return;
  float4 p = props[(size_t)b * NN + i];
  float x1 = clipf(p.x, 800.0f), y1 = clipf(p.y, 800.0f);
  float x2 = clipf(p.z, 800.0f), y2 = clipf(p.w, 800.0f);
  bool valid = ((x2 - x1) >= 16.0f) && ((y2 - y1) >= 16.0f);
  float s  = clsp[(size_t)b * NN + i].y;
  float sm = valid ? s : -INFINITY;
  uint u = __float_as_uint(sm);
  u = (u & 0x80000000u) ? ~u : (u | 0x80000000u);  // monotonic: ascending u == ascending score
  keyhi[(size_t)b * NN + i] = ~u;                   // ascending key == DESCENDING score
}

// ---------- pass 1b: range-partitioned histogram (LDS, zero global atomics) ----
// Block (r,b) owns bins [r*2048,(r+1)*2048). Tail also zeroes its slice of cnt.
__global__ __launch_bounds__(256) void hist_range(const uint4* __restrict__ keyhi4,
                                                  uint* __restrict__ hist1,
                                                  uint* __restrict__ cnt) {
  int b = blockIdx.y;
  uint lo = (uint)blockIdx.x << 11;     // 2048 bins per range block
  __shared__ uint lh[2048];
  for (int i = threadIdx.x; i < 2048; i += 256) lh[i] = 0u;
  __syncthreads();
  const uint4* K = keyhi4 + (size_t)b * (NN / 4);
  for (int i = threadIdx.x; i < NN / 4; i += 256) {
    uint4 v = K[i];
    uint b0 = (v.x >> 16) - lo; if (b0 < 2048u) atomicAdd(&lh[b0], 1u);
    uint b1 = (v.y >> 16) - lo; if (b1 < 2048u) atomicAdd(&lh[b1], 1u);
    uint b2 = (v.z >> 16) - lo; if (b2 < 2048u) atomicAdd(&lh[b2], 1u);
    uint b3 = (v.w >> 16) - lo; if (b3 < 2048u) atomicAdd(&lh[b3], 1u);
  }
  __syncthreads();
  uint* H = hist1 + (size_t)b * 65536 + lo;
  for (int i = threadIdx.x; i < 2048; i += 256) H[i] = lh[i];
  // zero this block's slice of cnt (ROWP = 32*188)
  uint* C = cnt + (size_t)b * ROWP + blockIdx.x * (ROWP / NRANGE);
  if (threadIdx.x < ROWP / NRANGE) C[threadIdx.x] = 0u;
}

// ---------- pass 2: exclusive scan of hist1 -> base[]; boundary; zero validW ----
__global__ __launch_bounds__(1024) void scan_base(const uint* __restrict__ hist,
                                                  uint* __restrict__ base,
                                                  uint* __restrict__ hdr,
                                                  u64* __restrict__ validW) {
  int b = blockIdx.x, tid = threadIdx.x, lane = tid & 63, W = tid >> 6;
  if (tid < 96) validW[(size_t)b * 96 + tid] = 0ull;
  const uint* h = hist + (size_t)b * 65536;
  const uint4* h4 = (const uint4*)h + tid * 16;
  uint* bs = base + (size_t)b * 65536;
  uint s = 0;
  #pragma unroll
  for (int k = 0; k < 16; ++k) {
    uint4 v = h4[k];
    s += v.x + v.y + v.z + v.w;
  }
  // inclusive wave scan (no barriers)
  uint ps = s;
  #pragma unroll
  for (int off = 1; off < 64; off <<= 1) {
    uint v = __shfl_up(ps, off);
    if (lane >= off) ps += v;
  }
  __shared__ uint wsum[16];
  if (lane == 63) wsum[W] = ps;
  __syncthreads();
  if (tid < 16) {
    uint v = wsum[tid], pv = v;
    #pragma unroll
    for (int off = 1; off < 16; off <<= 1) {
      uint t = __shfl_up(pv, off, 16);
      if (tid >= off) pv += t;
    }
    wsum[tid] = pv;   // inclusive over waves
  }
  __syncthreads();
  uint wbase = (W > 0) ? wsum[W - 1] : 0u;
  uint incl = wbase + ps, excl = incl - s;
  uint total = wsum[15];
  uint target = total < (uint)PRE ? total : (uint)PRE;
  if (target > 0 && excl < target && target <= incl) {   // unique owner thread
    uint c = excl;
    #pragma unroll 1
    for (int k = 0; k < 64; ++k) {          // re-read own 64 bins (L2-hot)
      uint hv = h[tid * 64 + k];
      if (c < target && target <= c + hv) {
        hdr[0 + b] = (uint)(tid * 64 + k);   // t1 boundary bucket
        hdr[4 + b] = c + hv;                 // limit = cumulative through t1
        break;
      }
      c += hv;
    }
  }
  // write exclusive bases, vectorized (re-read hist, L2-hot)
  uint run = excl;
  uint4* bs4 = (uint4*)bs + tid * 16;
  #pragma unroll
  for (int k = 0; k < 16; ++k) {
    uint4 v = h4[k];
    uint4 o;
    o.x = run; run += v.x;
    o.y = run; run += v.y;
    o.z = run; run += v.z;
    o.w = run; run += v.w;
    bs4[k] = o;
  }
}

// ---------- pass 3: scatter elems of buckets <= t1 into bucket slots ----------
__global__ void bucket_scatter(const uint* __restrict__ keyhi,
                               uint* __restrict__ base,
                               const uint* __restrict__ hdr,
                               u64* __restrict__ buck) {
  int b = blockIdx.y;
  int i = blockIdx.x * 256 + threadIdx.x;
  if (i >= NN) return;
  uint kh = keyhi[(size_t)b * NN + i];
  if ((kh >> 16) <= hdr[0 + b]) {
    uint pos = atomicAdd(&base[(size_t)b * 65536 + (kh >> 16)], 1u);
    if (pos < SCAP) buck[(size_t)b * SCAP + pos] = ((u64)kh << 32) | (uint)i;
  }
}

// ---------- pass 4: exact rank -> direct scatter of box/score/area/validW ----
// Fuses rank_write + gather6k: rank r < PRE is written exactly once (limit>=PRE),
// so boxes6k[r]/score6k[r]/area6k[r] rows [0,PRE) are fully defined. Rows
// [PRE,ROWP) stay garbage but validW bits there are 0 => masked everywhere.
__global__ void rank_scatter(const u64* __restrict__ buck,
                             const uint* __restrict__ base,
                             const uint* __restrict__ hist,
                             const uint* __restrict__ hdr,
                             const float4* __restrict__ props,
                             const float2* __restrict__ clsp,
                             float4* __restrict__ boxes6k,
                             float* __restrict__ score6k,
                             float* __restrict__ area6k,
                             u64* __restrict__ validW) {
  int b = blockIdx.y;
  int s = blockIdx.x * 256 + threadIdx.x;
  uint limit = hdr[4 + b];
  if (s >= (int)limit) return;
  u64 v = buck[(size_t)b * SCAP + s];
  uint bkt = (uint)(v >> 48);
  uint cntb = hist[(size_t)b * 65536 + bkt];
  uint b0 = base[(size_t)b * 65536 + bkt] - cntb;  // restore pre-scatter base
  uint r = b0;
  for (uint m = 0; m < cntb; ++m) {
    u64 w = buck[(size_t)b * SCAP + b0 + m];
    r += (w < v) ? 1u : 0u;                        // (key,idx) stable order
  }
  if (r >= (uint)PRE) return;
  uint idx = (uint)(v & 0xFFFFFFFFull);
  float4 p = props[(size_t)b * NN + idx];
  float x1 = clipf(p.x, 800.0f), y1 = clipf(p.y, 800.0f);
  float x2 = clipf(p.z, 800.0f), y2 = clipf(p.w, 800.0f);
  float w = x2 - x1, h = y2 - y1;
  bool valid = (w >= 16.0f) && (h >= 16.0f);
  float4 bx; bx.x = x1; bx.y = y1; bx.z = x2; bx.w = y2;
  boxes6k[(size_t)b * ROWP + r] = bx;
  score6k[(size_t)b * ROWP + r] = clsp[(size_t)b * NN + idx].y;
  area6k [(size_t)b * ROWP + r] = fmaxf(w, 0.0f) * fmaxf(h, 0.0f);
  if (valid) atomicOr(&validW[(size_t)b * 96 + (r >> 6)], 1ull << (r & 63));
}

// ---------- pass 5: sparse suppressor-list build (division-free exact test) ----
// fl32(inter/un) > 0.7f  <=>  inter/un >= mid, mid = 0.7f + 2^-25 =
// 0x1.6666668p-1 (rounding midpoint; the tie rounds-to-even UP).
// (double)inter >= mid*(double)un is EXACT: 25b x 24b = 49 bits <= 53.
__global__ __launch_bounds__(256) void sup_build(const float4* __restrict__ boxes6k,
                                                 const float* __restrict__ area6k,
                                                 const u64* __restrict__ validW,
                                                 uint* __restrict__ cnt,
                                                 uint* __restrict__ list) {
  int gb = blockIdx.y, b = blockIdx.z;
  int sub = threadIdx.x >> 6, t = threadIdx.x & 63;
  int cb = blockIdx.x * 4 + sub;
  __shared__ float4 rbox[64];
  __shared__ float  rar[64];
  if (threadIdx.x < 64) {
    rbox[t] = boxes6k[(size_t)b * ROWP + gb * 64 + t];
    rar[t]  = area6k [(size_t)b * ROWP + gb * 64 + t];
  }
  __syncthreads();
  if (cb >= NWRD || cb < gb) return;
  u64 vmask = validW[(size_t)b * 96 + gb];
  // row<col + valid applied AFTER the loop (bits &= rowsel)
  u64 rowsel = (cb == gb) ? (t ? (vmask & ((1ull << t) - 1ull)) : 0ull) : vmask;
  int col = cb * 64 + t;
  float4 c = boxes6k[(size_t)b * ROWP + col];
  float ca = area6k[(size_t)b * ROWP + col];
  const double M = 0x1.6666668p-1;   // exact decision midpoint for (iou > 0.7f)
  int rbase = gb * 64;
  u64 bits = 0;
  #pragma unroll 16
  for (int r = 0; r < 64; ++r) {
    float4 rb = rbox[r];
    float xx1 = fmaxf(rb.x, c.x), yy1 = fmaxf(rb.y, c.y);
    float xx2 = fminf(rb.z, c.z), yy2 = fminf(rb.w, c.w);
    float inter = fmaxf(xx2 - xx1, 0.0f) * fmaxf(yy2 - yy1, 0.0f);
    float un = fmaxf(rar[r] + ca - inter, 1e-9f);
    bits |= ((double)inter >= M * (double)un) ? (1ull << r) : 0ull;
  }
  bits &= rowsel;
  while (bits) {
    int r = __ffsll((long long)bits) - 1;
    bits &= bits - 1;
    uint pos = atomicAdd(&cnt[(size_t)b * ROWP + col], 1u);
    if (pos < KSUP) list[((size_t)b * ROWP + col) * KSUP + pos] = (uint)(rbase + r);
  }
}

// ---------- pass 6: sparse Jacobi fixpoint resolve + fused finalize ----------
__global__ __launch_bounds__(1024) void sparse_resolve(const uint* __restrict__ cnt,
                                                       const uint* __restrict__ list,
                                                       const u64* __restrict__ validW,
                                                       const float* __restrict__ score6k,
                                                       const float4* __restrict__ boxes6k,
                                                       float* __restrict__ out) {
  int b = blockIdx.x, tid = threadIdx.x;
  __shared__ u64 ALIVE[96], DEC[96], VW[96];
  __shared__ int changed;
  if (tid < 96) {
    ALIVE[tid] = 0ull; DEC[tid] = 0ull;
    VW[tid] = validW[(size_t)b * 96 + tid];
  }
  __syncthreads();

  uint myCnt[6];
  #pragma unroll
  for (int r = 0; r < 6; ++r) {
    int j = tid + r * 1024;
    myCnt[r] = (j < PRE) ? cnt[(size_t)b * ROWP + j] : 0u;
  }
  // init: cnt==0 or invalid boxes decide immediately
  #pragma unroll
  for (int r = 0; r < 6; ++r) {
    int j = tid + r * 1024;
    if (j >= PRE) continue;
    bool valid = (VW[j >> 6] >> (j & 63)) & 1ull;
    if (myCnt[r] == 0u || !valid) {
      atomicOr(&DEC[j >> 6], 1ull << (j & 63));
      if (valid) atomicOr(&ALIVE[j >> 6], 1ull << (j & 63));
    }
  }
  __syncthreads();

  // fixpoint rounds (terminates: lowest undecided box always decides)
  while (true) {
    if (tid == 0) changed = 0;
    __syncthreads();
    // compute phase (state is stable)
    int decJ[6]; bool decAlive[6];
    #pragma unroll
    for (int r = 0; r < 6; ++r) {
      decJ[r] = -1; decAlive[r] = false;
      int j = tid + r * 1024;
      if (j >= PRE || myCnt[r] == 0u) continue;
      if ((DEC[j >> 6] >> (j & 63)) & 1ull) continue;
      const uint* lj = list + ((size_t)b * ROWP + j) * KSUP;
      uint c = myCnt[r] < KSUP ? myCnt[r] : KSUP;
      bool anyAlive = false, pending = false;
      for (uint m = 0; m < c; ++m) {
        uint i = lj[m];
        bool ai = (ALIVE[i >> 6] >> (i & 63)) & 1ull;
        bool di = (DEC[i >> 6] >> (i & 63)) & 1ull;
        if (ai) { anyAlive = true; break; }
        if (!di) pending = true;
      }
      if (anyAlive)      { decJ[r] = j; decAlive[r] = false; }
      else if (!pending) { decJ[r] = j; decAlive[r] = true;  }
    }
    __syncthreads();
    // apply phase
    bool any = false;
    #pragma unroll
    for (int r = 0; r < 6; ++r) {
      if (decJ[r] >= 0) {
        int j = decJ[r];
        if (decAlive[r]) atomicOr(&ALIVE[j >> 6], 1ull << (j & 63));
        atomicOr(&DEC[j >> 6], 1ull << (j & 63));
        any = true;
      }
    }
    if (any) atomicAdd(&changed, 1);
    __syncthreads();
    if (changed == 0) break;
  }

  // ---- fused finalize: rank kept, emit first 1000 ----
  __shared__ uint pre[NWRD + 1];
  if (tid == 0) {
    uint c = 0;
    for (int w = 0; w < NWRD; ++w) { pre[w] = c; c += (uint)__popcll(ALIVE[w]); }
    pre[NWRD] = c;
  }
  __syncthreads();
  for (int q = tid; q < POST; q += 1024) out[(size_t)b * POST + q] = 0.0f;
  for (int t = tid; t < POST * 4; t += 1024) out[(size_t)BB * POST + (size_t)b * POST * 4 + t] = 0.0f;
  __syncthreads();
  for (int j = tid; j < PRE; j += 1024) {
    int w = j >> 6, bit = j & 63;
    u64 word = ALIVE[w];
    if ((word >> bit) & 1ull) {
      uint rank = pre[w] + (uint)__popcll(word & ((1ull << bit) - 1ull));
      if (rank < POST) {
        out[(size_t)b * POST + rank] = score6k[(size_t)b * ROWP + j];
        float4 bx = boxes6k[(size_t)b * ROWP + j];
        float* o = out + (size_t)BB * POST + ((size_t)b * POST + rank) * 4;
        o[0] = bx.x; o[1] = bx.y; o[2] = bx.z; o[3] = bx.w;
      }
    }
  }
}

extern "C" void kernel_launch(void* const* d_in, const int* in_sizes, int n_in,
                              void* d_out, int out_size, void* d_ws, size_t ws_size,
                              hipStream_t stream) {
  const float4* props = (const float4*)d_in[0];
  const float2* clsp  = (const float2*)d_in[1];
  float* out = (float*)d_out;
  char* ws = (char*)d_ws;

  uint*   hdr     = (uint*)(ws + OFF_HDR);
  uint*   cnt     = (uint*)(ws + OFF_CNT);
  uint*   hist1   = (uint*)(ws + OFF_H1);
  uint*   base    = (uint*)(ws + OFF_BASE);
  uint*   keyhi   = (uint*)(ws + OFF_KEY);
  u64*    buck    = (u64*) (ws + OFF_BUCK);
  uint*   list    = (uint*)(ws + OFF_LIST);
  float4* boxes6k = (float4*)(ws + OFF_BOX);
  float*  score6k = (float*)(ws + OFF_SCO);
  float*  area6k  = (float*)(ws + OFF_AREA);
  u64*    validW  = (u64*) (ws + OFF_VAL);

  dim3 gN((NN + 255) / 256, BB);
  keys_only<<<gN, 256, 0, stream>>>(props, clsp, keyhi);
  hist_range<<<dim3(NRANGE, BB), 256, 0, stream>>>((const uint4*)keyhi, hist1, cnt);
  scan_base<<<BB, 1024, 0, stream>>>(hist1, base, hdr, validW);
  bucket_scatter<<<gN, 256, 0, stream>>>(keyhi, base, hdr, buck);
  rank_scatter<<<dim3(SCAP / 256, BB), 256, 0, stream>>>(buck, base, hist1, hdr,
                                                         props, clsp, boxes6k,
                                                         score6k, area6k, validW);
  sup_build<<<dim3((NWRD + 3) / 4, NWRD, BB), 256, 0, stream>>>(boxes6k, area6k,
                                                                validW, cnt, list);
  sparse_resolve<<<BB, 1024, 0, stream>>>(cnt, list, validW, score6k, boxes6k, out);
}

// Round 11
// 242.969 us; speedup vs baseline: 10.8848x; 1.0118x over previous
//
#include <hip/hip_runtime.h>
#include <hip/hip_bf16.h>
#include <math.h>

typedef unsigned int uint;
typedef unsigned long long u64;

#define BB 4
#define NN 100000
#define PRE 6000
#define POST 1000
#define NWRD 94          // 6000/64 rounded up
#define SCAP 8192        // bucketed capacity
#define ROWP 6016        // padded rows/cols
#define KSUP 64          // max suppressors tracked per box
#define NRANGE 32        // hist range-blocks per image (2048 bins each)
#define WQ 16            // col-words per sup_build block

// ---- workspace layout (bytes) ----
constexpr size_t OFF_HDR   = 0;                                    // 16 uints: t1[4], limit[4]
constexpr size_t OFF_CNT   = 1024;                                 // BB*ROWP*4 (zeroed by hist_range)
constexpr size_t OFF_H1    = OFF_CNT + (size_t)BB*ROWP*4;          // hist1: 1MB (fully overwritten)
constexpr size_t OFF_BASE  = OFF_H1  + (size_t)BB*65536*4;         // base:  1MB (fully overwritten)
constexpr size_t OFF_KEY   = OFF_BASE+ (size_t)BB*65536*4;         // keyhi: BB*NN*4
constexpr size_t OFF_BUCK  = OFF_KEY + (size_t)BB*NN*4;            // BB*SCAP*8
constexpr size_t OFF_LIST  = OFF_BUCK+ (size_t)BB*SCAP*8;          // BB*ROWP*KSUP*4 ~= 6.2MB
constexpr size_t OFF_BOX   = OFF_LIST+ (size_t)BB*ROWP*KSUP*4;
constexpr size_t OFF_SCO   = OFF_BOX + (size_t)BB*ROWP*16;
constexpr size_t OFF_AREA  = OFF_SCO + (size_t)BB*ROWP*4;
constexpr size_t OFF_VAL   = OFF_AREA+ (size_t)BB*ROWP*4;          // validW: BB*96*8 (zeroed by scan_base)
// total ~= 10.3 MB

__device__ __forceinline__ float clipf(float v, float hi) {
  return fminf(fmaxf(v, 0.0f), hi);
}

// ---------- pass 1a: keys only (pure streaming, no atomics) ----------
__global__ void keys_only(const float4* __restrict__ props,
                          const float2* __restrict__ clsp,
                          uint* __restrict__ keyhi) {
  int b = blockIdx.y;
  int i = blockIdx.x * 256 + threadIdx.x;
  if (i >= NN) return;
  float4 p = props[(size_t)b * NN + i];
  float x1 = clipf(p.x, 800.0f), y1 = clipf(p.y, 800.0f);
  float x2 = clipf(p.z, 800.0f), y2 = clipf(p.w, 800.0f);
  bool valid = ((x2 - x1) >= 16.0f) && ((y2 - y1) >= 16.0f);
  float s  = clsp[(size_t)b * NN + i].y;
  float sm = valid ? s : -INFINITY;
  uint u = __float_as_uint(sm);
  u = (u & 0x80000000u) ? ~u : (u | 0x80000000u);  // monotonic: ascending u == ascending score
  keyhi[(size_t)b * NN + i] = ~u;                   // ascending key == DESCENDING score
}

// ---------- pass 1b: range-partitioned histogram (LDS, zero global atomics) ----
// Block (r,b) owns bins [r*2048,(r+1)*2048). Tail also zeroes its slice of cnt.
__global__ __launch_bounds__(256) void hist_range(const uint4* __restrict__ keyhi4,
                                                  uint* __restrict__ hist1,
                                                  uint* __restrict__ cnt) {
  int b = blockIdx.y;
  uint lo = (uint)blockIdx.x << 11;     // 2048 bins per range block
  __shared__ uint lh[2048];
  for (int i = threadIdx.x; i < 2048; i += 256) lh[i] = 0u;
  __syncthreads();
  const uint4* K = keyhi4 + (size_t)b * (NN / 4);
  for (int i = threadIdx.x; i < NN / 4; i += 256) {
    uint4 v = K[i];
    uint b0 = (v.x >> 16) - lo; if (b0 < 2048u) atomicAdd(&lh[b0], 1u);
    uint b1 = (v.y >> 16) - lo; if (b1 < 2048u) atomicAdd(&lh[b1], 1u);
    uint b2 = (v.z >> 16) - lo; if (b2 < 2048u) atomicAdd(&lh[b2], 1u);
    uint b3 = (v.w >> 16) - lo; if (b3 < 2048u) atomicAdd(&lh[b3], 1u);
  }
  __syncthreads();
  uint* H = hist1 + (size_t)b * 65536 + lo;
  for (int i = threadIdx.x; i < 2048; i += 256) H[i] = lh[i];
  // zero this block's slice of cnt (ROWP = 32*188)
  uint* C = cnt + (size_t)b * ROWP + blockIdx.x * (ROWP / NRANGE);
  if (threadIdx.x < ROWP / NRANGE) C[threadIdx.x] = 0u;
}

// ---------- pass 2: exclusive scan of hist1 -> base[]; boundary; zero validW ----
__global__ __launch_bounds__(1024) void scan_base(const uint* __restrict__ hist,
                                                  uint* __restrict__ base,
                                                  uint* __restrict__ hdr,
                                                  u64* __restrict__ validW) {
  int b = blockIdx.x, tid = threadIdx.x, lane = tid & 63, W = tid >> 6;
  if (tid < 96) validW[(size_t)b * 96 + tid] = 0ull;
  const uint* h = hist + (size_t)b * 65536;
  const uint4* h4 = (const uint4*)h + tid * 16;
  uint* bs = base + (size_t)b * 65536;
  uint s = 0;
  #pragma unroll
  for (int k = 0; k < 16; ++k) {
    uint4 v = h4[k];
    s += v.x + v.y + v.z + v.w;
  }
  // inclusive wave scan (no barriers)
  uint ps = s;
  #pragma unroll
  for (int off = 1; off < 64; off <<= 1) {
    uint v = __shfl_up(ps, off);
    if (lane >= off) ps += v;
  }
  __shared__ uint wsum[16];
  if (lane == 63) wsum[W] = ps;
  __syncthreads();
  if (tid < 16) {
    uint v = wsum[tid], pv = v;
    #pragma unroll
    for (int off = 1; off < 16; off <<= 1) {
      uint t = __shfl_up(pv, off, 16);
      if (tid >= off) pv += t;
    }
    wsum[tid] = pv;   // inclusive over waves
  }
  __syncthreads();
  uint wbase = (W > 0) ? wsum[W - 1] : 0u;
  uint incl = wbase + ps, excl = incl - s;
  uint total = wsum[15];
  uint target = total < (uint)PRE ? total : (uint)PRE;
  if (target > 0 && excl < target && target <= incl) {   // unique owner thread
    uint c = excl;
    #pragma unroll 1
    for (int k = 0; k < 64; ++k) {          // re-read own 64 bins (L2-hot)
      uint hv = h[tid * 64 + k];
      if (c < target && target <= c + hv) {
        hdr[0 + b] = (uint)(tid * 64 + k);   // t1 boundary bucket
        hdr[4 + b] = c + hv;                 // limit = cumulative through t1
        break;
      }
      c += hv;
    }
  }
  // write exclusive bases, vectorized (re-read hist, L2-hot)
  uint run = excl;
  uint4* bs4 = (uint4*)bs + tid * 16;
  #pragma unroll
  for (int k = 0; k < 16; ++k) {
    uint4 v = h4[k];
    uint4 o;
    o.x = run; run += v.x;
    o.y = run; run += v.y;
    o.z = run; run += v.z;
    o.w = run; run += v.w;
    bs4[k] = o;
  }
}

// ---------- pass 3: scatter elems of buckets <= t1 into bucket slots ----------
__global__ void bucket_scatter(const uint* __restrict__ keyhi,
                               uint* __restrict__ base,
                               const uint* __restrict__ hdr,
                               u64* __restrict__ buck) {
  int b = blockIdx.y;
  int i = blockIdx.x * 256 + threadIdx.x;
  if (i >= NN) return;
  uint kh = keyhi[(size_t)b * NN + i];
  if ((kh >> 16) <= hdr[0 + b]) {
    uint pos = atomicAdd(&base[(size_t)b * 65536 + (kh >> 16)], 1u);
    if (pos < SCAP) buck[(size_t)b * SCAP + pos] = ((u64)kh << 32) | (uint)i;
  }
}

// ---------- pass 4: exact rank -> direct scatter of box/score/area/validW ----
__global__ void rank_scatter(const u64* __restrict__ buck,
                             const uint* __restrict__ base,
                             const uint* __restrict__ hist,
                             const uint* __restrict__ hdr,
                             const float4* __restrict__ props,
                             const float2* __restrict__ clsp,
                             float4* __restrict__ boxes6k,
                             float* __restrict__ score6k,
                             float* __restrict__ area6k,
                             u64* __restrict__ validW) {
  int b = blockIdx.y;
  int s = blockIdx.x * 256 + threadIdx.x;
  uint limit = hdr[4 + b];
  if (s >= (int)limit) return;
  u64 v = buck[(size_t)b * SCAP + s];
  uint bkt = (uint)(v >> 48);
  uint cntb = hist[(size_t)b * 65536 + bkt];
  uint b0 = base[(size_t)b * 65536 + bkt] - cntb;  // restore pre-scatter base
  uint r = b0;
  for (uint m = 0; m < cntb; ++m) {
    u64 w = buck[(size_t)b * SCAP + b0 + m];
    r += (w < v) ? 1u : 0u;                        // (key,idx) stable order
  }
  if (r >= (uint)PRE) return;
  uint idx = (uint)(v & 0xFFFFFFFFull);
  float4 p = props[(size_t)b * NN + idx];
  float x1 = clipf(p.x, 800.0f), y1 = clipf(p.y, 800.0f);
  float x2 = clipf(p.z, 800.0f), y2 = clipf(p.w, 800.0f);
  float w = x2 - x1, h = y2 - y1;
  bool valid = (w >= 16.0f) && (h >= 16.0f);
  float4 bx; bx.x = x1; bx.y = y1; bx.z = x2; bx.w = y2;
  boxes6k[(size_t)b * ROWP + r] = bx;
  score6k[(size_t)b * ROWP + r] = clsp[(size_t)b * NN + idx].y;
  area6k [(size_t)b * ROWP + r] = fmaxf(w, 0.0f) * fmaxf(h, 0.0f);
  if (valid) atomicOr(&validW[(size_t)b * 96 + (r >> 6)], 1ull << (r & 63));
}

// ---------- pass 5: sparse suppressor-list build, 4-col ILP blocking ----------
// Per thread: 4 columns (4 independent IoU dependency chains) vs the 64-row
// tile; row box read once per 4 pairs. Exact division-free test:
// fl32(inter/un) > 0.7f  <=>  (double)inter >= mid*(double)un,
// mid = 0.7f + 2^-25 = 0x1.6666668p-1 (25b x 24b = 49 bits, exact).
__global__ __launch_bounds__(256) void sup_build(const float4* __restrict__ boxes6k,
                                                 const float* __restrict__ area6k,
                                                 const u64* __restrict__ validW,
                                                 uint* __restrict__ cnt,
                                                 uint* __restrict__ list) {
  int gb = blockIdx.y, b = blockIdx.z;
  int cw0 = blockIdx.x * WQ;
  if (cw0 + WQ - 1 < gb) return;       // block fully below the diagonal
  int w = threadIdx.x >> 6, lane = threadIdx.x & 63;
  __shared__ float4 rbox[64];
  __shared__ float  rar[64];
  if (threadIdx.x < 64) {
    rbox[lane] = boxes6k[(size_t)b * ROWP + gb * 64 + lane];
    rar[lane]  = area6k [(size_t)b * ROWP + gb * 64 + lane];
  }
  __syncthreads();
  u64 vmask = validW[(size_t)b * 96 + gb];

  int    cw[4];
  u64    rowsel[4], bits[4];
  float4 cbox[4];
  float  carea[4];
  #pragma unroll
  for (int k = 0; k < 4; ++k) {
    cw[k] = cw0 + 4 * k + w;            // wave w owns words cw0+w, +4, +8, +12
    int col = cw[k] * 64 + lane;
    int colc = col < (ROWP - 1) ? col : (ROWP - 1);
    cbox[k]  = boxes6k[(size_t)b * ROWP + colc];
    carea[k] = area6k [(size_t)b * ROWP + colc];
    rowsel[k] = (cw[k] > gb) ? vmask
              : ((cw[k] == gb && lane) ? (vmask & ((1ull << lane) - 1ull)) : 0ull);
    bits[k] = 0ull;
  }

  const double M = 0x1.6666668p-1;      // exact decision midpoint for (iou > 0.7f)
  #pragma unroll 4
  for (int r = 0; r < 64; ++r) {
    float4 rb = rbox[r];
    float  ra = rar[r];
    #pragma unroll
    for (int k = 0; k < 4; ++k) {
      float xx1 = fmaxf(rb.x, cbox[k].x), yy1 = fmaxf(rb.y, cbox[k].y);
      float xx2 = fminf(rb.z, cbox[k].z), yy2 = fminf(rb.w, cbox[k].w);
      float inter = fmaxf(xx2 - xx1, 0.0f) * fmaxf(yy2 - yy1, 0.0f);
      float un = fmaxf(ra + carea[k] - inter, 1e-9f);
      bits[k] |= ((double)inter >= M * (double)un) ? (1ull << r) : 0ull;
    }
  }

  int rbase = gb * 64;
  #pragma unroll
  for (int k = 0; k < 4; ++k) {
    if (cw[k] >= NWRD) continue;
    u64 bt = bits[k] & rowsel[k];
    int col = cw[k] * 64 + lane;
    while (bt) {
      int r = __ffsll((long long)bt) - 1;
      bt &= bt - 1;
      uint pos = atomicAdd(&cnt[(size_t)b * ROWP + col], 1u);
      if (pos < KSUP) list[((size_t)b * ROWP + col) * KSUP + pos] = (uint)(rbase + r);
    }
  }
}

// ---------- pass 6: sparse Jacobi fixpoint resolve + fused finalize ----------
__global__ __launch_bounds__(1024) void sparse_resolve(const uint* __restrict__ cnt,
                                                       const uint* __restrict__ list,
                                                       const u64* __restrict__ validW,
                                                       const float* __restrict__ score6k,
                                                       const float4* __restrict__ boxes6k,
                                                       float* __restrict__ out) {
  int b = blockIdx.x, tid = threadIdx.x;
  __shared__ u64 ALIVE[96], DEC[96], VW[96];
  __shared__ int changed;
  if (tid < 96) {
    ALIVE[tid] = 0ull; DEC[tid] = 0ull;
    VW[tid] = validW[(size_t)b * 96 + tid];
  }
  __syncthreads();

  uint myCnt[6];
  #pragma unroll
  for (int r = 0; r < 6; ++r) {
    int j = tid + r * 1024;
    myCnt[r] = (j < PRE) ? cnt[(size_t)b * ROWP + j] : 0u;
  }
  // init: cnt==0 or invalid boxes decide immediately
  #pragma unroll
  for (int r = 0; r < 6; ++r) {
    int j = tid + r * 1024;
    if (j >= PRE) continue;
    bool valid = (VW[j >> 6] >> (j & 63)) & 1ull;
    if (myCnt[r] == 0u || !valid) {
      atomicOr(&DEC[j >> 6], 1ull << (j & 63));
      if (valid) atomicOr(&ALIVE[j >> 6], 1ull << (j & 63));
    }
  }
  __syncthreads();

  // fixpoint rounds (terminates: lowest undecided box always decides)
  while (true) {
    if (tid == 0) changed = 0;
    __syncthreads();
    // compute phase (state is stable)
    int decJ[6]; bool decAlive[6];
    #pragma unroll
    for (int r = 0; r < 6; ++r) {
      decJ[r] = -1; decAlive[r] = false;
      int j = tid + r * 1024;
      if (j >= PRE || myCnt[r] == 0u) continue;
      if ((DEC[j >> 6] >> (j & 63)) & 1ull) continue;
      const uint* lj = list + ((size_t)b * ROWP + j) * KSUP;
      uint c = myCnt[r] < KSUP ? myCnt[r] : KSUP;
      bool anyAlive = false, pending = false;
      for (uint m = 0; m < c; ++m) {
        uint i = lj[m];
        bool ai = (ALIVE[i >> 6] >> (i & 63)) & 1ull;
        bool di = (DEC[i >> 6] >> (i & 63)) & 1ull;
        if (ai) { anyAlive = true; break; }
        if (!di) pending = true;
      }
      if (anyAlive)      { decJ[r] = j; decAlive[r] = false; }
      else if (!pending) { decJ[r] = j; decAlive[r] = true;  }
    }
    __syncthreads();
    // apply phase
    bool any = false;
    #pragma unroll
    for (int r = 0; r < 6; ++r) {
      if (decJ[r] >= 0) {
        int j = decJ[r];
        if (decAlive[r]) atomicOr(&ALIVE[j >> 6], 1ull << (j & 63));
        atomicOr(&DEC[j >> 6], 1ull << (j & 63));
        any = true;
      }
    }
    if (any) atomicAdd(&changed, 1);
    __syncthreads();
    if (changed == 0) break;
  }

  // ---- fused finalize: rank kept, emit first 1000 ----
  __shared__ uint pre[NWRD + 1];
  if (tid == 0) {
    uint c = 0;
    for (int w = 0; w < NWRD; ++w) { pre[w] = c; c += (uint)__popcll(ALIVE[w]); }
    pre[NWRD] = c;
  }
  __syncthreads();
  for (int q = tid; q < POST; q += 1024) out[(size_t)b * POST + q] = 0.0f;
  for (int t = tid; t < POST * 4; t += 1024) out[(size_t)BB * POST + (size_t)b * POST * 4 + t] = 0.0f;
  __syncthreads();
  for (int j = tid; j < PRE; j += 1024) {
    int w = j >> 6, bit = j & 63;
    u64 word = ALIVE[w];
    if ((word >> bit) & 1ull) {
      uint rank = pre[w] + (uint)__popcll(word & ((1ull << bit) - 1ull));
      if (rank < POST) {
        out[(size_t)b * POST + rank] = score6k[(size_t)b * ROWP + j];
        float4 bx = boxes6k[(size_t)b * ROWP + j];
        float* o = out + (size_t)BB * POST + ((size_t)b * POST + rank) * 4;
        o[0] = bx.x; o[1] = bx.y; o[2] = bx.z; o[3] = bx.w;
      }
    }
  }
}

extern "C" void kernel_launch(void* const* d_in, const int* in_sizes, int n_in,
                              void* d_out, int out_size, void* d_ws, size_t ws_size,
                              hipStream_t stream) {
  const float4* props = (const float4*)d_in[0];
  const float2* clsp  = (const float2*)d_in[1];
  float* out = (float*)d_out;
  char* ws = (char*)d_ws;

  uint*   hdr     = (uint*)(ws + OFF_HDR);
  uint*   cnt     = (uint*)(ws + OFF_CNT);
  uint*   hist1   = (uint*)(ws + OFF_H1);
  uint*   base    = (uint*)(ws + OFF_BASE);
  uint*   keyhi   = (uint*)(ws + OFF_KEY);
  u64*    buck    = (u64*) (ws + OFF_BUCK);
  uint*   list    = (uint*)(ws + OFF_LIST);
  float4* boxes6k = (float4*)(ws + OFF_BOX);
  float*  score6k = (float*)(ws + OFF_SCO);
  float*  area6k  = (float*)(ws + OFF_AREA);
  u64*    validW  = (u64*) (ws + OFF_VAL);

  dim3 gN((NN + 255) / 256, BB);
  keys_only<<<gN, 256, 0, stream>>>(props, clsp, keyhi);
  hist_range<<<dim3(NRANGE, BB), 256, 0, stream>>>((const uint4*)keyhi, hist1, cnt);
  scan_base<<<BB, 1024, 0, stream>>>(hist1, base, hdr, validW);
  bucket_scatter<<<gN, 256, 0, stream>>>(keyhi, base, hdr, buck);
  rank_scatter<<<dim3(SCAP / 256, BB), 256, 0, stream>>>(buck, base, hist1, hdr,
                                                         props, clsp, boxes6k,
                                                         score6k, area6k, validW);
  sup_build<<<dim3((NWRD + WQ - 1) / WQ, NWRD, BB), 256, 0, stream>>>(boxes6k, area6k,
                                                                      validW, cnt, list);
  sparse_resolve<<<BB, 1024, 0, stream>>>(cnt, list, validW, score6k, boxes6k, out);
}